// Round 5
// baseline (381.370 us; speedup 1.0000x reference)
//
#include <hip/hip_runtime.h>
#include <math.h>

#define TT 2048
#define DD 768
#define NN 256
#define NHH 12
#define BB 2
#define CH 512           // attention chunk (4 chunks of 4 x 128-tiles)

typedef unsigned short u16;
typedef __attribute__((ext_vector_type(8))) short bf16x8;
typedef __attribute__((ext_vector_type(8))) unsigned short u16x8;
typedef __attribute__((ext_vector_type(4))) float f32x4;

static inline int imin(int a, int b) { return a < b ? a : b; }

__device__ __forceinline__ u16 f2b(float f) {
  union { float f; unsigned u; } a; a.f = f;
  unsigned r = a.u + 0x7FFF + ((a.u >> 16) & 1);
  return (u16)(r >> 16);
}
__device__ __forceinline__ float b2f(u16 h) {
  union { unsigned u; float f; } a; a.u = ((unsigned)h) << 16;
  return a.f;
}

__device__ __forceinline__ void async16(const void* g, void* l) {
  __builtin_amdgcn_global_load_lds(
      (const __attribute__((address_space(1))) unsigned*)g,
      (__attribute__((address_space(3))) unsigned*)l, 16, 0, 0);
}

// K-chunk XOR swizzle (T2 adapted to [R][32] bf16 tiles filled by
// global_load_lds): LDS stays linear; the global SOURCE chunk is
// pre-swizzled at stage time and the SAME XOR is applied on every
// fragment read.  chunk' = chunk ^ ((row>>1)&3) gives exactly 2-way
// bank aliasing on ds_read_b128 (free) vs 8-way unswizzled.
#define KSWZ(row) (((row) >> 1) & 3)

// Stage a 128x32 bf16 tile (row-major, ld in elements) into LDS [128][32],
// source-swizzled.
__device__ __forceinline__ void stage128x32(
    const u16* __restrict__ gbase, size_t ld, u16* lds, int tid) {
  const int w = tid >> 6, l = tid & 63;
#pragma unroll
  for (int q = 0; q < 2; ++q) {
    const int row = w * 32 + q * 16 + (l >> 2);
    const int kc = ((l & 3) ^ KSWZ(row)) << 3;
    async16(gbase + (size_t)row * ld + kc, lds + (w * 32 + q * 16) * 32);
  }
}

// Stage a 64x32 bf16 tile into LDS [64][32], source-swizzled.
__device__ __forceinline__ void stage64x32(
    const u16* __restrict__ gbase, size_t ld, u16* lds, int tid) {
  const int w = tid >> 6, l = tid & 63;
  const int row = w * 16 + (l >> 2);
  const int kc = ((l & 3) ^ KSWZ(row)) << 3;
  async16(gbase + (size_t)row * ld + kc, lds + w * 512);
}

// 16 MFMAs of one BK=32 step; wave (wr,wc) computes 64x64 of the 128x128
// tile.  Fragment reads apply the chunk swizzle.
__device__ __forceinline__ void mfma_step(
    const u16* As, const u16* Bs, int wr, int wc, int lane, f32x4 acc[4][4]) {
  const int m16 = lane & 15, quad = lane >> 4;
  bf16x8 a[4], b[4];
#pragma unroll
  for (int i = 0; i < 4; ++i) {
    const int row = wr * 64 + i * 16 + m16;
    a[i] = *(const bf16x8*)&As[row * 32 + ((quad ^ KSWZ(row)) << 3)];
  }
#pragma unroll
  for (int j = 0; j < 4; ++j) {
    const int row = wc * 64 + j * 16 + m16;
    b[j] = *(const bf16x8*)&Bs[row * 32 + ((quad ^ KSWZ(row)) << 3)];
  }
#pragma unroll
  for (int i = 0; i < 4; ++i)
#pragma unroll
    for (int j = 0; j < 4; ++j)
      acc[i][j] = __builtin_amdgcn_mfma_f32_16x16x32_bf16(a[i], b[j], acc[i][j], 0, 0, 0);
}

// copy a full 128x128 u16 tile from LDS (row-major) to global rows of ld.
__device__ __forceinline__ void copy_out128(
    const u16* buf, u16* g, size_t ld, int tid) {
#pragma unroll
  for (int s = 0; s < 8; ++s) {
    const int off = (s * 256 + tid) * 8;
    const int row = off >> 7, col = off & 127;
    *(u16x8*)&g[(size_t)row * ld + col] = *(const u16x8*)&buf[off];
  }
}

#define GEMM_PROLOGUE()                                            \
  __shared__ __attribute__((aligned(16))) u16 smem[32768];         \
  const int tid = threadIdx.x;                                     \
  const int w = tid >> 6, lane = tid & 63;                         \
  const int wr = w >> 1, wc = w & 1;                               \
  const int col16 = lane & 15, quad = lane >> 4;                   \
  f32x4 acc[4][4];                                                 \
  _Pragma("unroll") for (int i = 0; i < 4; ++i)                    \
  _Pragma("unroll") for (int j = 0; j < 4; ++j)                    \
      acc[i][j] = (f32x4){0.f, 0.f, 0.f, 0.f};

// Double-buffered, counted-vmcnt pipelined K loop, BK=64:
// 32 MFMA per barrier-pair, 8 async16/thread/phase, vmcnt(8).
#define PIPELINED_K_LOOP64(ABASE, ALD, BBASE, BLD, KTOT)                    \
  {                                                                         \
    stage128x32((ABASE), (ALD), smem, tid);                                 \
    stage128x32((ABASE) + 32, (ALD), smem + 4096, tid);                     \
    stage128x32((BBASE), (BLD), smem + 8192, tid);                          \
    stage128x32((BBASE) + 32, (BLD), smem + 12288, tid);                    \
    const int np_ = (KTOT) / 64;                                            \
    for (int pp_ = 0; pp_ < np_; ++pp_) {                                   \
      u16* cb_ = (pp_ & 1) ? smem + 16384 : smem;                           \
      u16* nb_ = (pp_ & 1) ? smem : smem + 16384;                           \
      if (pp_ + 1 < np_) {                                                  \
        const int kn_ = (pp_ + 1) * 64;                                     \
        stage128x32((ABASE) + kn_, (ALD), nb_, tid);                        \
        stage128x32((ABASE) + kn_ + 32, (ALD), nb_ + 4096, tid);            \
        stage128x32((BBASE) + kn_, (BLD), nb_ + 8192, tid);                 \
        stage128x32((BBASE) + kn_ + 32, (BLD), nb_ + 12288, tid);           \
        asm volatile("s_waitcnt vmcnt(8)" ::: "memory");                    \
      } else {                                                              \
        asm volatile("s_waitcnt vmcnt(0)" ::: "memory");                    \
      }                                                                     \
      __builtin_amdgcn_s_barrier();                                         \
      __builtin_amdgcn_sched_barrier(0);                                    \
      mfma_step(cb_, cb_ + 8192, wr, wc, lane, acc);                        \
      mfma_step(cb_ + 4096, cb_ + 12288, wr, wc, lane, acc);                \
      __builtin_amdgcn_sched_barrier(0);                                    \
      __builtin_amdgcn_s_barrier();                                         \
    }                                                                       \
  }

// ---------------------------------------------------------------------------
__global__ __launch_bounds__(256) void cvt_bf16(
    const float* __restrict__ in, u16* __restrict__ out, size_t n4) {
  size_t i = ((size_t)blockIdx.x * 256 + threadIdx.x) * 4;
  if (i >= n4 * 4) return;
  float4 v = *(const float4*)&in[i];
  u16 o[4] = {f2b(v.x), f2b(v.y), f2b(v.z), f2b(v.w)};
  *(ushort4*)&out[i] = *(ushort4*)o;
}

__global__ __launch_bounds__(256) void tcvt_bf16(
    const float* __restrict__ in, u16* __restrict__ out, int R, int C,
    size_t inStride, size_t outStride) {
  __shared__ float tile[32][33];
  const float* ip = in + (size_t)blockIdx.z * inStride;
  u16* op = out + (size_t)blockIdx.z * outStride;
  const int c0 = blockIdx.x * 32, r0 = blockIdx.y * 32;
  const int tx = threadIdx.x & 31, ty = threadIdx.x >> 5;
#pragma unroll
  for (int p = 0; p < 4; ++p)
    tile[ty + p * 8][tx] = ip[(size_t)(r0 + ty + p * 8) * C + c0 + tx];
  __syncthreads();
#pragma unroll
  for (int p = 0; p < 4; ++p)
    op[(size_t)(c0 + ty + p * 8) * R + r0 + tx] = f2b(tile[tx][ty + p * 8]);
}

__global__ __launch_bounds__(256) void k_colsum(
    const u16* __restrict__ encvt, float* __restrict__ colsum) {
  const int row = blockIdx.x * 4 + (threadIdx.x >> 6);
  const int lane = threadIdx.x & 63;
  const u16* pr = encvt + (size_t)row * DD;
  float s = 0.f;
#pragma unroll
  for (int i = 0; i < 3; ++i) {
    ushort4 v = *(const ushort4*)&pr[(lane << 2) + i * 256];
    s += b2f(v.x) + b2f(v.y) + b2f(v.z) + b2f(v.w);
  }
#pragma unroll
  for (int off = 32; off; off >>= 1) s += __shfl_xor(s, off);
  if (lane == 0) colsum[row] = s;
}

// Precompute rope cos/sin table (bit-identical to the inline math).
__global__ __launch_bounds__(256) void k_cstab(float2* __restrict__ cs) {
  const int idx = blockIdx.x * 256 + threadIdx.x;   // t*128 + n2
  const int t = idx >> 7, n2 = idx & 127;
  const float freq = exp2f((float)(2 * n2) * -0.0625f) * 0.15915494309189535f;
  const float phase = (float)t * freq;
  const float ph = (phase - floorf(phase)) * 6.283185307179586f;
  cs[idx] = make_float2(__cosf(ph), __sinf(ph));
}

// ---------------------------------------------------------------------------
// K1: latent = X16 @ ENCT[h]^T; relu; rope -> QR16 [b][h][t][n] AND
// QRT16 [b][h][n][t].  BK=64 pipeline; XOR-swizzled epilogue tile for the
// QRT column read.
// ---------------------------------------------------------------------------
__device__ __forceinline__ int swz8(int row) { return ((row >> 3) & 7) << 3; }

__global__ __launch_bounds__(256) void k1_encode(
    const u16* __restrict__ x16, const u16* __restrict__ enct,
    const float2* __restrict__ CS,
    u16* __restrict__ qr16, u16* __restrict__ qrt16) {
  const int h = blockIdx.z;
  const int m0 = blockIdx.x * 128, n0 = blockIdx.y * 128;
  GEMM_PROLOGUE();
  PIPELINED_K_LOOP64(x16 + (size_t)m0 * DD, DD,
                     enct + ((size_t)h * NN + n0) * DD, DD, DD);
  __syncthreads();
#pragma unroll
  for (int i = 0; i < 4; ++i)
#pragma unroll
    for (int j = 0; j < 4; ++j) {
      const int n = n0 + wc * 64 + j * 16 + col16;
      float rv[4], pv[4];
#pragma unroll
      for (int r = 0; r < 4; ++r) rv[r] = fmaxf(acc[i][j][r], 0.f);
#pragma unroll
      for (int r = 0; r < 4; ++r) pv[r] = __shfl_xor(rv[r], 1);
#pragma unroll
      for (int r = 0; r < 4; ++r) {
        const int lrow = wr * 64 + i * 16 + quad * 4 + r;
        const int t = (m0 + lrow) & (TT - 1);
        const float2 cs = CS[t * 128 + (n >> 1)];
        const float o = (n & 1) ? (rv[r] * cs.x + pv[r] * cs.y)
                                : (rv[r] * cs.x - pv[r] * cs.y);
        smem[lrow * 128 + ((wc * 64 + j * 16 + col16) ^ swz8(lrow))] = f2b(o);
      }
    }
  __syncthreads();
  const int bq = m0 >> 11, tb = m0 & (TT - 1);
  const size_t sl = (size_t)(bq * NHH + h);
  // row-major copy (swizzle-aware source)
  u16* qg = qr16 + (sl * TT + tb) * NN + n0;
#pragma unroll
  for (int s = 0; s < 8; ++s) {
    const int off = (s * 256 + tid) * 8;
    const int row = off >> 7, col = off & 127;
    *(u16x8*)&qg[(size_t)row * NN + col] =
        *(const u16x8*)&smem[row * 128 + (col ^ swz8(row))];
  }
  // transposed copy: QRT16[sl][n][t] = tile[t][n]
#pragma unroll
  for (int s = 0; s < 8; ++s) {
    const int off = (s * 256 + tid) * 8;
    const int nr = off >> 7, tc = off & 127;
    const int sw = swz8(tc);                 // tc 8-aligned: same for tc..tc+7
    u16 vals[8];
#pragma unroll
    for (int k = 0; k < 8; ++k) vals[k] = smem[(tc + k) * 128 + (nr ^ sw)];
    *(u16x8*)&qrt16[(sl * NN + n0 + nr) * TT + tb + tc] = *(u16x8*)vals;
  }
}

// ---------------------------------------------------------------------------
// kS: block-diagonal band of S = QR QR^T (strict lower), 40 tiles/slice.
// ---------------------------------------------------------------------------
__global__ __launch_bounds__(256) void kS_band(
    const u16* __restrict__ qr16, u16* __restrict__ sb, int bh0) {
  const int z = blockIdx.y;                  // group-local slice
  const int bh = bh0 + z;
  const int cc = blockIdx.x / 10, rr = blockIdx.x % 10;
  int i = (int)((sqrtf(8.f * rr + 1.f) - 1.f) * 0.5f);
  while ((i + 1) * (i + 2) / 2 <= rr) ++i;
  while (i * (i + 1) / 2 > rr) --i;
  const int j = rr - i * (i + 1) / 2;
  const int t0 = (cc * 4 + i) * 128;
  const int s0 = cc * CH + j * 128;
  const u16* q = qr16 + (size_t)bh * TT * NN;
  GEMM_PROLOGUE();
  PIPELINED_K_LOOP64(q + (size_t)t0 * NN, NN, q + (size_t)s0 * NN, NN, NN);
  const bool diag = (i == j);
  __syncthreads();
#pragma unroll
  for (int ii = 0; ii < 4; ++ii)
#pragma unroll
    for (int jj = 0; jj < 4; ++jj) {
      const int s = s0 + wc * 64 + jj * 16 + col16;
#pragma unroll
      for (int r = 0; r < 4; ++r) {
        const int lrow = wr * 64 + ii * 16 + quad * 4 + r;
        const int t = t0 + lrow;
        float v = acc[ii][jj][r];
        if (diag && s >= t) v = 0.f;
        smem[lrow * 128 + wc * 64 + jj * 16 + col16] = f2b(v);
      }
    }
  __syncthreads();
  copy_out128(smem, sb + ((size_t)z * TT + t0) * CH + j * 128, CH, tid);
}

// ---------------------------------------------------------------------------
// kB_all: each block owns a 64(d) x 128(n) tile of H, K=0..1536 fp32 acc,
// bf16 snapshot H16[z][c] at each chunk boundary.  BK=64 phases, vmcnt(6).
// ---------------------------------------------------------------------------
__global__ __launch_bounds__(256) void kB_all(
    const u16* __restrict__ xt16, const u16* __restrict__ qrt16,
    u16* __restrict__ h16, int bh0) {
  __shared__ __attribute__((aligned(16))) u16 sm[32768];
  u16* buf0 = sm;            // A0 +0, A1 +2048, B0 +4096, B1 +8192 (u16)
  u16* buf1 = sm + 12288;
  u16* snap = sm + 24576;    // 64x128 u16
  const int tid = threadIdx.x;
  const int w = tid >> 6, lane = tid & 63;
  const int m16 = lane & 15, quad = lane >> 4;
  const int z = blockIdx.z;
  const int bh = bh0 + z, b = bh / NHH;
  const int d0 = blockIdx.x * 64, n0 = blockIdx.y * 128;
  f32x4 acc[4][2];
#pragma unroll
  for (int i = 0; i < 4; ++i)
#pragma unroll
    for (int j = 0; j < 2; ++j) acc[i][j] = (f32x4){0.f, 0.f, 0.f, 0.f};
  const u16* Ab = xt16 + ((size_t)b * DD + d0) * TT;
  const u16* Bb = qrt16 + ((size_t)bh * NN + n0) * TT;
#define KB_STAGE(buf, k0)                                                   \
  {                                                                         \
    stage64x32(Ab + (k0), TT, (buf), tid);                                  \
    stage64x32(Ab + (k0) + 32, TT, (buf) + 2048, tid);                      \
    stage128x32(Bb + (k0), TT, (buf) + 4096, tid);                          \
    stage128x32(Bb + (k0) + 32, TT, (buf) + 8192, tid);                     \
  }
  for (int c = 0; c < 3; ++c) {
    const int kbase = c * CH;
    KB_STAGE(buf0, kbase);
    for (int s = 0; s < CH / 64; ++s) {
      u16* cb = (s & 1) ? buf1 : buf0;
      u16* nb = (s & 1) ? buf0 : buf1;
      if (s + 1 < CH / 64) {
        KB_STAGE(nb, kbase + (s + 1) * 64);
        asm volatile("s_waitcnt vmcnt(6)" ::: "memory");
      } else {
        asm volatile("s_waitcnt vmcnt(0)" ::: "memory");
      }
      __builtin_amdgcn_s_barrier();
      __builtin_amdgcn_sched_barrier(0);
#pragma unroll
      for (int half = 0; half < 2; ++half) {
        bf16x8 a[4], bb[2];
#pragma unroll
        for (int i = 0; i < 4; ++i) {
          const int row = i * 16 + m16;
          a[i] = *(const bf16x8*)&cb[half * 2048 + row * 32 +
                                     ((quad ^ KSWZ(row)) << 3)];
        }
#pragma unroll
        for (int j = 0; j < 2; ++j) {
          const int row = w * 32 + j * 16 + m16;
          bb[j] = *(const bf16x8*)&cb[4096 + half * 4096 + row * 32 +
                                      ((quad ^ KSWZ(row)) << 3)];
        }
#pragma unroll
        for (int i = 0; i < 4; ++i)
#pragma unroll
          for (int j = 0; j < 2; ++j)
            acc[i][j] = __builtin_amdgcn_mfma_f32_16x16x32_bf16(a[i], bb[j], acc[i][j], 0, 0, 0);
      }
      __builtin_amdgcn_sched_barrier(0);
      __builtin_amdgcn_s_barrier();
    }
    // snapshot H16[z][c]
#pragma unroll
    for (int i = 0; i < 4; ++i)
#pragma unroll
      for (int j = 0; j < 2; ++j)
#pragma unroll
        for (int r = 0; r < 4; ++r)
          snap[(i * 16 + quad * 4 + r) * 128 + w * 32 + j * 16 + m16] =
              f2b(acc[i][j][r]);
    __syncthreads();
    u16* hd = h16 + (size_t)(z * 3 + c) * DD * NN;
#pragma unroll
    for (int s4 = 0; s4 < 4; ++s4) {
      const int off = (s4 * 256 + tid) * 8;
      const int row = off >> 7, col = off & 127;
      *(u16x8*)&hd[(size_t)(d0 + row) * NN + n0 + col] = *(const u16x8*)&snap[off];
    }
    __syncthreads();
  }
#undef KB_STAGE
}

// ---------------------------------------------------------------------------
// kA: 128x128 output, unified panel-pipelined K sequence.
// 1D grid, bijective chunked XCD swizzle (T1) + LPT tt order.
// Fused k3: per-row partial sum/sumsq of the bf16-rounded output is
// shfl-reduced over col16 lanes and atomicAdd'ed into SUMB/SQB.
// ---------------------------------------------------------------------------
__device__ static const int TTORD[16] = {15, 11, 7, 14, 10, 6, 13, 9,
                                         5, 3, 12, 8, 4, 2, 1, 0};

__global__ __launch_bounds__(256) void kA_attn(
    const u16* __restrict__ qr16, const u16* __restrict__ h16,
    const u16* __restrict__ sb, const u16* __restrict__ xt16,
    u16* __restrict__ ykv16, float* __restrict__ SUMB,
    float* __restrict__ SQB, int bh0) {
  __shared__ __attribute__((aligned(16))) u16 smem[32768];  // 2 x 32KB buffers
  const int tid = threadIdx.x;
  const int w = tid >> 6, lane = tid & 63;
  const int wr = w >> 1, wc = w & 1;
  const int col16 = lane & 15, quad = lane >> 4;
  const int nwg = gridDim.x;
  const int bid = blockIdx.x;
  const int qn = nwg >> 3, r8 = nwg & 7;
  const int xcd = bid & 7, pos = bid >> 3;
  const int wg = (xcd < r8 ? xcd * (qn + 1) : r8 * (qn + 1) + (xcd - r8) * qn) + pos;
  const int z = wg / 96;
  const int tt = TTORD[(wg / 6) & 15];       // LPT within chunk
  const int d0 = (wg % 6) * 128;
  const int bh = bh0 + z, b = bh / NHH;
  const int c = tt >> 2, it = tt & 3;
  const int t0 = tt * 128;
  f32x4 acc[4][4];
#pragma unroll
  for (int i = 0; i < 4; ++i)
#pragma unroll
    for (int j = 0; j < 4; ++j) acc[i][j] = (f32x4){0.f, 0.f, 0.f, 0.f};

  const int c4 = (c > 0) ? 4 : 0;
  const int nP = c4 + (it + 1) * 2;          // BK=64 panels total
  const u16* hs = h16 + ((size_t)(z * 3 + (c > 0 ? c - 1 : 0)) * DD + d0) * NN;
  const u16* qb = qr16 + ((size_t)bh * TT + t0) * NN;
  const u16* sbb = sb + ((size_t)z * TT + t0) * CH;
  const u16* xb = xt16 + ((size_t)b * DD + d0) * TT + c * CH;

#define KA_STAGE(buf, p)                                                  \
  {                                                                       \
    const u16 *pa_, *pb_; size_t la_, lb_;                                \
    if ((p) < c4) {                                                       \
      pa_ = qb + (p) * 64; la_ = NN;                                      \
      pb_ = hs + (p) * 64; lb_ = NN;                                      \
    } else {                                                              \
      const int q_ = (p) - c4;                                            \
      const int j_ = q_ >> 1, kk_ = (q_ & 1) << 6;                        \
      pa_ = sbb + j_ * 128 + kk_; la_ = CH;                               \
      pb_ = xb + j_ * 128 + kk_; lb_ = TT;                                \
    }                                                                     \
    stage128x32(pa_, la_, (buf), tid);                                    \
    stage128x32(pa_ + 32, la_, (buf) + 4096, tid);                        \
    stage128x32(pb_, lb_, (buf) + 8192, tid);                             \
    stage128x32(pb_ + 32, lb_, (buf) + 12288, tid);                       \
  }

  u16* bufA = smem;
  u16* bufB = smem + 16384;
  KA_STAGE(bufA, 0);
  for (int p = 0; p < nP; ++p) {
    u16* cb = (p & 1) ? bufB : bufA;
    u16* nb = (p & 1) ? bufA : bufB;
    if (p + 1 < nP) {
      KA_STAGE(nb, p + 1);
      asm volatile("s_waitcnt vmcnt(8)" ::: "memory");
    } else {
      asm volatile("s_waitcnt vmcnt(0)" ::: "memory");
    }
    __builtin_amdgcn_s_barrier();            // publish panel p across waves
    __builtin_amdgcn_sched_barrier(0);
    mfma_step(cb, cb + 8192, wr, wc, lane, acc);
    mfma_step(cb + 4096, cb + 12288, wr, wc, lane, acc);
    __builtin_amdgcn_sched_barrier(0);
    __builtin_amdgcn_s_barrier();            // reads of cb done before overwrite
  }
#undef KA_STAGE

  __syncthreads();
  float fsum[4][4], fsq[4][4];
#pragma unroll
  for (int i = 0; i < 4; ++i)
#pragma unroll
    for (int r = 0; r < 4; ++r) { fsum[i][r] = 0.f; fsq[i][r] = 0.f; }
#pragma unroll
  for (int i = 0; i < 4; ++i)
#pragma unroll
    for (int j = 0; j < 4; ++j)
#pragma unroll
      for (int r = 0; r < 4; ++r) {
        const int lrow = wr * 64 + i * 16 + quad * 4 + r;
        const u16 hv = f2b(acc[i][j][r]);
        smem[lrow * 128 + wc * 64 + j * 16 + col16] = hv;
        const float vr = b2f(hv);
        fsum[i][r] += vr;
        fsq[i][r] += vr * vr;
      }
  // col16-lane reduce; one atomicAdd pair per (row) from col16==0 lanes.
#pragma unroll
  for (int i = 0; i < 4; ++i)
#pragma unroll
    for (int r = 0; r < 4; ++r) {
      float s = fsum[i][r], q2 = fsq[i][r];
#pragma unroll
      for (int off = 1; off < 16; off <<= 1) {
        s += __shfl_xor(s, off);
        q2 += __shfl_xor(q2, off);
      }
      if (col16 == 0) {
        const int grow = z * TT + t0 + wr * 64 + i * 16 + quad * 4 + r;
        atomicAdd(&SUMB[grow], s);
        atomicAdd(&SQB[grow], q2);
      }
    }
  __syncthreads();
  copy_out128(smem, ykv16 + ((size_t)z * TT + t0) * DD + d0, DD, tid);
}

// ---------------------------------------------------------------------------
// K4: raw GEMM ykv16 @ ENCVT[h]^T with LN as epilogue affine (stats from
// SUMB/SQB); xs via inverse rope of QR16 (CS table), QR tile staged into
// LDS via coalesced async16; out2 = xs*ys; XY written in place into QR16.
// ---------------------------------------------------------------------------
__global__ __launch_bounds__(256) void k4_xy(
    const u16* __restrict__ ykv16, const u16* __restrict__ encvt,
    const float2* __restrict__ CS,
    u16* __restrict__ qrxy, const float* __restrict__ SUMB,
    const float* __restrict__ SQB, const float* __restrict__ colsum,
    float* __restrict__ out2, int bh0) {
  const int z = blockIdx.z;
  const int bh = bh0 + z, h = bh % NHH;
  const int t0 = blockIdx.x * 128, n0 = blockIdx.y * 128;
  GEMM_PROLOGUE();
  PIPELINED_K_LOOP64(ykv16 + ((size_t)z * TT + t0) * DD, DD,
                     encvt + ((size_t)h * NN + n0) * DD, DD, DD);
  // stage the QR tile (128x128) into the upper 32KB, coalesced.
  {
    const u16* qg = qrxy + ((size_t)bh * TT + t0) * NN + n0;
#pragma unroll
    for (int s = 0; s < 8; ++s) {
      const int row = s * 16 + w * 4 + (lane >> 4);
      const int col = (lane & 15) * 8;
      async16(qg + (size_t)row * NN + col,
              smem + 16384 + (s * 256 + w * 64) * 8);
    }
  }
  asm volatile("s_waitcnt vmcnt(0)" ::: "memory");
  __syncthreads();
#pragma unroll
  for (int i = 0; i < 4; ++i) {
    float muv[4], rsv[4];
#pragma unroll
    for (int r = 0; r < 4; ++r) {
      const int grow = z * TT + t0 + wr * 64 + i * 16 + quad * 4 + r;
      const float m_ = SUMB[grow] * (1.f / 768.f);
      muv[r] = m_;
      rsv[r] = rsqrtf(SQB[grow] * (1.f / 768.f) - m_ * m_ + 1e-5f);
    }
#pragma unroll
    for (int j = 0; j < 4; ++j) {
      const int lcol = wc * 64 + j * 16 + col16;
      const int n = n0 + lcol;
      const float csum = colsum[h * NN + n];
#pragma unroll
      for (int r = 0; r < 4; ++r) {
        const int lrow = wr * 64 + i * 16 + quad * 4 + r;
        const int t = t0 + lrow;
        const float ys = fmaxf(rsv[r] * acc[i][j][r] - rsv[r] * muv[r] * csum, 0.f);
        const unsigned pq =
            *(const unsigned*)&smem[16384 + lrow * 128 + (lcol & ~1)];
        const float lo = b2f((u16)pq), hi = b2f((u16)(pq >> 16));
        const float2 cs = CS[t * 128 + (n >> 1)];
        const float xs = (n & 1) ? (hi * cs.x - lo * cs.y)
                                 : (lo * cs.x + hi * cs.y);
        const float val = ys * xs;
        out2[((size_t)bh * TT + t) * NN + n] = val;
        smem[lrow * 128 + lcol] = f2b(val);
      }
    }
  }
  __syncthreads();
  copy_out128(smem, qrxy + ((size_t)bh * TT + t0) * NN + n0, NN, tid);
}

// ---------------------------------------------------------------------------
// K5: ymlp = flat(XY) @ DECT^T.  M=4096, N=768, K=3072.  64x64 tiles,
// BK=64, triple-buffered (2-deep prefetch, vmcnt(8)).
// ---------------------------------------------------------------------------
__global__ __launch_bounds__(256) void k5_mlp(
    const u16* __restrict__ xyq, const u16* __restrict__ dect,
    float* __restrict__ ymlp) {
  __shared__ __attribute__((aligned(16))) u16 sm[24576];
  const int tid = threadIdx.x;
  const int w = tid >> 6, lane = tid & 63;
  const int wr = w >> 1, wc = w & 1;
  const int m16 = lane & 15, quad = lane >> 4;
  const int m0 = blockIdx.x * 64, d0 = blockIdx.y * 64;
  f32x4 acc[2][2];
#pragma unroll
  for (int i = 0; i < 2; ++i)
#pragma unroll
    for (int j = 0; j < 2; ++j) acc[i][j] = (f32x4){0.f, 0.f, 0.f, 0.f};
  const int ar = w * 16 + (lane >> 2);      // A row within 64-tile
  const int m = m0 + ar;
  const int b = m >> 11, t = m & (TT - 1);
  const int kc = (((lane & 3) ^ KSWZ(ar)) << 3);   // source-swizzled chunk
#define K5_STAGE(buf, k0)                                                   \
  {                                                                         \
    const int hh_ = (k0) >> 8;                                              \
    const int kk_ = ((k0) & 255) + kc;                                      \
    const u16* ap_ = xyq + ((size_t)(b * NHH + hh_) * TT + t) * NN;         \
    async16(ap_ + kk_, (buf) + w * 512);                                    \
    async16(ap_ + kk_ + 32, (buf) + 2048 + w * 512);                        \
    stage64x32(dect + (size_t)d0 * (NHH * NN) + (k0), NHH * NN,             \
               (buf) + 4096, tid);                                          \
    stage64x32(dect + (size_t)d0 * (NHH * NN) + (k0) + 32, NHH * NN,        \
               (buf) + 6144, tid);                                          \
  }
  const int NK = (NHH * NN) / 64;           // 48 phases
  u16 *b0 = sm, *b1 = sm + 8192, *b2 = sm + 16384;
  K5_STAGE(b0, 0);
  K5_STAGE(b1, 64);
  for (int s = 0; s < NK; ++s) {
    if (s + 2 < NK) {
      K5_STAGE(b2, (s + 2) * 64);
      asm volatile("s_waitcnt vmcnt(8)" ::: "memory");
    } else if (s + 1 < NK) {
      asm volatile("s_waitcnt vmcnt(4)" ::: "memory");
    } else {
      asm volatile("s_waitcnt vmcnt(0)" ::: "memory");
    }
    __builtin_amdgcn_s_barrier();
    __builtin_amdgcn_sched_barrier(0);
#pragma unroll
    for (int half = 0; half < 2; ++half) {
      bf16x8 a[2], bb[2];
#pragma unroll
      for (int i = 0; i < 2; ++i) {
        const int row = wr * 32 + i * 16 + m16;
        a[i] = *(const bf16x8*)&b0[half * 2048 + row * 32 +
                                   ((quad ^ KSWZ(row)) << 3)];
      }
#pragma unroll
      for (int j = 0; j < 2; ++j) {
        const int row = wc * 32 + j * 16 + m16;
        bb[j] = *(const bf16x8*)&b0[4096 + half * 2048 + row * 32 +
                                    ((quad ^ KSWZ(row)) << 3)];
      }
#pragma unroll
      for (int i = 0; i < 2; ++i)
#pragma unroll
        for (int j = 0; j < 2; ++j)
          acc[i][j] = __builtin_amdgcn_mfma_f32_16x16x32_bf16(a[i], bb[j], acc[i][j], 0, 0, 0);
    }
    __builtin_amdgcn_sched_barrier(0);
    __builtin_amdgcn_s_barrier();
    u16* tmp = b0; b0 = b1; b1 = b2; b2 = tmp;
  }
#undef K5_STAGE
#pragma unroll
  for (int i = 0; i < 2; ++i)
#pragma unroll
    for (int j = 0; j < 2; ++j) {
      const int d = d0 + wc * 32 + j * 16 + m16;
#pragma unroll
      for (int r = 0; r < 4; ++r) {
        const int mm = m0 + wr * 32 + i * 16 + quad * 4 + r;
        ymlp[(size_t)mm * DD + d] = acc[i][j][r];
      }
    }
}

// ---------------------------------------------------------------------------
// K6: y = ln(ymlp)*sqrt(0.1/(ra+1e-6))*scale; out1 = ln(x+y). Block per row.
// ---------------------------------------------------------------------------
__global__ __launch_bounds__(256) void k6_final(
    const float* __restrict__ ymlp, const float* __restrict__ x,
    const float* __restrict__ scale, const float* __restrict__ ra,
    float* __restrict__ out1) {
  const int row = blockIdx.x;
  const int tid = threadIdx.x;
  const int wid = tid >> 6, lane = tid & 63;
  __shared__ float red[8];
  float v[3];
  float sum = 0.f, sq = 0.f;
#pragma unroll
  for (int j = 0; j < 3; ++j) {
    v[j] = ymlp[(size_t)row * DD + tid + j * 256];
    sum += v[j]; sq += v[j] * v[j];
  }
#pragma unroll
  for (int off = 32; off; off >>= 1) { sum += __shfl_xor(sum, off); sq += __shfl_xor(sq, off); }
  if (lane == 0) { red[wid] = sum; red[4 + wid] = sq; }
  __syncthreads();
  sum = red[0] + red[1] + red[2] + red[3];
  sq = red[4] + red[5] + red[6] + red[7];
  const float m1 = sum * (1.f / 768.f);
  const float r1 = rsqrtf(sq * (1.f / 768.f) - m1 * m1 + 1e-5f);
  float z[3];
  float sum2 = 0.f, sq2 = 0.f;
#pragma unroll
  for (int j = 0; j < 3; ++j) {
    const int d = tid + j * 256;
    float y = (v[j] - m1) * r1 * sqrtf(0.1f / (ra[d] + 1e-6f)) * scale[d];
    z[j] = x[(size_t)row * DD + d] + y;
    sum2 += z[j]; sq2 += z[j] * z[j];
  }
  __syncthreads();
#pragma unroll
  for (int off = 32; off; off >>= 1) { sum2 += __shfl_xor(sum2, off); sq2 += __shfl_xor(sq2, off); }
  if (lane == 0) { red[wid] = sum2; red[4 + wid] = sq2; }
  __syncthreads();
  sum2 = red[0] + red[1] + red[2] + red[3];
  sq2 = red[4] + red[5] + red[6] + red[7];
  const float m2 = sum2 * (1.f / 768.f);
  const float r2 = rsqrtf(sq2 * (1.f / 768.f) - m2 * m2 + 1e-5f);
#pragma unroll
  for (int j = 0; j < 3; ++j)
    out1[(size_t)row * DD + tid + j * 256] = (z[j] - m2) * r2;
}

// ---------------------------------------------------------------------------
extern "C" void kernel_launch(void* const* d_in, const int* in_sizes, int n_in,
                              void* d_out, int out_size, void* d_ws, size_t ws_size,
                              hipStream_t stream) {
  const float* x = (const float*)d_in[0];
  const float* enc = (const float*)d_in[1];
  const float* encv = (const float*)d_in[2];
  const float* dec = (const float*)d_in[3];
  const float* scale = (const float*)d_in[4];
  const float* ra = (const float*)d_in[5];
  float* out1 = (float*)d_out;
  float* out2 = out1 + (size_t)BB * TT * DD;
  float* ymlp = out1;                         // k5 scratch, k6 in-place

  const int NS = BB * NHH;  // 24 slices
  unsigned char* p = (unsigned char*)d_ws;
  u16* X16 = (u16*)p;    p += (size_t)BB * TT * DD * 2;
  u16* XT16 = (u16*)p;   p += (size_t)BB * DD * TT * 2;
  u16* ENCT = (u16*)p;   p += (size_t)NHH * NN * DD * 2;
  u16* ENCVT = (u16*)p;  p += (size_t)NHH * NN * DD * 2;
  u16* DECT = (u16*)p;   p += (size_t)DD * NHH * NN * 2;
  u16* QR16 = (u16*)p;   p += (size_t)NS * TT * NN * 2;   // holds QR, then XY
  u16* QRT16 = (u16*)p;  p += (size_t)NS * NN * TT * 2;
  float* COLSUM = (float*)p; p += (size_t)NHH * NN * 4;
  float2* CS = (float2*)p;   p += (size_t)TT * (NN / 2) * sizeof(float2);
  const size_t SLICE_B = (size_t)TT * CH * 2 + 3 * (size_t)DD * NN * 2 +
                         (size_t)TT * DD * 2 + (size_t)TT * 8;
  size_t fixed = (size_t)(p - (unsigned char*)d_ws);
  size_t rem = (ws_size > fixed) ? ws_size - fixed : 0;
  int GSmax = (int)(rem / SLICE_B);
  if (GSmax < 1) GSmax = 1;
  if (GSmax > NS) GSmax = NS;
  const int ngrp = (NS + GSmax - 1) / GSmax;
  const int GS = (NS + ngrp - 1) / ngrp;     // balanced groups
  u16* SB = (u16*)p;     p += (size_t)GS * TT * CH * 2;
  u16* H16 = (u16*)p;    p += (size_t)GS * 3 * DD * NN * 2;
  u16* YKV16 = (u16*)p;  p += (size_t)GS * TT * DD * 2;
  float* SUMB = (float*)p; p += (size_t)GS * TT * 4;
  float* SQB = (float*)p;  p += (size_t)GS * TT * 4;

  // One-time conversions / transposes
  cvt_bf16<<<dim3((BB * TT * DD) / 1024), 256, 0, stream>>>(x, X16, (size_t)BB * TT * DD / 4);
  tcvt_bf16<<<dim3(DD / 32, TT / 32, BB), 256, 0, stream>>>(
      x, XT16, TT, DD, (size_t)TT * DD, (size_t)DD * TT);
  tcvt_bf16<<<dim3(NN / 32, DD / 32, NHH), 256, 0, stream>>>(
      enc, ENCT, DD, NN, (size_t)DD * NN, (size_t)NN * DD);
  tcvt_bf16<<<dim3(NN / 32, DD / 32, NHH), 256, 0, stream>>>(
      encv, ENCVT, DD, NN, (size_t)DD * NN, (size_t)NN * DD);
  tcvt_bf16<<<dim3(DD / 32, (NHH * NN) / 32, 1), 256, 0, stream>>>(
      dec, DECT, NHH * NN, DD, 0, 0);
  k_colsum<<<dim3(NHH * NN / 4), 256, 0, stream>>>(ENCVT, COLSUM);
  k_cstab<<<dim3(TT * (NN / 2) / 256), 256, 0, stream>>>(CS);

  k1_encode<<<dim3(BB * TT / 128, NN / 128, NHH), 256, 0, stream>>>(
      X16, ENCT, CS, QR16, QRT16);

  for (int bh0 = 0; bh0 < NS; bh0 += GS) {
    const int gs = imin(GS, NS - bh0);
    hipMemsetAsync(SUMB, 0, (size_t)GS * TT * 8, stream);  // SUMB+SQB
    kS_band<<<dim3(40, gs), 256, 0, stream>>>(QR16, SB, bh0);
    kB_all<<<dim3(DD / 64, NN / 128, gs), 256, 0, stream>>>(
        XT16, QRT16, H16, bh0);
    kA_attn<<<dim3(96 * gs), 256, 0, stream>>>(
        QR16, H16, SB, XT16, YKV16, SUMB, SQB, bh0);
    k4_xy<<<dim3(TT / 128, NN / 128, gs), 256, 0, stream>>>(
        YKV16, ENCVT, CS, QR16, SUMB, SQB, COLSUM, out2, bh0);
  }

  k5_mlp<<<dim3(BB * TT / 64, DD / 64), 256, 0, stream>>>(QR16, DECT, ymlp);
  k6_final<<<dim3(BB * TT), 256, 0, stream>>>(ymlp, x, scale, ra, out1);
}

// Round 6
// 378.712 us; speedup vs baseline: 1.0070x; 1.0070x over previous
//
#include <hip/hip_runtime.h>
#include <math.h>

#define TT 2048
#define DD 768
#define NN 256
#define NHH 12
#define BB 2
#define CH 512           // attention chunk (4 chunks of 4 x 128-tiles)

typedef unsigned short u16;
typedef __attribute__((ext_vector_type(8))) short bf16x8;
typedef __attribute__((ext_vector_type(8))) unsigned short u16x8;
typedef __attribute__((ext_vector_type(4))) float f32x4;

static inline int imin(int a, int b) { return a < b ? a : b; }

__device__ __forceinline__ u16 f2b(float f) {
  union { float f; unsigned u; } a; a.f = f;
  unsigned r = a.u + 0x7FFF + ((a.u >> 16) & 1);
  return (u16)(r >> 16);
}
__device__ __forceinline__ float b2f(u16 h) {
  union { unsigned u; float f; } a; a.u = ((unsigned)h) << 16;
  return a.f;
}

__device__ __forceinline__ void async16(const void* g, void* l) {
  __builtin_amdgcn_global_load_lds(
      (const __attribute__((address_space(1))) unsigned*)g,
      (__attribute__((address_space(3))) unsigned*)l, 16, 0, 0);
}

// K-chunk XOR swizzle: LDS stays linear; the global SOURCE chunk is
// pre-swizzled at stage time and the SAME XOR is applied on every
// fragment read.  chunk' = chunk ^ ((row>>1)&3) gives 2-way bank
// aliasing on ds_read_b128 (free) vs 8-way unswizzled.
#define KSWZ(row) (((row) >> 1) & 3)

// Stage a 128x32 bf16 tile (row-major, ld in elements) into LDS [128][32],
// source-swizzled.
__device__ __forceinline__ void stage128x32(
    const u16* __restrict__ gbase, size_t ld, u16* lds, int tid) {
  const int w = tid >> 6, l = tid & 63;
#pragma unroll
  for (int q = 0; q < 2; ++q) {
    const int row = w * 32 + q * 16 + (l >> 2);
    const int kc = ((l & 3) ^ KSWZ(row)) << 3;
    async16(gbase + (size_t)row * ld + kc, lds + (w * 32 + q * 16) * 32);
  }
}

// Stage a 64x32 bf16 tile into LDS [64][32], source-swizzled.
__device__ __forceinline__ void stage64x32(
    const u16* __restrict__ gbase, size_t ld, u16* lds, int tid) {
  const int w = tid >> 6, l = tid & 63;
  const int row = w * 16 + (l >> 2);
  const int kc = ((l & 3) ^ KSWZ(row)) << 3;
  async16(gbase + (size_t)row * ld + kc, lds + w * 512);
}

// 16 MFMAs of one BK=32 step; wave (wr,wc) computes 64x64 of the 128x128
// tile.  Fragment reads apply the chunk swizzle.
__device__ __forceinline__ void mfma_step(
    const u16* As, const u16* Bs, int wr, int wc, int lane, f32x4 acc[4][4]) {
  const int m16 = lane & 15, quad = lane >> 4;
  bf16x8 a[4], b[4];
#pragma unroll
  for (int i = 0; i < 4; ++i) {
    const int row = wr * 64 + i * 16 + m16;
    a[i] = *(const bf16x8*)&As[row * 32 + ((quad ^ KSWZ(row)) << 3)];
  }
#pragma unroll
  for (int j = 0; j < 4; ++j) {
    const int row = wc * 64 + j * 16 + m16;
    b[j] = *(const bf16x8*)&Bs[row * 32 + ((quad ^ KSWZ(row)) << 3)];
  }
#pragma unroll
  for (int i = 0; i < 4; ++i)
#pragma unroll
    for (int j = 0; j < 4; ++j)
      acc[i][j] = __builtin_amdgcn_mfma_f32_16x16x32_bf16(a[i], b[j], acc[i][j], 0, 0, 0);
}

// copy a full 128x128 u16 tile from LDS (row-major) to global rows of ld.
__device__ __forceinline__ void copy_out128(
    const u16* buf, u16* g, size_t ld, int tid) {
#pragma unroll
  for (int s = 0; s < 8; ++s) {
    const int off = (s * 256 + tid) * 8;
    const int row = off >> 7, col = off & 127;
    *(u16x8*)&g[(size_t)row * ld + col] = *(const u16x8*)&buf[off];
  }
}

#define GEMM_PROLOGUE()                                            \
  __shared__ __attribute__((aligned(16))) u16 smem[32768];         \
  const int tid = threadIdx.x;                                     \
  const int w = tid >> 6, lane = tid & 63;                         \
  const int wr = w >> 1, wc = w & 1;                               \
  const int col16 = lane & 15, quad = lane >> 4;                   \
  f32x4 acc[4][4];                                                 \
  _Pragma("unroll") for (int i = 0; i < 4; ++i)                    \
  _Pragma("unroll") for (int j = 0; j < 4; ++j)                    \
      acc[i][j] = (f32x4){0.f, 0.f, 0.f, 0.f};

// Double-buffered, counted-vmcnt pipelined K loop, BK=64:
// 32 MFMA per barrier-pair, 8 async16/thread/phase, vmcnt(8).
#define PIPELINED_K_LOOP64(ABASE, ALD, BBASE, BLD, KTOT)                    \
  {                                                                         \
    stage128x32((ABASE), (ALD), smem, tid);                                 \
    stage128x32((ABASE) + 32, (ALD), smem + 4096, tid);                     \
    stage128x32((BBASE), (BLD), smem + 8192, tid);                          \
    stage128x32((BBASE) + 32, (BLD), smem + 12288, tid);                    \
    const int np_ = (KTOT) / 64;                                            \
    for (int pp_ = 0; pp_ < np_; ++pp_) {                                   \
      u16* cb_ = (pp_ & 1) ? smem + 16384 : smem;                           \
      u16* nb_ = (pp_ & 1) ? smem : smem + 16384;                           \
      if (pp_ + 1 < np_) {                                                  \
        const int kn_ = (pp_ + 1) * 64;                                     \
        stage128x32((ABASE) + kn_, (ALD), nb_, tid);                        \
        stage128x32((ABASE) + kn_ + 32, (ALD), nb_ + 4096, tid);            \
        stage128x32((BBASE) + kn_, (BLD), nb_ + 8192, tid);                 \
        stage128x32((BBASE) + kn_ + 32, (BLD), nb_ + 12288, tid);           \
        asm volatile("s_waitcnt vmcnt(8)" ::: "memory");                    \
      } else {                                                              \
        asm volatile("s_waitcnt vmcnt(0)" ::: "memory");                    \
      }                                                                     \
      __builtin_amdgcn_s_barrier();                                         \
      __builtin_amdgcn_sched_barrier(0);                                    \
      mfma_step(cb_, cb_ + 8192, wr, wc, lane, acc);                        \
      mfma_step(cb_ + 4096, cb_ + 12288, wr, wc, lane, acc);                \
      __builtin_amdgcn_sched_barrier(0);                                    \
      __builtin_amdgcn_s_barrier();                                         \
    }                                                                       \
  }

// ---------------------------------------------------------------------------
__global__ __launch_bounds__(256) void cvt_bf16(
    const float* __restrict__ in, u16* __restrict__ out, size_t n4) {
  size_t i = ((size_t)blockIdx.x * 256 + threadIdx.x) * 4;
  if (i >= n4 * 4) return;
  float4 v = *(const float4*)&in[i];
  u16 o[4] = {f2b(v.x), f2b(v.y), f2b(v.z), f2b(v.w)};
  *(ushort4*)&out[i] = *(ushort4*)o;
}

__global__ __launch_bounds__(256) void tcvt_bf16(
    const float* __restrict__ in, u16* __restrict__ out, int R, int C,
    size_t inStride, size_t outStride) {
  __shared__ float tile[32][33];
  const float* ip = in + (size_t)blockIdx.z * inStride;
  u16* op = out + (size_t)blockIdx.z * outStride;
  const int c0 = blockIdx.x * 32, r0 = blockIdx.y * 32;
  const int tx = threadIdx.x & 31, ty = threadIdx.x >> 5;
#pragma unroll
  for (int p = 0; p < 4; ++p)
    tile[ty + p * 8][tx] = ip[(size_t)(r0 + ty + p * 8) * C + c0 + tx];
  __syncthreads();
#pragma unroll
  for (int p = 0; p < 4; ++p)
    op[(size_t)(c0 + ty + p * 8) * R + r0 + tx] = f2b(tile[tx][ty + p * 8]);
}

__global__ __launch_bounds__(256) void k_colsum(
    const u16* __restrict__ encvt, float* __restrict__ colsum) {
  const int row = blockIdx.x * 4 + (threadIdx.x >> 6);
  const int lane = threadIdx.x & 63;
  const u16* pr = encvt + (size_t)row * DD;
  float s = 0.f;
#pragma unroll
  for (int i = 0; i < 3; ++i) {
    ushort4 v = *(const ushort4*)&pr[(lane << 2) + i * 256];
    s += b2f(v.x) + b2f(v.y) + b2f(v.z) + b2f(v.w);
  }
#pragma unroll
  for (int off = 32; off; off >>= 1) s += __shfl_xor(s, off);
  if (lane == 0) colsum[row] = s;
}

// Precompute rope cos/sin table (bit-identical to the inline math).
__global__ __launch_bounds__(256) void k_cstab(float2* __restrict__ cs) {
  const int idx = blockIdx.x * 256 + threadIdx.x;   // t*128 + n2
  const int t = idx >> 7, n2 = idx & 127;
  const float freq = exp2f((float)(2 * n2) * -0.0625f) * 0.15915494309189535f;
  const float phase = (float)t * freq;
  const float ph = (phase - floorf(phase)) * 6.283185307179586f;
  cs[idx] = make_float2(__cosf(ph), __sinf(ph));
}

// ---------------------------------------------------------------------------
// K1: latent = X16 @ ENCT[h]^T; relu; rope -> QR16 [b][h][t][n] AND
// QRT16 [b][h][n][t].  BK=64 pipeline; XOR-swizzled epilogue tile for the
// QRT column read.
// ---------------------------------------------------------------------------
__device__ __forceinline__ int swz8(int row) { return ((row >> 3) & 7) << 3; }

__global__ __launch_bounds__(256) void k1_encode(
    const u16* __restrict__ x16, const u16* __restrict__ enct,
    const float2* __restrict__ CS,
    u16* __restrict__ qr16, u16* __restrict__ qrt16) {
  const int h = blockIdx.z;
  const int m0 = blockIdx.x * 128, n0 = blockIdx.y * 128;
  GEMM_PROLOGUE();
  PIPELINED_K_LOOP64(x16 + (size_t)m0 * DD, DD,
                     enct + ((size_t)h * NN + n0) * DD, DD, DD);
  __syncthreads();
#pragma unroll
  for (int i = 0; i < 4; ++i)
#pragma unroll
    for (int j = 0; j < 4; ++j) {
      const int n = n0 + wc * 64 + j * 16 + col16;
      float rv[4], pv[4];
#pragma unroll
      for (int r = 0; r < 4; ++r) rv[r] = fmaxf(acc[i][j][r], 0.f);
#pragma unroll
      for (int r = 0; r < 4; ++r) pv[r] = __shfl_xor(rv[r], 1);
#pragma unroll
      for (int r = 0; r < 4; ++r) {
        const int lrow = wr * 64 + i * 16 + quad * 4 + r;
        const int t = (m0 + lrow) & (TT - 1);
        const float2 cs = CS[t * 128 + (n >> 1)];
        const float o = (n & 1) ? (rv[r] * cs.x + pv[r] * cs.y)
                                : (rv[r] * cs.x - pv[r] * cs.y);
        smem[lrow * 128 + ((wc * 64 + j * 16 + col16) ^ swz8(lrow))] = f2b(o);
      }
    }
  __syncthreads();
  const int bq = m0 >> 11, tb = m0 & (TT - 1);
  const size_t sl = (size_t)(bq * NHH + h);
  // row-major copy (swizzle-aware source)
  u16* qg = qr16 + (sl * TT + tb) * NN + n0;
#pragma unroll
  for (int s = 0; s < 8; ++s) {
    const int off = (s * 256 + tid) * 8;
    const int row = off >> 7, col = off & 127;
    *(u16x8*)&qg[(size_t)row * NN + col] =
        *(const u16x8*)&smem[row * 128 + (col ^ swz8(row))];
  }
  // transposed copy: QRT16[sl][n][t] = tile[t][n]
#pragma unroll
  for (int s = 0; s < 8; ++s) {
    const int off = (s * 256 + tid) * 8;
    const int nr = off >> 7, tc = off & 127;
    const int sw = swz8(tc);                 // tc 8-aligned: same for tc..tc+7
    u16 vals[8];
#pragma unroll
    for (int k = 0; k < 8; ++k) vals[k] = smem[(tc + k) * 128 + (nr ^ sw)];
    *(u16x8*)&qrt16[(sl * NN + n0 + nr) * TT + tb + tc] = *(u16x8*)vals;
  }
}

// ---------------------------------------------------------------------------
// kS: block-diagonal band of S = QR QR^T (strict lower), 40 tiles/slice.
// ---------------------------------------------------------------------------
__global__ __launch_bounds__(256) void kS_band(
    const u16* __restrict__ qr16, u16* __restrict__ sb, int bh0) {
  const int z = blockIdx.y;                  // group-local slice
  const int bh = bh0 + z;
  const int cc = blockIdx.x / 10, rr = blockIdx.x % 10;
  int i = (int)((sqrtf(8.f * rr + 1.f) - 1.f) * 0.5f);
  while ((i + 1) * (i + 2) / 2 <= rr) ++i;
  while (i * (i + 1) / 2 > rr) --i;
  const int j = rr - i * (i + 1) / 2;
  const int t0 = (cc * 4 + i) * 128;
  const int s0 = cc * CH + j * 128;
  const u16* q = qr16 + (size_t)bh * TT * NN;
  GEMM_PROLOGUE();
  PIPELINED_K_LOOP64(q + (size_t)t0 * NN, NN, q + (size_t)s0 * NN, NN, NN);
  const bool diag = (i == j);
  __syncthreads();
#pragma unroll
  for (int ii = 0; ii < 4; ++ii)
#pragma unroll
    for (int jj = 0; jj < 4; ++jj) {
      const int s = s0 + wc * 64 + jj * 16 + col16;
#pragma unroll
      for (int r = 0; r < 4; ++r) {
        const int lrow = wr * 64 + ii * 16 + quad * 4 + r;
        const int t = t0 + lrow;
        float v = acc[ii][jj][r];
        if (diag && s >= t) v = 0.f;
        smem[lrow * 128 + wc * 64 + jj * 16 + col16] = f2b(v);
      }
    }
  __syncthreads();
  copy_out128(smem, sb + ((size_t)z * TT + t0) * CH + j * 128, CH, tid);
}

// ---------------------------------------------------------------------------
// kB_all: each block owns a 64(d) x 128(n) tile of H, K=0..1536 fp32 acc,
// bf16 snapshot H16[z][c] at each chunk boundary.  BK=64 phases, vmcnt(6).
// ---------------------------------------------------------------------------
__global__ __launch_bounds__(256) void kB_all(
    const u16* __restrict__ xt16, const u16* __restrict__ qrt16,
    u16* __restrict__ h16, int bh0) {
  __shared__ __attribute__((aligned(16))) u16 sm[32768];
  u16* buf0 = sm;            // A0 +0, A1 +2048, B0 +4096, B1 +8192 (u16)
  u16* buf1 = sm + 12288;
  u16* snap = sm + 24576;    // 64x128 u16
  const int tid = threadIdx.x;
  const int w = tid >> 6, lane = tid & 63;
  const int m16 = lane & 15, quad = lane >> 4;
  const int z = blockIdx.z;
  const int bh = bh0 + z, b = bh / NHH;
  const int d0 = blockIdx.x * 64, n0 = blockIdx.y * 128;
  f32x4 acc[4][2];
#pragma unroll
  for (int i = 0; i < 4; ++i)
#pragma unroll
    for (int j = 0; j < 2; ++j) acc[i][j] = (f32x4){0.f, 0.f, 0.f, 0.f};
  const u16* Ab = xt16 + ((size_t)b * DD + d0) * TT;
  const u16* Bb = qrt16 + ((size_t)bh * NN + n0) * TT;
#define KB_STAGE(buf, k0)                                                   \
  {                                                                         \
    stage64x32(Ab + (k0), TT, (buf), tid);                                  \
    stage64x32(Ab + (k0) + 32, TT, (buf) + 2048, tid);                      \
    stage128x32(Bb + (k0), TT, (buf) + 4096, tid);                          \
    stage128x32(Bb + (k0) + 32, TT, (buf) + 8192, tid);                     \
  }
  for (int c = 0; c < 3; ++c) {
    const int kbase = c * CH;
    KB_STAGE(buf0, kbase);
    for (int s = 0; s < CH / 64; ++s) {
      u16* cb = (s & 1) ? buf1 : buf0;
      u16* nb = (s & 1) ? buf0 : buf1;
      if (s + 1 < CH / 64) {
        KB_STAGE(nb, kbase + (s + 1) * 64);
        asm volatile("s_waitcnt vmcnt(6)" ::: "memory");
      } else {
        asm volatile("s_waitcnt vmcnt(0)" ::: "memory");
      }
      __builtin_amdgcn_s_barrier();
      __builtin_amdgcn_sched_barrier(0);
#pragma unroll
      for (int half = 0; half < 2; ++half) {
        bf16x8 a[4], bb[2];
#pragma unroll
        for (int i = 0; i < 4; ++i) {
          const int row = i * 16 + m16;
          a[i] = *(const bf16x8*)&cb[half * 2048 + row * 32 +
                                     ((quad ^ KSWZ(row)) << 3)];
        }
#pragma unroll
        for (int j = 0; j < 2; ++j) {
          const int row = w * 32 + j * 16 + m16;
          bb[j] = *(const bf16x8*)&cb[4096 + half * 4096 + row * 32 +
                                      ((quad ^ KSWZ(row)) << 3)];
        }
#pragma unroll
        for (int i = 0; i < 4; ++i)
#pragma unroll
          for (int j = 0; j < 2; ++j)
            acc[i][j] = __builtin_amdgcn_mfma_f32_16x16x32_bf16(a[i], bb[j], acc[i][j], 0, 0, 0);
      }
      __builtin_amdgcn_sched_barrier(0);
      __builtin_amdgcn_s_barrier();
    }
    // snapshot H16[z][c]
#pragma unroll
    for (int i = 0; i < 4; ++i)
#pragma unroll
      for (int j = 0; j < 2; ++j)
#pragma unroll
        for (int r = 0; r < 4; ++r)
          snap[(i * 16 + quad * 4 + r) * 128 + w * 32 + j * 16 + m16] =
              f2b(acc[i][j][r]);
    __syncthreads();
    u16* hd = h16 + (size_t)(z * 3 + c) * DD * NN;
#pragma unroll
    for (int s4 = 0; s4 < 4; ++s4) {
      const int off = (s4 * 256 + tid) * 8;
      const int row = off >> 7, col = off & 127;
      *(u16x8*)&hd[(size_t)(d0 + row) * NN + n0 + col] = *(const u16x8*)&snap[off];
    }
    __syncthreads();
  }
#undef KB_STAGE
}

// ---------------------------------------------------------------------------
// kA: 128x128 output, unified panel-pipelined K sequence.
// 1D grid, bijective chunked XCD swizzle (T1) + LPT tt order.
// Fused stats: per-row {sum,sumsq} over this block's 128-col slice is
// shfl-reduced within the wave and stored NON-ATOMICALLY into
// PART[row*12 + dblk*2 + wc] (each slot written exactly once).
// ---------------------------------------------------------------------------
__device__ static const int TTORD[16] = {15, 11, 7, 14, 10, 6, 13, 9,
                                         5, 3, 12, 8, 4, 2, 1, 0};

__global__ __launch_bounds__(256) void kA_attn(
    const u16* __restrict__ qr16, const u16* __restrict__ h16,
    const u16* __restrict__ sb, const u16* __restrict__ xt16,
    u16* __restrict__ ykv16, float2* __restrict__ PART, int bh0) {
  __shared__ __attribute__((aligned(16))) u16 smem[32768];  // 2 x 32KB buffers
  const int tid = threadIdx.x;
  const int w = tid >> 6, lane = tid & 63;
  const int wr = w >> 1, wc = w & 1;
  const int col16 = lane & 15, quad = lane >> 4;
  const int nwg = gridDim.x;
  const int bid = blockIdx.x;
  const int qn = nwg >> 3, r8 = nwg & 7;
  const int xcd = bid & 7, pos = bid >> 3;
  const int wg = (xcd < r8 ? xcd * (qn + 1) : r8 * (qn + 1) + (xcd - r8) * qn) + pos;
  const int z = wg / 96;
  const int tt = TTORD[(wg / 6) & 15];       // LPT within chunk
  const int dblk = wg % 6;
  const int d0 = dblk * 128;
  const int bh = bh0 + z, b = bh / NHH;
  const int c = tt >> 2, it = tt & 3;
  const int t0 = tt * 128;
  f32x4 acc[4][4];
#pragma unroll
  for (int i = 0; i < 4; ++i)
#pragma unroll
    for (int j = 0; j < 4; ++j) acc[i][j] = (f32x4){0.f, 0.f, 0.f, 0.f};

  const int c4 = (c > 0) ? 4 : 0;
  const int nP = c4 + (it + 1) * 2;          // BK=64 panels total
  const u16* hs = h16 + ((size_t)(z * 3 + (c > 0 ? c - 1 : 0)) * DD + d0) * NN;
  const u16* qb = qr16 + ((size_t)bh * TT + t0) * NN;
  const u16* sbb = sb + ((size_t)z * TT + t0) * CH;
  const u16* xb = xt16 + ((size_t)b * DD + d0) * TT + c * CH;

#define KA_STAGE(buf, p)                                                  \
  {                                                                       \
    const u16 *pa_, *pb_; size_t la_, lb_;                                \
    if ((p) < c4) {                                                       \
      pa_ = qb + (p) * 64; la_ = NN;                                      \
      pb_ = hs + (p) * 64; lb_ = NN;                                      \
    } else {                                                              \
      const int q_ = (p) - c4;                                            \
      const int j_ = q_ >> 1, kk_ = (q_ & 1) << 6;                        \
      pa_ = sbb + j_ * 128 + kk_; la_ = CH;                               \
      pb_ = xb + j_ * 128 + kk_; lb_ = TT;                                \
    }                                                                     \
    stage128x32(pa_, la_, (buf), tid);                                    \
    stage128x32(pa_ + 32, la_, (buf) + 4096, tid);                        \
    stage128x32(pb_, lb_, (buf) + 8192, tid);                             \
    stage128x32(pb_ + 32, lb_, (buf) + 12288, tid);                       \
  }

  u16* bufA = smem;
  u16* bufB = smem + 16384;
  KA_STAGE(bufA, 0);
  for (int p = 0; p < nP; ++p) {
    u16* cb = (p & 1) ? bufB : bufA;
    u16* nb = (p & 1) ? bufA : bufB;
    if (p + 1 < nP) {
      KA_STAGE(nb, p + 1);
      asm volatile("s_waitcnt vmcnt(8)" ::: "memory");
    } else {
      asm volatile("s_waitcnt vmcnt(0)" ::: "memory");
    }
    __builtin_amdgcn_s_barrier();            // publish panel p across waves
    __builtin_amdgcn_sched_barrier(0);
    mfma_step(cb, cb + 8192, wr, wc, lane, acc);
    mfma_step(cb + 4096, cb + 12288, wr, wc, lane, acc);
    __builtin_amdgcn_sched_barrier(0);
    __builtin_amdgcn_s_barrier();            // reads of cb done before overwrite
  }
#undef KA_STAGE

  __syncthreads();
  float fsum[4][4], fsq[4][4];
#pragma unroll
  for (int i = 0; i < 4; ++i)
#pragma unroll
    for (int r = 0; r < 4; ++r) { fsum[i][r] = 0.f; fsq[i][r] = 0.f; }
#pragma unroll
  for (int i = 0; i < 4; ++i)
#pragma unroll
    for (int j = 0; j < 4; ++j)
#pragma unroll
      for (int r = 0; r < 4; ++r) {
        const int lrow = wr * 64 + i * 16 + quad * 4 + r;
        const u16 hv = f2b(acc[i][j][r]);
        smem[lrow * 128 + wc * 64 + j * 16 + col16] = hv;
        const float vr = b2f(hv);
        fsum[i][r] += vr;
        fsq[i][r] += vr * vr;
      }
  // col16-lane reduce; one non-atomic float2 store per row-half.
#pragma unroll
  for (int i = 0; i < 4; ++i)
#pragma unroll
    for (int r = 0; r < 4; ++r) {
      float s = fsum[i][r], q2 = fsq[i][r];
#pragma unroll
      for (int off = 1; off < 16; off <<= 1) {
        s += __shfl_xor(s, off);
        q2 += __shfl_xor(q2, off);
      }
      if (col16 == 0) {
        const int grow = z * TT + t0 + wr * 64 + i * 16 + quad * 4 + r;
        PART[grow * 12 + dblk * 2 + wc] = make_float2(s, q2);
      }
    }
  __syncthreads();
  copy_out128(smem, ykv16 + ((size_t)z * TT + t0) * DD + d0, DD, tid);
}

// ---------------------------------------------------------------------------
// k3r: fold the 12 per-block partials into mu/rs per row.  Reads 4.7MB
// (vs k3's 75MB re-read of ykv16).  One thread per row.
// ---------------------------------------------------------------------------
__global__ __launch_bounds__(256) void k3r_stats(
    const float2* __restrict__ PART, float* __restrict__ mu,
    float* __restrict__ rs) {
  const int row = blockIdx.x * 256 + threadIdx.x;
  const float2* pp = &PART[(size_t)row * 12];
  float s = 0.f, q = 0.f;
#pragma unroll
  for (int k = 0; k < 12; ++k) { s += pp[k].x; q += pp[k].y; }
  const float m = s * (1.f / 768.f);
  mu[row] = m;
  rs[row] = rsqrtf(q * (1.f / 768.f) - m * m + 1e-5f);
}

// ---------------------------------------------------------------------------
// K4: raw GEMM ykv16 @ ENCVT[h]^T with LN as epilogue affine (mu/rs from
// k3r); xs via inverse rope of QR16 (CS table), QR tile staged into LDS
// via coalesced async16; out2 = xs*ys; XY written in place into QR16.
// ---------------------------------------------------------------------------
__global__ __launch_bounds__(256) void k4_xy(
    const u16* __restrict__ ykv16, const u16* __restrict__ encvt,
    const float2* __restrict__ CS,
    u16* __restrict__ qrxy, const float* __restrict__ mu,
    const float* __restrict__ rs, const float* __restrict__ colsum,
    float* __restrict__ out2, int bh0) {
  const int z = blockIdx.z;
  const int bh = bh0 + z, h = bh % NHH;
  const int t0 = blockIdx.x * 128, n0 = blockIdx.y * 128;
  GEMM_PROLOGUE();
  PIPELINED_K_LOOP64(ykv16 + ((size_t)z * TT + t0) * DD, DD,
                     encvt + ((size_t)h * NN + n0) * DD, DD, DD);
  // stage the QR tile (128x128) into the upper 32KB, coalesced.
  {
    const u16* qg = qrxy + ((size_t)bh * TT + t0) * NN + n0;
#pragma unroll
    for (int s = 0; s < 8; ++s) {
      const int row = s * 16 + w * 4 + (lane >> 4);
      const int col = (lane & 15) * 8;
      async16(qg + (size_t)row * NN + col,
              smem + 16384 + (s * 256 + w * 64) * 8);
    }
  }
  asm volatile("s_waitcnt vmcnt(0)" ::: "memory");
  __syncthreads();
#pragma unroll
  for (int i = 0; i < 4; ++i) {
    float muv[4], rsv[4];
#pragma unroll
    for (int r = 0; r < 4; ++r) {
      const int grow = z * TT + t0 + wr * 64 + i * 16 + quad * 4 + r;
      muv[r] = mu[grow];
      rsv[r] = rs[grow];
    }
#pragma unroll
    for (int j = 0; j < 4; ++j) {
      const int lcol = wc * 64 + j * 16 + col16;
      const int n = n0 + lcol;
      const float csum = colsum[h * NN + n];
#pragma unroll
      for (int r = 0; r < 4; ++r) {
        const int lrow = wr * 64 + i * 16 + quad * 4 + r;
        const int t = t0 + lrow;
        const float ys = fmaxf(rsv[r] * acc[i][j][r] - rsv[r] * muv[r] * csum, 0.f);
        const unsigned pq =
            *(const unsigned*)&smem[16384 + lrow * 128 + (lcol & ~1)];
        const float lo = b2f((u16)pq), hi = b2f((u16)(pq >> 16));
        const float2 cs = CS[t * 128 + (n >> 1)];
        const float xs = (n & 1) ? (hi * cs.x - lo * cs.y)
                                 : (lo * cs.x + hi * cs.y);
        const float val = ys * xs;
        out2[((size_t)bh * TT + t) * NN + n] = val;
        smem[lrow * 128 + lcol] = f2b(val);
      }
    }
  }
  __syncthreads();
  copy_out128(smem, qrxy + ((size_t)bh * TT + t0) * NN + n0, NN, tid);
}

// ---------------------------------------------------------------------------
// K5: ymlp = flat(XY) @ DECT^T.  M=4096, N=768, K=3072.  64x64 tiles,
// BK=64, triple-buffered (2-deep prefetch, vmcnt(8)).
// ---------------------------------------------------------------------------
__global__ __launch_bounds__(256) void k5_mlp(
    const u16* __restrict__ xyq, const u16* __restrict__ dect,
    float* __restrict__ ymlp) {
  __shared__ __attribute__((aligned(16))) u16 sm[24576];
  const int tid = threadIdx.x;
  const int w = tid >> 6, lane = tid & 63;
  const int wr = w >> 1, wc = w & 1;
  const int m16 = lane & 15, quad = lane >> 4;
  const int m0 = blockIdx.x * 64, d0 = blockIdx.y * 64;
  f32x4 acc[2][2];
#pragma unroll
  for (int i = 0; i < 2; ++i)
#pragma unroll
    for (int j = 0; j < 2; ++j) acc[i][j] = (f32x4){0.f, 0.f, 0.f, 0.f};
  const int ar = w * 16 + (lane >> 2);      // A row within 64-tile
  const int m = m0 + ar;
  const int b = m >> 11, t = m & (TT - 1);
  const int kc = (((lane & 3) ^ KSWZ(ar)) << 3);   // source-swizzled chunk
#define K5_STAGE(buf, k0)                                                   \
  {                                                                         \
    const int hh_ = (k0) >> 8;                                              \
    const int kk_ = ((k0) & 255) + kc;                                      \
    const u16* ap_ = xyq + ((size_t)(b * NHH + hh_) * TT + t) * NN;         \
    async16(ap_ + kk_, (buf) + w * 512);                                    \
    async16(ap_ + kk_ + 32, (buf) + 2048 + w * 512);                        \
    stage64x32(dect + (size_t)d0 * (NHH * NN) + (k0), NHH * NN,             \
               (buf) + 4096, tid);                                          \
    stage64x32(dect + (size_t)d0 * (NHH * NN) + (k0) + 32, NHH * NN,        \
               (buf) + 6144, tid);                                          \
  }
  const int NK = (NHH * NN) / 64;           // 48 phases
  u16 *b0 = sm, *b1 = sm + 8192, *b2 = sm + 16384;
  K5_STAGE(b0, 0);
  K5_STAGE(b1, 64);
  for (int s = 0; s < NK; ++s) {
    if (s + 2 < NK) {
      K5_STAGE(b2, (s + 2) * 64);
      asm volatile("s_waitcnt vmcnt(8)" ::: "memory");
    } else if (s + 1 < NK) {
      asm volatile("s_waitcnt vmcnt(4)" ::: "memory");
    } else {
      asm volatile("s_waitcnt vmcnt(0)" ::: "memory");
    }
    __builtin_amdgcn_s_barrier();
    __builtin_amdgcn_sched_barrier(0);
#pragma unroll
    for (int half = 0; half < 2; ++half) {
      bf16x8 a[2], bb[2];
#pragma unroll
      for (int i = 0; i < 2; ++i) {
        const int row = wr * 32 + i * 16 + m16;
        a[i] = *(const bf16x8*)&b0[half * 2048 + row * 32 +
                                   ((quad ^ KSWZ(row)) << 3)];
      }
#pragma unroll
      for (int j = 0; j < 2; ++j) {
        const int row = wc * 32 + j * 16 + m16;
        bb[j] = *(const bf16x8*)&b0[4096 + half * 2048 + row * 32 +
                                    ((quad ^ KSWZ(row)) << 3)];
      }
#pragma unroll
      for (int i = 0; i < 2; ++i)
#pragma unroll
        for (int j = 0; j < 2; ++j)
          acc[i][j] = __builtin_amdgcn_mfma_f32_16x16x32_bf16(a[i], bb[j], acc[i][j], 0, 0, 0);
    }
    __builtin_amdgcn_sched_barrier(0);
    __builtin_amdgcn_s_barrier();
    u16* tmp = b0; b0 = b1; b1 = b2; b2 = tmp;
  }
#undef K5_STAGE
#pragma unroll
  for (int i = 0; i < 2; ++i)
#pragma unroll
    for (int j = 0; j < 2; ++j) {
      const int d = d0 + wc * 32 + j * 16 + m16;
#pragma unroll
      for (int r = 0; r < 4; ++r) {
        const int mm = m0 + wr * 32 + i * 16 + quad * 4 + r;
        ymlp[(size_t)mm * DD + d] = acc[i][j][r];
      }
    }
}

// ---------------------------------------------------------------------------
// K6: y = ln(ymlp)*sqrt(0.1/(ra+1e-6))*scale; out1 = ln(x+y). Block per row.
// ---------------------------------------------------------------------------
__global__ __launch_bounds__(256) void k6_final(
    const float* __restrict__ ymlp, const float* __restrict__ x,
    const float* __restrict__ scale, const float* __restrict__ ra,
    float* __restrict__ out1) {
  const int row = blockIdx.x;
  const int tid = threadIdx.x;
  const int wid = tid >> 6, lane = tid & 63;
  __shared__ float red[8];
  float v[3];
  float sum = 0.f, sq = 0.f;
#pragma unroll
  for (int j = 0; j < 3; ++j) {
    v[j] = ymlp[(size_t)row * DD + tid + j * 256];
    sum += v[j]; sq += v[j] * v[j];
  }
#pragma unroll
  for (int off = 32; off; off >>= 1) { sum += __shfl_xor(sum, off); sq += __shfl_xor(sq, off); }
  if (lane == 0) { red[wid] = sum; red[4 + wid] = sq; }
  __syncthreads();
  sum = red[0] + red[1] + red[2] + red[3];
  sq = red[4] + red[5] + red[6] + red[7];
  const float m1 = sum * (1.f / 768.f);
  const float r1 = rsqrtf(sq * (1.f / 768.f) - m1 * m1 + 1e-5f);
  float z[3];
  float sum2 = 0.f, sq2 = 0.f;
#pragma unroll
  for (int j = 0; j < 3; ++j) {
    const int d = tid + j * 256;
    float y = (v[j] - m1) * r1 * sqrtf(0.1f / (ra[d] + 1e-6f)) * scale[d];
    z[j] = x[(size_t)row * DD + d] + y;
    sum2 += z[j]; sq2 += z[j] * z[j];
  }
  __syncthreads();
#pragma unroll
  for (int off = 32; off; off >>= 1) { sum2 += __shfl_xor(sum2, off); sq2 += __shfl_xor(sq2, off); }
  if (lane == 0) { red[wid] = sum2; red[4 + wid] = sq2; }
  __syncthreads();
  sum2 = red[0] + red[1] + red[2] + red[3];
  sq2 = red[4] + red[5] + red[6] + red[7];
  const float m2 = sum2 * (1.f / 768.f);
  const float r2 = rsqrtf(sq2 * (1.f / 768.f) - m2 * m2 + 1e-5f);
#pragma unroll
  for (int j = 0; j < 3; ++j)
    out1[(size_t)row * DD + tid + j * 256] = (z[j] - m2) * r2;
}

// ---------------------------------------------------------------------------
extern "C" void kernel_launch(void* const* d_in, const int* in_sizes, int n_in,
                              void* d_out, int out_size, void* d_ws, size_t ws_size,
                              hipStream_t stream) {
  const float* x = (const float*)d_in[0];
  const float* enc = (const float*)d_in[1];
  const float* encv = (const float*)d_in[2];
  const float* dec = (const float*)d_in[3];
  const float* scale = (const float*)d_in[4];
  const float* ra = (const float*)d_in[5];
  float* out1 = (float*)d_out;
  float* out2 = out1 + (size_t)BB * TT * DD;
  float* ymlp = out1;                         // k5 scratch, k6 in-place

  const int NS = BB * NHH;  // 24 slices
  unsigned char* p = (unsigned char*)d_ws;
  u16* X16 = (u16*)p;    p += (size_t)BB * TT * DD * 2;
  u16* XT16 = (u16*)p;   p += (size_t)BB * DD * TT * 2;
  u16* ENCT = (u16*)p;   p += (size_t)NHH * NN * DD * 2;
  u16* ENCVT = (u16*)p;  p += (size_t)NHH * NN * DD * 2;
  u16* DECT = (u16*)p;   p += (size_t)DD * NHH * NN * 2;
  u16* QR16 = (u16*)p;   p += (size_t)NS * TT * NN * 2;   // holds QR, then XY
  u16* QRT16 = (u16*)p;  p += (size_t)NS * NN * TT * 2;
  float* COLSUM = (float*)p; p += (size_t)NHH * NN * 4;
  float2* CS = (float2*)p;   p += (size_t)TT * (NN / 2) * sizeof(float2);
  // Per-slice pool: SB + H16 + YKV16 + PART(96B/row) + MU/RS(8B/row)
  const size_t SLICE_B = (size_t)TT * CH * 2 + 3 * (size_t)DD * NN * 2 +
                         (size_t)TT * DD * 2 + (size_t)TT * 104;
  size_t fixed = (size_t)(p - (unsigned char*)d_ws);
  size_t rem = (ws_size > fixed) ? ws_size - fixed : 0;
  int GSmax = (int)(rem / SLICE_B);
  if (GSmax < 1) GSmax = 1;
  if (GSmax > NS) GSmax = NS;
  const int ngrp = (NS + GSmax - 1) / GSmax;
  const int GS = (NS + ngrp - 1) / ngrp;     // balanced groups
  u16* SB = (u16*)p;     p += (size_t)GS * TT * CH * 2;
  u16* H16 = (u16*)p;    p += (size_t)GS * 3 * DD * NN * 2;
  u16* YKV16 = (u16*)p;  p += (size_t)GS * TT * DD * 2;
  float2* PART = (float2*)p; p += (size_t)GS * TT * 12 * sizeof(float2);
  float* MU = (float*)p; p += (size_t)GS * TT * 4;
  float* RS = (float*)p; p += (size_t)GS * TT * 4;

  // One-time conversions / transposes
  cvt_bf16<<<dim3((BB * TT * DD) / 1024), 256, 0, stream>>>(x, X16, (size_t)BB * TT * DD / 4);
  tcvt_bf16<<<dim3(DD / 32, TT / 32, BB), 256, 0, stream>>>(
      x, XT16, TT, DD, (size_t)TT * DD, (size_t)DD * TT);
  tcvt_bf16<<<dim3(NN / 32, DD / 32, NHH), 256, 0, stream>>>(
      enc, ENCT, DD, NN, (size_t)DD * NN, (size_t)NN * DD);
  tcvt_bf16<<<dim3(NN / 32, DD / 32, NHH), 256, 0, stream>>>(
      encv, ENCVT, DD, NN, (size_t)DD * NN, (size_t)NN * DD);
  tcvt_bf16<<<dim3(DD / 32, (NHH * NN) / 32, 1), 256, 0, stream>>>(
      dec, DECT, NHH * NN, DD, 0, 0);
  k_colsum<<<dim3(NHH * NN / 4), 256, 0, stream>>>(ENCVT, COLSUM);
  k_cstab<<<dim3(TT * (NN / 2) / 256), 256, 0, stream>>>(CS);

  k1_encode<<<dim3(BB * TT / 128, NN / 128, NHH), 256, 0, stream>>>(
      X16, ENCT, CS, QR16, QRT16);

  for (int bh0 = 0; bh0 < NS; bh0 += GS) {
    const int gs = imin(GS, NS - bh0);
    kS_band<<<dim3(40, gs), 256, 0, stream>>>(QR16, SB, bh0);
    kB_all<<<dim3(DD / 64, NN / 128, gs), 256, 0, stream>>>(
        XT16, QRT16, H16, bh0);
    kA_attn<<<dim3(96 * gs), 256, 0, stream>>>(
        QR16, H16, SB, XT16, YKV16, PART, bh0);
    k3r_stats<<<dim3(gs * TT / 256), 256, 0, stream>>>(PART, MU, RS);
    k4_xy<<<dim3(TT / 128, NN / 128, gs), 256, 0, stream>>>(
        YKV16, ENCVT, CS, QR16, MU, RS, COLSUM, out2, bh0);
  }

  k5_mlp<<<dim3(BB * TT / 64, DD / 64), 256, 0, stream>>>(QR16, DECT, ymlp);
  k6_final<<<dim3(BB * TT), 256, 0, stream>>>(ymlp, x, scale, ra, out1);
}

// Round 7
// 356.184 us; speedup vs baseline: 1.0707x; 1.0632x over previous
//
#include <hip/hip_runtime.h>
#include <math.h>

#define TT 2048
#define DD 768
#define NN 256
#define NHH 12
#define BB 2
#define CH 512           // attention chunk (4 chunks of 4 x 128-tiles)

typedef unsigned short u16;
typedef __attribute__((ext_vector_type(8))) short bf16x8;
typedef __attribute__((ext_vector_type(8))) unsigned short u16x8;
typedef __attribute__((ext_vector_type(4))) float f32x4;

static inline int imin(int a, int b) { return a < b ? a : b; }

__device__ __forceinline__ u16 f2b(float f) {
  union { float f; unsigned u; } a; a.f = f;
  unsigned r = a.u + 0x7FFF + ((a.u >> 16) & 1);
  return (u16)(r >> 16);
}
__device__ __forceinline__ float b2f(u16 h) {
  union { unsigned u; float f; } a; a.u = ((unsigned)h) << 16;
  return a.f;
}

__device__ __forceinline__ void async16(const void* g, void* l) {
  __builtin_amdgcn_global_load_lds(
      (const __attribute__((address_space(1))) unsigned*)g,
      (__attribute__((address_space(3))) unsigned*)l, 16, 0, 0);
}

// K-chunk XOR swizzle: LDS stays linear; the global SOURCE chunk is
// pre-swizzled at stage time and the SAME XOR is applied on every
// fragment read.  chunk' = chunk ^ ((row>>1)&3) gives 2-way bank
// aliasing on ds_read_b128 (free) vs 8-way unswizzled.
#define KSWZ(row) (((row) >> 1) & 3)

// Stage a 128x32 bf16 tile (row-major, ld in elements) into LDS [128][32],
// source-swizzled.
__device__ __forceinline__ void stage128x32(
    const u16* __restrict__ gbase, size_t ld, u16* lds, int tid) {
  const int w = tid >> 6, l = tid & 63;
#pragma unroll
  for (int q = 0; q < 2; ++q) {
    const int row = w * 32 + q * 16 + (l >> 2);
    const int kc = ((l & 3) ^ KSWZ(row)) << 3;
    async16(gbase + (size_t)row * ld + kc, lds + (w * 32 + q * 16) * 32);
  }
}

// Stage a 64x32 bf16 tile into LDS [64][32], source-swizzled.
__device__ __forceinline__ void stage64x32(
    const u16* __restrict__ gbase, size_t ld, u16* lds, int tid) {
  const int w = tid >> 6, l = tid & 63;
  const int row = w * 16 + (l >> 2);
  const int kc = ((l & 3) ^ KSWZ(row)) << 3;
  async16(gbase + (size_t)row * ld + kc, lds + w * 512);
}

// 16 MFMAs of one BK=32 step; wave (wr,wc) computes 64x64 of the 128x128
// tile.  Fragment reads apply the chunk swizzle.
__device__ __forceinline__ void mfma_step(
    const u16* As, const u16* Bs, int wr, int wc, int lane, f32x4 acc[4][4]) {
  const int m16 = lane & 15, quad = lane >> 4;
  bf16x8 a[4], b[4];
#pragma unroll
  for (int i = 0; i < 4; ++i) {
    const int row = wr * 64 + i * 16 + m16;
    a[i] = *(const bf16x8*)&As[row * 32 + ((quad ^ KSWZ(row)) << 3)];
  }
#pragma unroll
  for (int j = 0; j < 4; ++j) {
    const int row = wc * 64 + j * 16 + m16;
    b[j] = *(const bf16x8*)&Bs[row * 32 + ((quad ^ KSWZ(row)) << 3)];
  }
#pragma unroll
  for (int i = 0; i < 4; ++i)
#pragma unroll
    for (int j = 0; j < 4; ++j)
      acc[i][j] = __builtin_amdgcn_mfma_f32_16x16x32_bf16(a[i], b[j], acc[i][j], 0, 0, 0);
}

// copy a full 128x128 u16 tile from LDS (row-major) to global rows of ld.
__device__ __forceinline__ void copy_out128(
    const u16* buf, u16* g, size_t ld, int tid) {
#pragma unroll
  for (int s = 0; s < 8; ++s) {
    const int off = (s * 256 + tid) * 8;
    const int row = off >> 7, col = off & 127;
    *(u16x8*)&g[(size_t)row * ld + col] = *(const u16x8*)&buf[off];
  }
}

#define GEMM_PROLOGUE()                                            \
  __shared__ __attribute__((aligned(16))) u16 smem[32768];         \
  const int tid = threadIdx.x;                                     \
  const int w = tid >> 6, lane = tid & 63;                         \
  const int wr = w >> 1, wc = w & 1;                               \
  const int col16 = lane & 15, quad = lane >> 4;                   \
  f32x4 acc[4][4];                                                 \
  _Pragma("unroll") for (int i = 0; i < 4; ++i)                    \
  _Pragma("unroll") for (int j = 0; j < 4; ++j)                    \
      acc[i][j] = (f32x4){0.f, 0.f, 0.f, 0.f};

// Double-buffered, counted-vmcnt pipelined K loop, BK=64:
// 32 MFMA per barrier-pair, 8 async16/thread/phase, vmcnt(8).
#define PIPELINED_K_LOOP64(ABASE, ALD, BBASE, BLD, KTOT)                    \
  {                                                                         \
    stage128x32((ABASE), (ALD), smem, tid);                                 \
    stage128x32((ABASE) + 32, (ALD), smem + 4096, tid);                     \
    stage128x32((BBASE), (BLD), smem + 8192, tid);                          \
    stage128x32((BBASE) + 32, (BLD), smem + 12288, tid);                    \
    const int np_ = (KTOT) / 64;                                            \
    for (int pp_ = 0; pp_ < np_; ++pp_) {                                   \
      u16* cb_ = (pp_ & 1) ? smem + 16384 : smem;                           \
      u16* nb_ = (pp_ & 1) ? smem : smem + 16384;                           \
      if (pp_ + 1 < np_) {                                                  \
        const int kn_ = (pp_ + 1) * 64;                                     \
        stage128x32((ABASE) + kn_, (ALD), nb_, tid);                        \
        stage128x32((ABASE) + kn_ + 32, (ALD), nb_ + 4096, tid);            \
        stage128x32((BBASE) + kn_, (BLD), nb_ + 8192, tid);                 \
        stage128x32((BBASE) + kn_ + 32, (BLD), nb_ + 12288, tid);           \
        asm volatile("s_waitcnt vmcnt(8)" ::: "memory");                    \
      } else {                                                              \
        asm volatile("s_waitcnt vmcnt(0)" ::: "memory");                    \
      }                                                                     \
      __builtin_amdgcn_s_barrier();                                         \
      __builtin_amdgcn_sched_barrier(0);                                    \
      mfma_step(cb_, cb_ + 8192, wr, wc, lane, acc);                        \
      mfma_step(cb_ + 4096, cb_ + 12288, wr, wc, lane, acc);                \
      __builtin_amdgcn_sched_barrier(0);                                    \
      __builtin_amdgcn_s_barrier();                                         \
    }                                                                       \
  }

// ---------------------------------------------------------------------------
// tcvt body: transpose-convert a 32x32 fp32 tile to bf16.
// ---------------------------------------------------------------------------
__device__ __forceinline__ void tcvt_body(
    const float* __restrict__ ip, u16* __restrict__ op, int R, int C,
    int bx, int by, int tid, float (*tile)[33]) {
  const int c0 = bx * 32, r0 = by * 32;
  const int tx = tid & 31, ty = tid >> 5;
#pragma unroll
  for (int p = 0; p < 4; ++p)
    tile[ty + p * 8][tx] = ip[(size_t)(r0 + ty + p * 8) * C + c0 + tx];
  __syncthreads();
#pragma unroll
  for (int p = 0; p < 4; ++p)
    op[(size_t)(c0 + ty + p * 8) * R + r0 + tx] = f2b(tile[tx][ty + p * 8]);
}

// ---------------------------------------------------------------------------
// k_prep: ALL one-time conversions fused into one launch (role-switched on
// blockIdx ranges; every block is branch-uniform).  Saves 5 launch gaps.
//   [0,3072):      x -> X16 (bf16 copy)
//   [3072,6144):   x^T -> XT16 (per batch)
//   [6144,8448):   enc^T -> ENCT (per head)
//   [8448,10752):  encv^T -> ENCVT (per head)
//   [10752,13056): dec^T -> DECT
//   [13056,14080): rope cos/sin table CS (bit-identical to inline math)
// ---------------------------------------------------------------------------
__global__ __launch_bounds__(256) void k_prep(
    const float* __restrict__ x, u16* __restrict__ X16, u16* __restrict__ XT16,
    const float* __restrict__ enc, u16* __restrict__ ENCT,
    const float* __restrict__ encv, u16* __restrict__ ENCVT,
    const float* __restrict__ dec, u16* __restrict__ DECT,
    float2* __restrict__ CS) {
  __shared__ float tile[32][33];
  const int tid = threadIdx.x;
  const int bid = blockIdx.x;
  if (bid < 3072) {
    const size_t i = ((size_t)bid * 256 + tid) * 4;
    float4 v = *(const float4*)&x[i];
    u16 o[4] = {f2b(v.x), f2b(v.y), f2b(v.z), f2b(v.w)};
    *(ushort4*)&X16[i] = *(ushort4*)o;
  } else if (bid < 6144) {
    const int b = bid - 3072;
    const int bz = b / 1536, rb = b % 1536;
    tcvt_body(x + (size_t)bz * TT * DD, XT16 + (size_t)bz * DD * TT,
              TT, DD, rb % 24, rb / 24, tid, tile);
  } else if (bid < 8448) {
    const int b = bid - 6144;
    const int bz = b / 192, rb = b % 192;
    tcvt_body(enc + (size_t)bz * DD * NN, ENCT + (size_t)bz * NN * DD,
              DD, NN, rb % 8, rb / 8, tid, tile);
  } else if (bid < 10752) {
    const int b = bid - 8448;
    const int bz = b / 192, rb = b % 192;
    tcvt_body(encv + (size_t)bz * DD * NN, ENCVT + (size_t)bz * NN * DD,
              DD, NN, rb % 8, rb / 8, tid, tile);
  } else if (bid < 13056) {
    const int b = bid - 10752;
    tcvt_body(dec, DECT, NHH * NN, DD, b % 24, b / 24, tid, tile);
  } else {
    const int idx = (bid - 13056) * 256 + tid;   // t*128 + n2
    const int t = idx >> 7, n2 = idx & 127;
    const float freq = exp2f((float)(2 * n2) * -0.0625f) * 0.15915494309189535f;
    const float phase = (float)t * freq;
    const float ph = (phase - floorf(phase)) * 6.283185307179586f;
    CS[idx] = make_float2(__cosf(ph), __sinf(ph));
  }
}

__global__ __launch_bounds__(256) void k_colsum(
    const u16* __restrict__ encvt, float* __restrict__ colsum) {
  const int row = blockIdx.x * 4 + (threadIdx.x >> 6);
  const int lane = threadIdx.x & 63;
  const u16* pr = encvt + (size_t)row * DD;
  float s = 0.f;
#pragma unroll
  for (int i = 0; i < 3; ++i) {
    ushort4 v = *(const ushort4*)&pr[(lane << 2) + i * 256];
    s += b2f(v.x) + b2f(v.y) + b2f(v.z) + b2f(v.w);
  }
#pragma unroll
  for (int off = 32; off; off >>= 1) s += __shfl_xor(s, off);
  if (lane == 0) colsum[row] = s;
}

// ---------------------------------------------------------------------------
// K1: latent = X16 @ ENCT[h]^T; relu; rope -> QR16 [b][h][t][n] AND
// QRT16 [b][h][n][t].  BK=64 pipeline; XOR-swizzled epilogue tile for the
// QRT column read.
// ---------------------------------------------------------------------------
__device__ __forceinline__ int swz8(int row) { return ((row >> 3) & 7) << 3; }

__global__ __launch_bounds__(256) void k1_encode(
    const u16* __restrict__ x16, const u16* __restrict__ enct,
    const float2* __restrict__ CS,
    u16* __restrict__ qr16, u16* __restrict__ qrt16) {
  const int h = blockIdx.z;
  const int m0 = blockIdx.x * 128, n0 = blockIdx.y * 128;
  GEMM_PROLOGUE();
  PIPELINED_K_LOOP64(x16 + (size_t)m0 * DD, DD,
                     enct + ((size_t)h * NN + n0) * DD, DD, DD);
  __syncthreads();
#pragma unroll
  for (int i = 0; i < 4; ++i)
#pragma unroll
    for (int j = 0; j < 4; ++j) {
      const int n = n0 + wc * 64 + j * 16 + col16;
      float rv[4], pv[4];
#pragma unroll
      for (int r = 0; r < 4; ++r) rv[r] = fmaxf(acc[i][j][r], 0.f);
#pragma unroll
      for (int r = 0; r < 4; ++r) pv[r] = __shfl_xor(rv[r], 1);
#pragma unroll
      for (int r = 0; r < 4; ++r) {
        const int lrow = wr * 64 + i * 16 + quad * 4 + r;
        const int t = (m0 + lrow) & (TT - 1);
        const float2 cs = CS[t * 128 + (n >> 1)];
        const float o = (n & 1) ? (rv[r] * cs.x + pv[r] * cs.y)
                                : (rv[r] * cs.x - pv[r] * cs.y);
        smem[lrow * 128 + ((wc * 64 + j * 16 + col16) ^ swz8(lrow))] = f2b(o);
      }
    }
  __syncthreads();
  const int bq = m0 >> 11, tb = m0 & (TT - 1);
  const size_t sl = (size_t)(bq * NHH + h);
  // row-major copy (swizzle-aware source)
  u16* qg = qr16 + (sl * TT + tb) * NN + n0;
#pragma unroll
  for (int s = 0; s < 8; ++s) {
    const int off = (s * 256 + tid) * 8;
    const int row = off >> 7, col = off & 127;
    *(u16x8*)&qg[(size_t)row * NN + col] =
        *(const u16x8*)&smem[row * 128 + (col ^ swz8(row))];
  }
  // transposed copy: QRT16[sl][n][t] = tile[t][n]
#pragma unroll
  for (int s = 0; s < 8; ++s) {
    const int off = (s * 256 + tid) * 8;
    const int nr = off >> 7, tc = off & 127;
    const int sw = swz8(tc);                 // tc 8-aligned: same for tc..tc+7
    u16 vals[8];
#pragma unroll
    for (int k = 0; k < 8; ++k) vals[k] = smem[(tc + k) * 128 + (nr ^ sw)];
    *(u16x8*)&qrt16[(sl * NN + n0 + nr) * TT + tb + tc] = *(u16x8*)vals;
  }
}

// ---------------------------------------------------------------------------
// kS: block-diagonal band of S = QR QR^T (strict lower), 40 tiles/slice.
// ---------------------------------------------------------------------------
__global__ __launch_bounds__(256) void kS_band(
    const u16* __restrict__ qr16, u16* __restrict__ sb, int bh0) {
  const int z = blockIdx.y;                  // group-local slice
  const int bh = bh0 + z;
  const int cc = blockIdx.x / 10, rr = blockIdx.x % 10;
  int i = (int)((sqrtf(8.f * rr + 1.f) - 1.f) * 0.5f);
  while ((i + 1) * (i + 2) / 2 <= rr) ++i;
  while (i * (i + 1) / 2 > rr) --i;
  const int j = rr - i * (i + 1) / 2;
  const int t0 = (cc * 4 + i) * 128;
  const int s0 = cc * CH + j * 128;
  const u16* q = qr16 + (size_t)bh * TT * NN;
  GEMM_PROLOGUE();
  PIPELINED_K_LOOP64(q + (size_t)t0 * NN, NN, q + (size_t)s0 * NN, NN, NN);
  const bool diag = (i == j);
  __syncthreads();
#pragma unroll
  for (int ii = 0; ii < 4; ++ii)
#pragma unroll
    for (int jj = 0; jj < 4; ++jj) {
      const int s = s0 + wc * 64 + jj * 16 + col16;
#pragma unroll
      for (int r = 0; r < 4; ++r) {
        const int lrow = wr * 64 + ii * 16 + quad * 4 + r;
        const int t = t0 + lrow;
        float v = acc[ii][jj][r];
        if (diag && s >= t) v = 0.f;
        smem[lrow * 128 + wc * 64 + jj * 16 + col16] = f2b(v);
      }
    }
  __syncthreads();
  copy_out128(smem, sb + ((size_t)z * TT + t0) * CH + j * 128, CH, tid);
}

// ---------------------------------------------------------------------------
// kB_all: each block owns a 64(d) x 128(n) tile of H, K=0..1536 fp32 acc,
// bf16 snapshot H16[z][c] at each chunk boundary.  BK=64 phases, vmcnt(6).
// ---------------------------------------------------------------------------
__global__ __launch_bounds__(256) void kB_all(
    const u16* __restrict__ xt16, const u16* __restrict__ qrt16,
    u16* __restrict__ h16, int bh0) {
  __shared__ __attribute__((aligned(16))) u16 sm[32768];
  u16* buf0 = sm;            // A0 +0, A1 +2048, B0 +4096, B1 +8192 (u16)
  u16* buf1 = sm + 12288;
  u16* snap = sm + 24576;    // 64x128 u16
  const int tid = threadIdx.x;
  const int w = tid >> 6, lane = tid & 63;
  const int m16 = lane & 15, quad = lane >> 4;
  const int z = blockIdx.z;
  const int bh = bh0 + z, b = bh / NHH;
  const int d0 = blockIdx.x * 64, n0 = blockIdx.y * 128;
  f32x4 acc[4][2];
#pragma unroll
  for (int i = 0; i < 4; ++i)
#pragma unroll
    for (int j = 0; j < 2; ++j) acc[i][j] = (f32x4){0.f, 0.f, 0.f, 0.f};
  const u16* Ab = xt16 + ((size_t)b * DD + d0) * TT;
  const u16* Bb = qrt16 + ((size_t)bh * NN + n0) * TT;
#define KB_STAGE(buf, k0)                                                   \
  {                                                                         \
    stage64x32(Ab + (k0), TT, (buf), tid);                                  \
    stage64x32(Ab + (k0) + 32, TT, (buf) + 2048, tid);                      \
    stage128x32(Bb + (k0), TT, (buf) + 4096, tid);                          \
    stage128x32(Bb + (k0) + 32, TT, (buf) + 8192, tid);                     \
  }
  for (int c = 0; c < 3; ++c) {
    const int kbase = c * CH;
    KB_STAGE(buf0, kbase);
    for (int s = 0; s < CH / 64; ++s) {
      u16* cb = (s & 1) ? buf1 : buf0;
      u16* nb = (s & 1) ? buf0 : buf1;
      if (s + 1 < CH / 64) {
        KB_STAGE(nb, kbase + (s + 1) * 64);
        asm volatile("s_waitcnt vmcnt(6)" ::: "memory");
      } else {
        asm volatile("s_waitcnt vmcnt(0)" ::: "memory");
      }
      __builtin_amdgcn_s_barrier();
      __builtin_amdgcn_sched_barrier(0);
#pragma unroll
      for (int half = 0; half < 2; ++half) {
        bf16x8 a[4], bb[2];
#pragma unroll
        for (int i = 0; i < 4; ++i) {
          const int row = i * 16 + m16;
          a[i] = *(const bf16x8*)&cb[half * 2048 + row * 32 +
                                     ((quad ^ KSWZ(row)) << 3)];
        }
#pragma unroll
        for (int j = 0; j < 2; ++j) {
          const int row = w * 32 + j * 16 + m16;
          bb[j] = *(const bf16x8*)&cb[4096 + half * 4096 + row * 32 +
                                      ((quad ^ KSWZ(row)) << 3)];
        }
#pragma unroll
        for (int i = 0; i < 4; ++i)
#pragma unroll
          for (int j = 0; j < 2; ++j)
            acc[i][j] = __builtin_amdgcn_mfma_f32_16x16x32_bf16(a[i], bb[j], acc[i][j], 0, 0, 0);
      }
      __builtin_amdgcn_sched_barrier(0);
      __builtin_amdgcn_s_barrier();
    }
    // snapshot H16[z][c]
#pragma unroll
    for (int i = 0; i < 4; ++i)
#pragma unroll
      for (int j = 0; j < 2; ++j)
#pragma unroll
        for (int r = 0; r < 4; ++r)
          snap[(i * 16 + quad * 4 + r) * 128 + w * 32 + j * 16 + m16] =
              f2b(acc[i][j][r]);
    __syncthreads();
    u16* hd = h16 + (size_t)(z * 3 + c) * DD * NN;
#pragma unroll
    for (int s4 = 0; s4 < 4; ++s4) {
      const int off = (s4 * 256 + tid) * 8;
      const int row = off >> 7, col = off & 127;
      *(u16x8*)&hd[(size_t)(d0 + row) * NN + n0 + col] = *(const u16x8*)&snap[off];
    }
    __syncthreads();
  }
#undef KB_STAGE
}

// ---------------------------------------------------------------------------
// kA: 128x128 output, unified panel-pipelined K sequence.
// 1D grid, bijective chunked XCD swizzle (T1) + LPT tt order.
// Fused stats v3: Σ/Σ² accumulated DURING the copy-out pass (rides the
// existing register stream), per-chunk partials staged in padded LDS
// scratch, then ONE coalesced dblk-major float2 store per row — no
// atomics, no ds_bpermute, no partial cachelines.
// ---------------------------------------------------------------------------
__device__ static const int TTORD[16] = {15, 11, 7, 14, 10, 6, 13, 9,
                                         5, 3, 12, 8, 4, 2, 1, 0};

__global__ __launch_bounds__(256) void kA_attn(
    const u16* __restrict__ qr16, const u16* __restrict__ h16,
    const u16* __restrict__ sb, const u16* __restrict__ xt16,
    u16* __restrict__ ykv16, float2* __restrict__ PART, int gsTT, int bh0) {
  __shared__ __attribute__((aligned(16))) u16 smem[32768];  // 2 x 32KB buffers
  const int tid = threadIdx.x;
  const int w = tid >> 6, lane = tid & 63;
  const int wr = w >> 1, wc = w & 1;
  const int col16 = lane & 15, quad = lane >> 4;
  const int nwg = gridDim.x;
  const int bid = blockIdx.x;
  const int qn = nwg >> 3, r8 = nwg & 7;
  const int xcd = bid & 7, pos = bid >> 3;
  const int wg = (xcd < r8 ? xcd * (qn + 1) : r8 * (qn + 1) + (xcd - r8) * qn) + pos;
  const int z = wg / 96;
  const int tt = TTORD[(wg / 6) & 15];       // LPT within chunk
  const int dblk = wg % 6;
  const int d0 = dblk * 128;
  const int bh = bh0 + z, b = bh / NHH;
  const int c = tt >> 2, it = tt & 3;
  const int t0 = tt * 128;
  f32x4 acc[4][4];
#pragma unroll
  for (int i = 0; i < 4; ++i)
#pragma unroll
    for (int j = 0; j < 4; ++j) acc[i][j] = (f32x4){0.f, 0.f, 0.f, 0.f};

  const int c4 = (c > 0) ? 4 : 0;
  const int nP = c4 + (it + 1) * 2;          // BK=64 panels total
  const u16* hs = h16 + ((size_t)(z * 3 + (c > 0 ? c - 1 : 0)) * DD + d0) * NN;
  const u16* qb = qr16 + ((size_t)bh * TT + t0) * NN;
  const u16* sbb = sb + ((size_t)z * TT + t0) * CH;
  const u16* xb = xt16 + ((size_t)b * DD + d0) * TT + c * CH;

#define KA_STAGE(buf, p)                                                  \
  {                                                                       \
    const u16 *pa_, *pb_; size_t la_, lb_;                                \
    if ((p) < c4) {                                                       \
      pa_ = qb + (p) * 64; la_ = NN;                                      \
      pb_ = hs + (p) * 64; lb_ = NN;                                      \
    } else {                                                              \
      const int q_ = (p) - c4;                                            \
      const int j_ = q_ >> 1, kk_ = (q_ & 1) << 6;                        \
      pa_ = sbb + j_ * 128 + kk_; la_ = CH;                               \
      pb_ = xb + j_ * 128 + kk_; lb_ = TT;                                \
    }                                                                     \
    stage128x32(pa_, la_, (buf), tid);                                    \
    stage128x32(pa_ + 32, la_, (buf) + 4096, tid);                        \
    stage128x32(pb_, lb_, (buf) + 8192, tid);                             \
    stage128x32(pb_ + 32, lb_, (buf) + 12288, tid);                       \
  }

  u16* bufA = smem;
  u16* bufB = smem + 16384;
  KA_STAGE(bufA, 0);
  for (int p = 0; p < nP; ++p) {
    u16* cb = (p & 1) ? bufB : bufA;
    u16* nb = (p & 1) ? bufA : bufB;
    if (p + 1 < nP) {
      KA_STAGE(nb, p + 1);
      asm volatile("s_waitcnt vmcnt(8)" ::: "memory");
    } else {
      asm volatile("s_waitcnt vmcnt(0)" ::: "memory");
    }
    __builtin_amdgcn_s_barrier();            // publish panel p across waves
    __builtin_amdgcn_sched_barrier(0);
    mfma_step(cb, cb + 8192, wr, wc, lane, acc);
    mfma_step(cb + 4096, cb + 12288, wr, wc, lane, acc);
    __builtin_amdgcn_sched_barrier(0);
    __builtin_amdgcn_s_barrier();            // reads of cb done before overwrite
  }
#undef KA_STAGE

  __syncthreads();
#pragma unroll
  for (int i = 0; i < 4; ++i)
#pragma unroll
    for (int j = 0; j < 4; ++j)
#pragma unroll
      for (int r = 0; r < 4; ++r) {
        const int lrow = wr * 64 + i * 16 + quad * 4 + r;
        smem[lrow * 128 + wc * 64 + j * 16 + col16] = f2b(acc[i][j][r]);
      }
  __syncthreads();
  // copy-out + per-chunk stats.  Thread handles chunk (s*256+tid):
  // row = 16s + (tid>>4), within-row chunk = tid&15 -> unique scratch slot.
  float2* scratch = (float2*)&smem[16384];   // [128][17] padded, 17.4KB
  u16* yg = ykv16 + ((size_t)z * TT + t0) * DD + d0;
#pragma unroll
  for (int s = 0; s < 8; ++s) {
    const int off = (s * 256 + tid) * 8;
    const int row = off >> 7, col = off & 127;
    const u16x8 v = *(const u16x8*)&smem[off];
    *(u16x8*)&yg[(size_t)row * DD + col] = v;
    float ps = 0.f, pq = 0.f;
#pragma unroll
    for (int k = 0; k < 8; ++k) {
      const float f = b2f(v[k]);
      ps += f;
      pq += f * f;
    }
    scratch[row * 17 + (tid & 15)] = make_float2(ps, pq);
  }
  __syncthreads();
  if (tid < 128) {
    const float2* pr = &scratch[tid * 17];
    float s = 0.f, q2 = 0.f;
#pragma unroll
    for (int k = 0; k < 16; ++k) { s += pr[k].x; q2 += pr[k].y; }
    PART[(size_t)dblk * gsTT + z * TT + t0 + tid] = make_float2(s, q2);
  }
}

// ---------------------------------------------------------------------------
// k3r: fold the 6 dblk-major partials into mu/rs per row (reads 2.4MB,
// fully coalesced).  One thread per row.
// ---------------------------------------------------------------------------
__global__ __launch_bounds__(256) void k3r_stats(
    const float2* __restrict__ PART, float* __restrict__ mu,
    float* __restrict__ rs, int gsTT) {
  const int row = blockIdx.x * 256 + threadIdx.x;
  float s = 0.f, q = 0.f;
#pragma unroll
  for (int d = 0; d < 6; ++d) {
    const float2 p2 = PART[(size_t)d * gsTT + row];
    s += p2.x;
    q += p2.y;
  }
  const float m = s * (1.f / 768.f);
  mu[row] = m;
  rs[row] = rsqrtf(q * (1.f / 768.f) - m * m + 1e-5f);
}

// ---------------------------------------------------------------------------
// K4: raw GEMM ykv16 @ ENCVT[h]^T with LN as epilogue affine (mu/rs from
// k3r); xs via inverse rope of QR16 (CS table), QR tile staged into LDS
// via coalesced async16; out2 = xs*ys; XY written in place into QR16.
// ---------------------------------------------------------------------------
__global__ __launch_bounds__(256) void k4_xy(
    const u16* __restrict__ ykv16, const u16* __restrict__ encvt,
    const float2* __restrict__ CS,
    u16* __restrict__ qrxy, const float* __restrict__ mu,
    const float* __restrict__ rs, const float* __restrict__ colsum,
    float* __restrict__ out2, int bh0) {
  const int z = blockIdx.z;
  const int bh = bh0 + z, h = bh % NHH;
  const int t0 = blockIdx.x * 128, n0 = blockIdx.y * 128;
  GEMM_PROLOGUE();
  PIPELINED_K_LOOP64(ykv16 + ((size_t)z * TT + t0) * DD, DD,
                     encvt + ((size_t)h * NN + n0) * DD, DD, DD);
  // stage the QR tile (128x128) into the upper 32KB, coalesced.
  {
    const u16* qg = qrxy + ((size_t)bh * TT + t0) * NN + n0;
#pragma unroll
    for (int s = 0; s < 8; ++s) {
      const int row = s * 16 + w * 4 + (lane >> 4);
      const int col = (lane & 15) * 8;
      async16(qg + (size_t)row * NN + col,
              smem + 16384 + (s * 256 + w * 64) * 8);
    }
  }
  asm volatile("s_waitcnt vmcnt(0)" ::: "memory");
  __syncthreads();
#pragma unroll
  for (int i = 0; i < 4; ++i) {
    float muv[4], rsv[4];
#pragma unroll
    for (int r = 0; r < 4; ++r) {
      const int grow = z * TT + t0 + wr * 64 + i * 16 + quad * 4 + r;
      muv[r] = mu[grow];
      rsv[r] = rs[grow];
    }
#pragma unroll
    for (int j = 0; j < 4; ++j) {
      const int lcol = wc * 64 + j * 16 + col16;
      const int n = n0 + lcol;
      const float csum = colsum[h * NN + n];
#pragma unroll
      for (int r = 0; r < 4; ++r) {
        const int lrow = wr * 64 + i * 16 + quad * 4 + r;
        const int t = t0 + lrow;
        const float ys = fmaxf(rsv[r] * acc[i][j][r] - rsv[r] * muv[r] * csum, 0.f);
        const unsigned pq =
            *(const unsigned*)&smem[16384 + lrow * 128 + (lcol & ~1)];
        const float lo = b2f((u16)pq), hi = b2f((u16)(pq >> 16));
        const float2 cs = CS[t * 128 + (n >> 1)];
        const float xs = (n & 1) ? (hi * cs.x - lo * cs.y)
                                 : (lo * cs.x + hi * cs.y);
        const float val = ys * xs;
        out2[((size_t)bh * TT + t) * NN + n] = val;
        smem[lrow * 128 + lcol] = f2b(val);
      }
    }
  }
  __syncthreads();
  copy_out128(smem, qrxy + ((size_t)bh * TT + t0) * NN + n0, NN, tid);
}

// ---------------------------------------------------------------------------
// K5: ymlp = flat(XY) @ DECT^T.  M=4096, N=768, K=3072.  64x64 tiles,
// BK=64, triple-buffered (2-deep prefetch, vmcnt(8)).
// ---------------------------------------------------------------------------
__global__ __launch_bounds__(256) void k5_mlp(
    const u16* __restrict__ xyq, const u16* __restrict__ dect,
    float* __restrict__ ymlp) {
  __shared__ __attribute__((aligned(16))) u16 sm[24576];
  const int tid = threadIdx.x;
  const int w = tid >> 6, lane = tid & 63;
  const int wr = w >> 1, wc = w & 1;
  const int m16 = lane & 15, quad = lane >> 4;
  const int m0 = blockIdx.x * 64, d0 = blockIdx.y * 64;
  f32x4 acc[2][2];
#pragma unroll
  for (int i = 0; i < 2; ++i)
#pragma unroll
    for (int j = 0; j < 2; ++j) acc[i][j] = (f32x4){0.f, 0.f, 0.f, 0.f};
  const int ar = w * 16 + (lane >> 2);      // A row within 64-tile
  const int m = m0 + ar;
  const int b = m >> 11, t = m & (TT - 1);
  const int kc = (((lane & 3) ^ KSWZ(ar)) << 3);   // source-swizzled chunk
#define K5_STAGE(buf, k0)                                                   \
  {                                                                         \
    const int hh_ = (k0) >> 8;                                              \
    const int kk_ = ((k0) & 255) + kc;                                      \
    const u16* ap_ = xyq + ((size_t)(b * NHH + hh_) * TT + t) * NN;         \
    async16(ap_ + kk_, (buf) + w * 512);                                    \
    async16(ap_ + kk_ + 32, (buf) + 2048 + w * 512);                        \
    stage64x32(dect + (size_t)d0 * (NHH * NN) + (k0), NHH * NN,             \
               (buf) + 4096, tid);                                          \
    stage64x32(dect + (size_t)d0 * (NHH * NN) + (k0) + 32, NHH * NN,        \
               (buf) + 6144, tid);                                          \
  }
  const int NK = (NHH * NN) / 64;           // 48 phases
  u16 *b0 = sm, *b1 = sm + 8192, *b2 = sm + 16384;
  K5_STAGE(b0, 0);
  K5_STAGE(b1, 64);
  for (int s = 0; s < NK; ++s) {
    if (s + 2 < NK) {
      K5_STAGE(b2, (s + 2) * 64);
      asm volatile("s_waitcnt vmcnt(8)" ::: "memory");
    } else if (s + 1 < NK) {
      asm volatile("s_waitcnt vmcnt(4)" ::: "memory");
    } else {
      asm volatile("s_waitcnt vmcnt(0)" ::: "memory");
    }
    __builtin_amdgcn_s_barrier();
    __builtin_amdgcn_sched_barrier(0);
#pragma unroll
    for (int half = 0; half < 2; ++half) {
      bf16x8 a[2], bb[2];
#pragma unroll
      for (int i = 0; i < 2; ++i) {
        const int row = wr * 32 + i * 16 + m16;
        a[i] = *(const bf16x8*)&b0[half * 2048 + row * 32 +
                                   ((quad ^ KSWZ(row)) << 3)];
      }
#pragma unroll
      for (int j = 0; j < 2; ++j) {
        const int row = wc * 32 + j * 16 + m16;
        bb[j] = *(const bf16x8*)&b0[4096 + half * 2048 + row * 32 +
                                    ((quad ^ KSWZ(row)) << 3)];
      }
#pragma unroll
      for (int i = 0; i < 2; ++i)
#pragma unroll
        for (int j = 0; j < 2; ++j)
          acc[i][j] = __builtin_amdgcn_mfma_f32_16x16x32_bf16(a[i], bb[j], acc[i][j], 0, 0, 0);
    }
    __builtin_amdgcn_sched_barrier(0);
    __builtin_amdgcn_s_barrier();
    u16* tmp = b0; b0 = b1; b1 = b2; b2 = tmp;
  }
#undef K5_STAGE
#pragma unroll
  for (int i = 0; i < 2; ++i)
#pragma unroll
    for (int j = 0; j < 2; ++j) {
      const int d = d0 + wc * 32 + j * 16 + m16;
#pragma unroll
      for (int r = 0; r < 4; ++r) {
        const int mm = m0 + wr * 32 + i * 16 + quad * 4 + r;
        ymlp[(size_t)mm * DD + d] = acc[i][j][r];
      }
    }
}

// ---------------------------------------------------------------------------
// K6: y = ln(ymlp)*sqrt(0.1/(ra+1e-6))*scale; out1 = ln(x+y). Block per row.
// ---------------------------------------------------------------------------
__global__ __launch_bounds__(256) void k6_final(
    const float* __restrict__ ymlp, const float* __restrict__ x,
    const float* __restrict__ scale, const float* __restrict__ ra,
    float* __restrict__ out1) {
  const int row = blockIdx.x;
  const int tid = threadIdx.x;
  const int wid = tid >> 6, lane = tid & 63;
  __shared__ float red[8];
  float v[3];
  float sum = 0.f, sq = 0.f;
#pragma unroll
  for (int j = 0; j < 3; ++j) {
    v[j] = ymlp[(size_t)row * DD + tid + j * 256];
    sum += v[j]; sq += v[j] * v[j];
  }
#pragma unroll
  for (int off = 32; off; off >>= 1) { sum += __shfl_xor(sum, off); sq += __shfl_xor(sq, off); }
  if (lane == 0) { red[wid] = sum; red[4 + wid] = sq; }
  __syncthreads();
  sum = red[0] + red[1] + red[2] + red[3];
  sq = red[4] + red[5] + red[6] + red[7];
  const float m1 = sum * (1.f / 768.f);
  const float r1 = rsqrtf(sq * (1.f / 768.f) - m1 * m1 + 1e-5f);
  float z[3];
  float sum2 = 0.f, sq2 = 0.f;
#pragma unroll
  for (int j = 0; j < 3; ++j) {
    const int d = tid + j * 256;
    float y = (v[j] - m1) * r1 * sqrtf(0.1f / (ra[d] + 1e-6f)) * scale[d];
    z[j] = x[(size_t)row * DD + d] + y;
    sum2 += z[j]; sq2 += z[j] * z[j];
  }
  __syncthreads();
#pragma unroll
  for (int off = 32; off; off >>= 1) { sum2 += __shfl_xor(sum2, off); sq2 += __shfl_xor(sq2, off); }
  if (lane == 0) { red[wid] = sum2; red[4 + wid] = sq2; }
  __syncthreads();
  sum2 = red[0] + red[1] + red[2] + red[3];
  sq2 = red[4] + red[5] + red[6] + red[7];
  const float m2 = sum2 * (1.f / 768.f);
  const float r2 = rsqrtf(sq2 * (1.f / 768.f) - m2 * m2 + 1e-5f);
#pragma unroll
  for (int j = 0; j < 3; ++j)
    out1[(size_t)row * DD + tid + j * 256] = (z[j] - m2) * r2;
}

// ---------------------------------------------------------------------------
extern "C" void kernel_launch(void* const* d_in, const int* in_sizes, int n_in,
                              void* d_out, int out_size, void* d_ws, size_t ws_size,
                              hipStream_t stream) {
  const float* x = (const float*)d_in[0];
  const float* enc = (const float*)d_in[1];
  const float* encv = (const float*)d_in[2];
  const float* dec = (const float*)d_in[3];
  const float* scale = (const float*)d_in[4];
  const float* ra = (const float*)d_in[5];
  float* out1 = (float*)d_out;
  float* out2 = out1 + (size_t)BB * TT * DD;
  float* ymlp = out1;                         // k5 scratch, k6 in-place

  const int NS = BB * NHH;  // 24 slices
  unsigned char* p = (unsigned char*)d_ws;
  u16* X16 = (u16*)p;    p += (size_t)BB * TT * DD * 2;
  u16* XT16 = (u16*)p;   p += (size_t)BB * DD * TT * 2;
  u16* ENCT = (u16*)p;   p += (size_t)NHH * NN * DD * 2;
  u16* ENCVT = (u16*)p;  p += (size_t)NHH * NN * DD * 2;
  u16* DECT = (u16*)p;   p += (size_t)DD * NHH * NN * 2;
  u16* QR16 = (u16*)p;   p += (size_t)NS * TT * NN * 2;   // holds QR, then XY
  u16* QRT16 = (u16*)p;  p += (size_t)NS * NN * TT * 2;
  float* COLSUM = (float*)p; p += (size_t)NHH * NN * 4;
  float2* CS = (float2*)p;   p += (size_t)TT * (NN / 2) * sizeof(float2);
  // Per-slice pool: SB + H16 + YKV16 + PART(48B/row) + MU/RS(8B/row)
  const size_t SLICE_B = (size_t)TT * CH * 2 + 3 * (size_t)DD * NN * 2 +
                         (size_t)TT * DD * 2 + (size_t)TT * 56;
  size_t fixed = (size_t)(p - (unsigned char*)d_ws);
  size_t rem = (ws_size > fixed) ? ws_size - fixed : 0;
  int GSmax = (int)(rem / SLICE_B);
  if (GSmax < 1) GSmax = 1;
  if (GSmax > NS) GSmax = NS;
  const int ngrp = (NS + GSmax - 1) / GSmax;
  const int GS = (NS + ngrp - 1) / ngrp;     // balanced groups
  u16* SB = (u16*)p;     p += (size_t)GS * TT * CH * 2;
  u16* H16 = (u16*)p;    p += (size_t)GS * 3 * DD * NN * 2;
  u16* YKV16 = (u16*)p;  p += (size_t)GS * TT * DD * 2;
  float2* PART = (float2*)p; p += (size_t)GS * TT * 6 * sizeof(float2);
  float* MU = (float*)p; p += (size_t)GS * TT * 4;
  float* RS = (float*)p; p += (size_t)GS * TT * 4;
  const int gsTT = GS * TT;

  // One-time conversions / transposes / tables: single fused launch,
  // then colsum (reads ENCVT -> must be a separate, later dispatch).
  k_prep<<<dim3(14080), 256, 0, stream>>>(
      x, X16, XT16, enc, ENCT, encv, ENCVT, dec, DECT, CS);
  k_colsum<<<dim3(NHH * NN / 4), 256, 0, stream>>>(ENCVT, COLSUM);

  k1_encode<<<dim3(BB * TT / 128, NN / 128, NHH), 256, 0, stream>>>(
      X16, ENCT, CS, QR16, QRT16);

  for (int bh0 = 0; bh0 < NS; bh0 += GS) {
    const int gs = imin(GS, NS - bh0);
    kS_band<<<dim3(40, gs), 256, 0, stream>>>(QR16, SB, bh0);
    kB_all<<<dim3(DD / 64, NN / 128, gs), 256, 0, stream>>>(
        XT16, QRT16, H16, bh0);
    kA_attn<<<dim3(96 * gs), 256, 0, stream>>>(
        QR16, H16, SB, XT16, YKV16, PART, gsTT, bh0);
    k3r_stats<<<dim3(gs * TT / 256), 256, 0, stream>>>(PART, MU, RS, gsTT);
    k4_xy<<<dim3(TT / 128, NN / 128, gs), 256, 0, stream>>>(
        YKV16, ENCVT, CS, QR16, MU, RS, COLSUM, out2, bh0);
  }

  k5_mlp<<<dim3(BB * TT / 64, DD / 64), 256, 0, stream>>>(QR16, DECT, ymlp);
  k6_final<<<dim3(BB * TT), 256, 0, stream>>>(ymlp, x, scale, ra, out1);
}

// Round 8
// 352.994 us; speedup vs baseline: 1.0804x; 1.0090x over previous
//
#include <hip/hip_runtime.h>
#include <math.h>

#define TT 2048
#define DD 768
#define NN 256
#define NHH 12
#define BB 2
#define CH 512           // attention chunk (4 chunks of 4 x 128-tiles)

typedef unsigned short u16;
typedef __attribute__((ext_vector_type(8))) short bf16x8;
typedef __attribute__((ext_vector_type(8))) unsigned short u16x8;
typedef __attribute__((ext_vector_type(4))) float f32x4;

static inline int imin(int a, int b) { return a < b ? a : b; }

__device__ __forceinline__ u16 f2b(float f) {
  union { float f; unsigned u; } a; a.f = f;
  unsigned r = a.u + 0x7FFF + ((a.u >> 16) & 1);
  return (u16)(r >> 16);
}
__device__ __forceinline__ float b2f(u16 h) {
  union { unsigned u; float f; } a; a.u = ((unsigned)h) << 16;
  return a.f;
}

__device__ __forceinline__ void async16(const void* g, void* l) {
  __builtin_amdgcn_global_load_lds(
      (const __attribute__((address_space(1))) unsigned*)g,
      (__attribute__((address_space(3))) unsigned*)l, 16, 0, 0);
}

// K-chunk XOR swizzle: LDS stays linear; the global SOURCE chunk is
// pre-swizzled at stage time and the SAME XOR is applied on every
// fragment read.  chunk' = chunk ^ ((row>>1)&3) gives 2-way bank
// aliasing on ds_read_b128 (free) vs 8-way unswizzled.
#define KSWZ(row) (((row) >> 1) & 3)

// Stage a 128x32 bf16 tile (row-major, ld in elements) into LDS [128][32],
// source-swizzled.
__device__ __forceinline__ void stage128x32(
    const u16* __restrict__ gbase, size_t ld, u16* lds, int tid) {
  const int w = tid >> 6, l = tid & 63;
#pragma unroll
  for (int q = 0; q < 2; ++q) {
    const int row = w * 32 + q * 16 + (l >> 2);
    const int kc = ((l & 3) ^ KSWZ(row)) << 3;
    async16(gbase + (size_t)row * ld + kc, lds + (w * 32 + q * 16) * 32);
  }
}

// Stage a 64x32 bf16 tile into LDS [64][32], source-swizzled.
__device__ __forceinline__ void stage64x32(
    const u16* __restrict__ gbase, size_t ld, u16* lds, int tid) {
  const int w = tid >> 6, l = tid & 63;
  const int row = w * 16 + (l >> 2);
  const int kc = ((l & 3) ^ KSWZ(row)) << 3;
  async16(gbase + (size_t)row * ld + kc, lds + w * 512);
}

// 16 MFMAs of one BK=32 step; wave (wr,wc) computes 64x64 of the 128x128
// tile.  Fragment reads apply the chunk swizzle.
__device__ __forceinline__ void mfma_step(
    const u16* As, const u16* Bs, int wr, int wc, int lane, f32x4 acc[4][4]) {
  const int m16 = lane & 15, quad = lane >> 4;
  bf16x8 a[4], b[4];
#pragma unroll
  for (int i = 0; i < 4; ++i) {
    const int row = wr * 64 + i * 16 + m16;
    a[i] = *(const bf16x8*)&As[row * 32 + ((quad ^ KSWZ(row)) << 3)];
  }
#pragma unroll
  for (int j = 0; j < 4; ++j) {
    const int row = wc * 64 + j * 16 + m16;
    b[j] = *(const bf16x8*)&Bs[row * 32 + ((quad ^ KSWZ(row)) << 3)];
  }
#pragma unroll
  for (int i = 0; i < 4; ++i)
#pragma unroll
    for (int j = 0; j < 4; ++j)
      acc[i][j] = __builtin_amdgcn_mfma_f32_16x16x32_bf16(a[i], b[j], acc[i][j], 0, 0, 0);
}

// copy a full 128x128 u16 tile from LDS (row-major) to global rows of ld.
__device__ __forceinline__ void copy_out128(
    const u16* buf, u16* g, size_t ld, int tid) {
#pragma unroll
  for (int s = 0; s < 8; ++s) {
    const int off = (s * 256 + tid) * 8;
    const int row = off >> 7, col = off & 127;
    *(u16x8*)&g[(size_t)row * ld + col] = *(const u16x8*)&buf[off];
  }
}

#define GEMM_SMEM \
  __shared__ __attribute__((aligned(16))) u16 smem[32768];

#define GEMM_VARS()                                                \
  const int tid = threadIdx.x;                                     \
  const int w = tid >> 6, lane = tid & 63;                         \
  const int wr = w >> 1, wc = w & 1;                               \
  const int col16 = lane & 15, quad = lane >> 4;                   \
  f32x4 acc[4][4];                                                 \
  _Pragma("unroll") for (int i = 0; i < 4; ++i)                    \
  _Pragma("unroll") for (int j = 0; j < 4; ++j)                    \
      acc[i][j] = (f32x4){0.f, 0.f, 0.f, 0.f};

#define GEMM_PROLOGUE() GEMM_SMEM GEMM_VARS()

// Double-buffered, counted-vmcnt pipelined K loop, BK=64:
// 32 MFMA per barrier-pair, 8 async16/thread/phase, vmcnt(8).
#define PIPELINED_K_LOOP64(ABASE, ALD, BBASE, BLD, KTOT)                    \
  {                                                                         \
    stage128x32((ABASE), (ALD), smem, tid);                                 \
    stage128x32((ABASE) + 32, (ALD), smem + 4096, tid);                     \
    stage128x32((BBASE), (BLD), smem + 8192, tid);                          \
    stage128x32((BBASE) + 32, (BLD), smem + 12288, tid);                    \
    const int np_ = (KTOT) / 64;                                            \
    for (int pp_ = 0; pp_ < np_; ++pp_) {                                   \
      u16* cb_ = (pp_ & 1) ? smem + 16384 : smem;                           \
      u16* nb_ = (pp_ & 1) ? smem : smem + 16384;                           \
      if (pp_ + 1 < np_) {                                                  \
        const int kn_ = (pp_ + 1) * 64;                                     \
        stage128x32((ABASE) + kn_, (ALD), nb_, tid);                        \
        stage128x32((ABASE) + kn_ + 32, (ALD), nb_ + 4096, tid);            \
        stage128x32((BBASE) + kn_, (BLD), nb_ + 8192, tid);                 \
        stage128x32((BBASE) + kn_ + 32, (BLD), nb_ + 12288, tid);           \
        asm volatile("s_waitcnt vmcnt(8)" ::: "memory");                    \
      } else {                                                              \
        asm volatile("s_waitcnt vmcnt(0)" ::: "memory");                    \
      }                                                                     \
      __builtin_amdgcn_s_barrier();                                         \
      __builtin_amdgcn_sched_barrier(0);                                    \
      mfma_step(cb_, cb_ + 8192, wr, wc, lane, acc);                        \
      mfma_step(cb_ + 4096, cb_ + 12288, wr, wc, lane, acc);                \
      __builtin_amdgcn_sched_barrier(0);                                    \
      __builtin_amdgcn_s_barrier();                                         \
    }                                                                       \
  }

// ---------------------------------------------------------------------------
// tcvt body: transpose-convert a 32x32 fp32 tile to bf16.
// ---------------------------------------------------------------------------
__device__ __forceinline__ void tcvt_body(
    const float* __restrict__ ip, u16* __restrict__ op, int R, int C,
    int bx, int by, int tid, float (*tile)[33]) {
  const int c0 = bx * 32, r0 = by * 32;
  const int tx = tid & 31, ty = tid >> 5;
#pragma unroll
  for (int p = 0; p < 4; ++p)
    tile[ty + p * 8][tx] = ip[(size_t)(r0 + ty + p * 8) * C + c0 + tx];
  __syncthreads();
#pragma unroll
  for (int p = 0; p < 4; ++p)
    op[(size_t)(c0 + ty + p * 8) * R + r0 + tx] = f2b(tile[tx][ty + p * 8]);
}

// ---------------------------------------------------------------------------
// k_prep: ALL one-time conversions fused into one launch.
// ---------------------------------------------------------------------------
__global__ __launch_bounds__(256) void k_prep(
    const float* __restrict__ x, u16* __restrict__ X16, u16* __restrict__ XT16,
    const float* __restrict__ enc, u16* __restrict__ ENCT,
    const float* __restrict__ encv, u16* __restrict__ ENCVT,
    const float* __restrict__ dec, u16* __restrict__ DECT,
    float2* __restrict__ CS) {
  __shared__ float tile[32][33];
  const int tid = threadIdx.x;
  const int bid = blockIdx.x;
  if (bid < 3072) {
    const size_t i = ((size_t)bid * 256 + tid) * 4;
    float4 v = *(const float4*)&x[i];
    u16 o[4] = {f2b(v.x), f2b(v.y), f2b(v.z), f2b(v.w)};
    *(ushort4*)&X16[i] = *(ushort4*)o;
  } else if (bid < 6144) {
    const int b = bid - 3072;
    const int bz = b / 1536, rb = b % 1536;
    tcvt_body(x + (size_t)bz * TT * DD, XT16 + (size_t)bz * DD * TT,
              TT, DD, rb % 24, rb / 24, tid, tile);
  } else if (bid < 8448) {
    const int b = bid - 6144;
    const int bz = b / 192, rb = b % 192;
    tcvt_body(enc + (size_t)bz * DD * NN, ENCT + (size_t)bz * NN * DD,
              DD, NN, rb % 8, rb / 8, tid, tile);
  } else if (bid < 10752) {
    const int b = bid - 8448;
    const int bz = b / 192, rb = b % 192;
    tcvt_body(encv + (size_t)bz * DD * NN, ENCVT + (size_t)bz * NN * DD,
              DD, NN, rb % 8, rb / 8, tid, tile);
  } else if (bid < 13056) {
    const int b = bid - 10752;
    tcvt_body(dec, DECT, NHH * NN, DD, b % 24, b / 24, tid, tile);
  } else {
    const int idx = (bid - 13056) * 256 + tid;   // t*128 + n2
    const int t = idx >> 7, n2 = idx & 127;
    const float freq = exp2f((float)(2 * n2) * -0.0625f) * 0.15915494309189535f;
    const float phase = (float)t * freq;
    const float ph = (phase - floorf(phase)) * 6.283185307179586f;
    CS[idx] = make_float2(__cosf(ph), __sinf(ph));
  }
}

__global__ __launch_bounds__(256) void k_colsum(
    const u16* __restrict__ encvt, float* __restrict__ colsum) {
  const int row = blockIdx.x * 4 + (threadIdx.x >> 6);
  const int lane = threadIdx.x & 63;
  const u16* pr = encvt + (size_t)row * DD;
  float s = 0.f;
#pragma unroll
  for (int i = 0; i < 3; ++i) {
    ushort4 v = *(const ushort4*)&pr[(lane << 2) + i * 256];
    s += b2f(v.x) + b2f(v.y) + b2f(v.z) + b2f(v.w);
  }
#pragma unroll
  for (int off = 32; off; off >>= 1) s += __shfl_xor(s, off);
  if (lane == 0) colsum[row] = s;
}

// ---------------------------------------------------------------------------
// K1: latent = X16 @ ENCT[h]^T; relu; rope -> QR16 [b][h][t][n] AND
// QRT16 [b][h][n][t].  BK=64 pipeline; XOR-swizzled epilogue tile for the
// QRT column read.
// ---------------------------------------------------------------------------
__device__ __forceinline__ int swz8(int row) { return ((row >> 3) & 7) << 3; }

__global__ __launch_bounds__(256) void k1_encode(
    const u16* __restrict__ x16, const u16* __restrict__ enct,
    const float2* __restrict__ CS,
    u16* __restrict__ qr16, u16* __restrict__ qrt16) {
  const int h = blockIdx.z;
  const int m0 = blockIdx.x * 128, n0 = blockIdx.y * 128;
  GEMM_PROLOGUE();
  PIPELINED_K_LOOP64(x16 + (size_t)m0 * DD, DD,
                     enct + ((size_t)h * NN + n0) * DD, DD, DD);
  __syncthreads();
#pragma unroll
  for (int i = 0; i < 4; ++i)
#pragma unroll
    for (int j = 0; j < 4; ++j) {
      const int n = n0 + wc * 64 + j * 16 + col16;
      float rv[4], pv[4];
#pragma unroll
      for (int r = 0; r < 4; ++r) rv[r] = fmaxf(acc[i][j][r], 0.f);
#pragma unroll
      for (int r = 0; r < 4; ++r) pv[r] = __shfl_xor(rv[r], 1);
#pragma unroll
      for (int r = 0; r < 4; ++r) {
        const int lrow = wr * 64 + i * 16 + quad * 4 + r;
        const int t = (m0 + lrow) & (TT - 1);
        const float2 cs = CS[t * 128 + (n >> 1)];
        const float o = (n & 1) ? (rv[r] * cs.x + pv[r] * cs.y)
                                : (rv[r] * cs.x - pv[r] * cs.y);
        smem[lrow * 128 + ((wc * 64 + j * 16 + col16) ^ swz8(lrow))] = f2b(o);
      }
    }
  __syncthreads();
  const int bq = m0 >> 11, tb = m0 & (TT - 1);
  const size_t sl = (size_t)(bq * NHH + h);
  // row-major copy (swizzle-aware source)
  u16* qg = qr16 + (sl * TT + tb) * NN + n0;
#pragma unroll
  for (int s = 0; s < 8; ++s) {
    const int off = (s * 256 + tid) * 8;
    const int row = off >> 7, col = off & 127;
    *(u16x8*)&qg[(size_t)row * NN + col] =
        *(const u16x8*)&smem[row * 128 + (col ^ swz8(row))];
  }
  // transposed copy: QRT16[sl][n][t] = tile[t][n]
#pragma unroll
  for (int s = 0; s < 8; ++s) {
    const int off = (s * 256 + tid) * 8;
    const int nr = off >> 7, tc = off & 127;
    const int sw = swz8(tc);                 // tc 8-aligned: same for tc..tc+7
    u16 vals[8];
#pragma unroll
    for (int k = 0; k < 8; ++k) vals[k] = smem[(tc + k) * 128 + (nr ^ sw)];
    *(u16x8*)&qrt16[(sl * NN + n0 + nr) * TT + tb + tc] = *(u16x8*)vals;
  }
}

// ---------------------------------------------------------------------------
// kSB: kS (S-band GEMM) and kB (H-state GEMM) FUSED into one launch —
// they are data-independent; fusing removes a stream sync and merges two
// ragged tails (960 + 576 blocks -> 1536 blocks, ~6/CU).
// Role split on blockIdx.x (block-uniform): [0,nS) = kS, [nS,..) = kB.
// ---------------------------------------------------------------------------
__global__ __launch_bounds__(256) void kSB(
    const u16* __restrict__ qr16, const u16* __restrict__ xt16,
    const u16* __restrict__ qrt16, u16* __restrict__ sb,
    u16* __restrict__ h16, int nS, int bh0) {
  GEMM_SMEM;
  const int tid = threadIdx.x;
  const int w = tid >> 6, lane = tid & 63;
  const int col16 = lane & 15, quad = lane >> 4;
  if ((int)blockIdx.x < nS) {
    // ---------------- kS role: S = QR QR^T band tile ----------------
    const int wr = w >> 1, wc = w & 1;
    const int z = blockIdx.x / 40, sub = blockIdx.x % 40;
    const int bh = bh0 + z;
    const int cc = sub / 10, rr = sub % 10;
    int i = (int)((sqrtf(8.f * rr + 1.f) - 1.f) * 0.5f);
    while ((i + 1) * (i + 2) / 2 <= rr) ++i;
    while (i * (i + 1) / 2 > rr) --i;
    const int j = rr - i * (i + 1) / 2;
    const int t0 = (cc * 4 + i) * 128;
    const int s0 = cc * CH + j * 128;
    const u16* q = qr16 + (size_t)bh * TT * NN;
    f32x4 acc[4][4];
#pragma unroll
    for (int a = 0; a < 4; ++a)
#pragma unroll
      for (int b = 0; b < 4; ++b) acc[a][b] = (f32x4){0.f, 0.f, 0.f, 0.f};
    PIPELINED_K_LOOP64(q + (size_t)t0 * NN, NN, q + (size_t)s0 * NN, NN, NN);
    const bool diag = (i == j);
    __syncthreads();
#pragma unroll
    for (int ii = 0; ii < 4; ++ii)
#pragma unroll
      for (int jj = 0; jj < 4; ++jj) {
        const int s = s0 + wc * 64 + jj * 16 + col16;
#pragma unroll
        for (int r = 0; r < 4; ++r) {
          const int lrow = wr * 64 + ii * 16 + quad * 4 + r;
          const int t = t0 + lrow;
          float v = acc[ii][jj][r];
          if (diag && s >= t) v = 0.f;
          smem[lrow * 128 + wc * 64 + jj * 16 + col16] = f2b(v);
        }
      }
    __syncthreads();
    copy_out128(smem, sb + ((size_t)z * TT + t0) * CH + j * 128, CH, tid);
  } else {
    // ---------------- kB role: H chunk-prefix GEMM ----------------
    const int r2 = blockIdx.x - nS;
    const int z = r2 / 24, rr2 = r2 % 24;
    const int d0 = (rr2 % 12) * 64, n0 = (rr2 / 12) * 128;
    const int bh = bh0 + z, b = bh / NHH;
    u16* buf0 = smem;          // A0 +0, A1 +2048, B0 +4096, B1 +8192
    u16* buf1 = smem + 12288;
    u16* snap = smem + 24576;  // 64x128 u16
    f32x4 acc[4][2];
#pragma unroll
    for (int i = 0; i < 4; ++i)
#pragma unroll
      for (int j = 0; j < 2; ++j) acc[i][j] = (f32x4){0.f, 0.f, 0.f, 0.f};
    const u16* Ab = xt16 + ((size_t)b * DD + d0) * TT;
    const u16* Bb = qrt16 + ((size_t)bh * NN + n0) * TT;
#define KB_STAGE(buf, k0)                                                   \
  {                                                                         \
    stage64x32(Ab + (k0), TT, (buf), tid);                                  \
    stage64x32(Ab + (k0) + 32, TT, (buf) + 2048, tid);                      \
    stage128x32(Bb + (k0), TT, (buf) + 4096, tid);                          \
    stage128x32(Bb + (k0) + 32, TT, (buf) + 8192, tid);                     \
  }
    for (int c = 0; c < 3; ++c) {
      const int kbase = c * CH;
      KB_STAGE(buf0, kbase);
      for (int s = 0; s < CH / 64; ++s) {
        u16* cb = (s & 1) ? buf1 : buf0;
        u16* nb = (s & 1) ? buf0 : buf1;
        if (s + 1 < CH / 64) {
          KB_STAGE(nb, kbase + (s + 1) * 64);
          asm volatile("s_waitcnt vmcnt(6)" ::: "memory");
        } else {
          asm volatile("s_waitcnt vmcnt(0)" ::: "memory");
        }
        __builtin_amdgcn_s_barrier();
        __builtin_amdgcn_sched_barrier(0);
#pragma unroll
        for (int half = 0; half < 2; ++half) {
          bf16x8 a[4], bb[2];
#pragma unroll
          for (int i = 0; i < 4; ++i) {
            const int row = i * 16 + col16;
            a[i] = *(const bf16x8*)&cb[half * 2048 + row * 32 +
                                       ((quad ^ KSWZ(row)) << 3)];
          }
#pragma unroll
          for (int j = 0; j < 2; ++j) {
            const int row = w * 32 + j * 16 + col16;
            bb[j] = *(const bf16x8*)&cb[4096 + half * 4096 + row * 32 +
                                        ((quad ^ KSWZ(row)) << 3)];
          }
#pragma unroll
          for (int i = 0; i < 4; ++i)
#pragma unroll
            for (int j = 0; j < 2; ++j)
              acc[i][j] = __builtin_amdgcn_mfma_f32_16x16x32_bf16(a[i], bb[j], acc[i][j], 0, 0, 0);
        }
        __builtin_amdgcn_sched_barrier(0);
        __builtin_amdgcn_s_barrier();
      }
      // snapshot H16[z][c]
#pragma unroll
      for (int i = 0; i < 4; ++i)
#pragma unroll
        for (int j = 0; j < 2; ++j)
#pragma unroll
          for (int r = 0; r < 4; ++r)
            snap[(i * 16 + quad * 4 + r) * 128 + w * 32 + j * 16 + col16] =
                f2b(acc[i][j][r]);
      __syncthreads();
      u16* hd = h16 + (size_t)(z * 3 + c) * DD * NN;
#pragma unroll
      for (int s4 = 0; s4 < 4; ++s4) {
        const int off = (s4 * 256 + tid) * 8;
        const int row = off >> 7, col = off & 127;
        *(u16x8*)&hd[(size_t)(d0 + row) * NN + n0 + col] = *(const u16x8*)&snap[off];
      }
      __syncthreads();
    }
#undef KB_STAGE
  }
}

// ---------------------------------------------------------------------------
// kA: 128x128 output, unified panel-pipelined K sequence.
// 1D grid, bijective chunked XCD swizzle (T1) + LPT tt order.
// Fused stats v3: Σ/Σ² ride the copy-out register stream; padded LDS
// scratch; one coalesced dblk-major float2 store per row.
// ---------------------------------------------------------------------------
__device__ static const int TTORD[16] = {15, 11, 7, 14, 10, 6, 13, 9,
                                         5, 3, 12, 8, 4, 2, 1, 0};

__global__ __launch_bounds__(256) void kA_attn(
    const u16* __restrict__ qr16, const u16* __restrict__ h16,
    const u16* __restrict__ sb, const u16* __restrict__ xt16,
    u16* __restrict__ ykv16, float2* __restrict__ PART, int gsTT, int bh0) {
  GEMM_SMEM;
  const int tid = threadIdx.x;
  const int w = tid >> 6, lane = tid & 63;
  const int wr = w >> 1, wc = w & 1;
  const int col16 = lane & 15, quad = lane >> 4;
  const int nwg = gridDim.x;
  const int bid = blockIdx.x;
  const int qn = nwg >> 3, r8 = nwg & 7;
  const int xcd = bid & 7, pos = bid >> 3;
  const int wg = (xcd < r8 ? xcd * (qn + 1) : r8 * (qn + 1) + (xcd - r8) * qn) + pos;
  const int z = wg / 96;
  const int tt = TTORD[(wg / 6) & 15];       // LPT within chunk
  const int dblk = wg % 6;
  const int d0 = dblk * 128;
  const int bh = bh0 + z, b = bh / NHH;
  const int c = tt >> 2, it = tt & 3;
  const int t0 = tt * 128;
  f32x4 acc[4][4];
#pragma unroll
  for (int i = 0; i < 4; ++i)
#pragma unroll
    for (int j = 0; j < 4; ++j) acc[i][j] = (f32x4){0.f, 0.f, 0.f, 0.f};

  const int c4 = (c > 0) ? 4 : 0;
  const int nP = c4 + (it + 1) * 2;          // BK=64 panels total
  const u16* hs = h16 + ((size_t)(z * 3 + (c > 0 ? c - 1 : 0)) * DD + d0) * NN;
  const u16* qb = qr16 + ((size_t)bh * TT + t0) * NN;
  const u16* sbb = sb + ((size_t)z * TT + t0) * CH;
  const u16* xb = xt16 + ((size_t)b * DD + d0) * TT + c * CH;

#define KA_STAGE(buf, p)                                                  \
  {                                                                       \
    const u16 *pa_, *pb_; size_t la_, lb_;                                \
    if ((p) < c4) {                                                       \
      pa_ = qb + (p) * 64; la_ = NN;                                      \
      pb_ = hs + (p) * 64; lb_ = NN;                                      \
    } else {                                                              \
      const int q_ = (p) - c4;                                            \
      const int j_ = q_ >> 1, kk_ = (q_ & 1) << 6;                        \
      pa_ = sbb + j_ * 128 + kk_; la_ = CH;                               \
      pb_ = xb + j_ * 128 + kk_; lb_ = TT;                                \
    }                                                                     \
    stage128x32(pa_, la_, (buf), tid);                                    \
    stage128x32(pa_ + 32, la_, (buf) + 4096, tid);                        \
    stage128x32(pb_, lb_, (buf) + 8192, tid);                             \
    stage128x32(pb_ + 32, lb_, (buf) + 12288, tid);                       \
  }

  u16* bufA = smem;
  u16* bufB = smem + 16384;
  KA_STAGE(bufA, 0);
  for (int p = 0; p < nP; ++p) {
    u16* cb = (p & 1) ? bufB : bufA;
    u16* nb = (p & 1) ? bufA : bufB;
    if (p + 1 < nP) {
      KA_STAGE(nb, p + 1);
      asm volatile("s_waitcnt vmcnt(8)" ::: "memory");
    } else {
      asm volatile("s_waitcnt vmcnt(0)" ::: "memory");
    }
    __builtin_amdgcn_s_barrier();            // publish panel p across waves
    __builtin_amdgcn_sched_barrier(0);
    mfma_step(cb, cb + 8192, wr, wc, lane, acc);
    mfma_step(cb + 4096, cb + 12288, wr, wc, lane, acc);
    __builtin_amdgcn_sched_barrier(0);
    __builtin_amdgcn_s_barrier();            // reads of cb done before overwrite
  }
#undef KA_STAGE

  __syncthreads();
#pragma unroll
  for (int i = 0; i < 4; ++i)
#pragma unroll
    for (int j = 0; j < 4; ++j)
#pragma unroll
      for (int r = 0; r < 4; ++r) {
        const int lrow = wr * 64 + i * 16 + quad * 4 + r;
        smem[lrow * 128 + wc * 64 + j * 16 + col16] = f2b(acc[i][j][r]);
      }
  __syncthreads();
  // copy-out + per-chunk stats.
  float2* scratch = (float2*)&smem[16384];   // [128][17] padded
  u16* yg = ykv16 + ((size_t)z * TT + t0) * DD + d0;
#pragma unroll
  for (int s = 0; s < 8; ++s) {
    const int off = (s * 256 + tid) * 8;
    const int row = off >> 7, col = off & 127;
    const u16x8 v = *(const u16x8*)&smem[off];
    *(u16x8*)&yg[(size_t)row * DD + col] = v;
    float ps = 0.f, pq = 0.f;
#pragma unroll
    for (int k = 0; k < 8; ++k) {
      const float f = b2f(v[k]);
      ps += f;
      pq += f * f;
    }
    scratch[row * 17 + (tid & 15)] = make_float2(ps, pq);
  }
  __syncthreads();
  if (tid < 128) {
    const float2* pr = &scratch[tid * 17];
    float s = 0.f, q2 = 0.f;
#pragma unroll
    for (int k = 0; k < 16; ++k) { s += pr[k].x; q2 += pr[k].y; }
    PART[(size_t)dblk * gsTT + z * TT + t0 + tid] = make_float2(s, q2);
  }
}

// ---------------------------------------------------------------------------
// K4: raw GEMM ykv16 @ ENCVT[h]^T with LN as epilogue affine; row stats
// folded INLINE from PART (6 float2 per row, L2-resident — k3r removed);
// xs via inverse rope of QR16 (CS table); out2 = xs*ys; XY in place.
// ---------------------------------------------------------------------------
__global__ __launch_bounds__(256) void k4_xy(
    const u16* __restrict__ ykv16, const u16* __restrict__ encvt,
    const float2* __restrict__ CS,
    u16* __restrict__ qrxy, const float2* __restrict__ PART,
    const float* __restrict__ colsum,
    float* __restrict__ out2, int gsTT, int bh0) {
  const int z = blockIdx.z;
  const int bh = bh0 + z, h = bh % NHH;
  const int t0 = blockIdx.x * 128, n0 = blockIdx.y * 128;
  GEMM_PROLOGUE();
  PIPELINED_K_LOOP64(ykv16 + ((size_t)z * TT + t0) * DD, DD,
                     encvt + ((size_t)h * NN + n0) * DD, DD, DD);
  // stage the QR tile (128x128) into the upper 32KB, coalesced.
  {
    const u16* qg = qrxy + ((size_t)bh * TT + t0) * NN + n0;
#pragma unroll
    for (int s = 0; s < 8; ++s) {
      const int row = s * 16 + w * 4 + (lane >> 4);
      const int col = (lane & 15) * 8;
      async16(qg + (size_t)row * NN + col,
              smem + 16384 + (s * 256 + w * 64) * 8);
    }
  }
  asm volatile("s_waitcnt vmcnt(0)" ::: "memory");
  __syncthreads();
#pragma unroll
  for (int i = 0; i < 4; ++i) {
    float muv[4], rsv[4];
#pragma unroll
    for (int r = 0; r < 4; ++r) {
      const int grow = z * TT + t0 + wr * 64 + i * 16 + quad * 4 + r;
      float s_ = 0.f, q_ = 0.f;
#pragma unroll
      for (int d = 0; d < 6; ++d) {
        const float2 p2 = PART[(size_t)d * gsTT + grow];
        s_ += p2.x;
        q_ += p2.y;
      }
      const float m_ = s_ * (1.f / 768.f);
      muv[r] = m_;
      rsv[r] = rsqrtf(q_ * (1.f / 768.f) - m_ * m_ + 1e-5f);
    }
#pragma unroll
    for (int j = 0; j < 4; ++j) {
      const int lcol = wc * 64 + j * 16 + col16;
      const int n = n0 + lcol;
      const float csum = colsum[h * NN + n];
#pragma unroll
      for (int r = 0; r < 4; ++r) {
        const int lrow = wr * 64 + i * 16 + quad * 4 + r;
        const int t = t0 + lrow;
        const float ys = fmaxf(rsv[r] * acc[i][j][r] - rsv[r] * muv[r] * csum, 0.f);
        const unsigned pq =
            *(const unsigned*)&smem[16384 + lrow * 128 + (lcol & ~1)];
        const float lo = b2f((u16)pq), hi = b2f((u16)(pq >> 16));
        const float2 cs = CS[t * 128 + (n >> 1)];
        const float xs = (n & 1) ? (hi * cs.x - lo * cs.y)
                                 : (lo * cs.x + hi * cs.y);
        const float val = ys * xs;
        out2[((size_t)bh * TT + t) * NN + n] = val;
        smem[lrow * 128 + lcol] = f2b(val);
      }
    }
  }
  __syncthreads();
  copy_out128(smem, qrxy + ((size_t)bh * TT + t0) * NN + n0, NN, tid);
}

// ---------------------------------------------------------------------------
// K5: ymlp = flat(XY) @ DECT^T.  M=4096, N=768, K=3072.  128x128 tiles
// (32 MFMA/phase/wave vs old 64-tile's 16), BK=64 dbuf + vmcnt(8).
// Grid 192 (1D, XCD-swizzled, d0-inner so same-m0 blocks share A in L2).
// A panels never straddle heads (256 % 64 == 0) -> regular strided stage.
// ---------------------------------------------------------------------------
__global__ __launch_bounds__(256) void k5_mlp(
    const u16* __restrict__ xyq, const u16* __restrict__ dect,
    float* __restrict__ ymlp) {
  GEMM_PROLOGUE();
  const int bid = blockIdx.x;                // 192 = 8 XCD x 24
  const int wg = (bid & 7) * 24 + (bid >> 3);
  const int m0 = (wg / 6) * 128, d0 = (wg % 6) * 128;
  const int b = m0 >> 11, t0 = m0 & (TT - 1);
#define K5_ST(buf, p)                                                       \
  {                                                                         \
    const int k0_ = (p) * 64, hh_ = k0_ >> 8, kk_ = k0_ & 255;              \
    const u16* pa_ = xyq + ((size_t)(b * NHH + hh_) * TT + t0) * NN + kk_;  \
    const u16* pb_ = dect + (size_t)d0 * (NHH * NN) + k0_;                  \
    stage128x32(pa_, NN, (buf), tid);                                       \
    stage128x32(pa_ + 32, NN, (buf) + 4096, tid);                           \
    stage128x32(pb_, NHH * NN, (buf) + 8192, tid);                          \
    stage128x32(pb_ + 32, NHH * NN, (buf) + 12288, tid);                    \
  }
  const int NP = (NHH * NN) / 64;            // 48 panels
  u16* bufA = smem;
  u16* bufB = smem + 16384;
  K5_ST(bufA, 0);
  for (int p = 0; p < NP; ++p) {
    u16* cb = (p & 1) ? bufB : bufA;
    u16* nb = (p & 1) ? bufA : bufB;
    if (p + 1 < NP) {
      K5_ST(nb, p + 1);
      asm volatile("s_waitcnt vmcnt(8)" ::: "memory");
    } else {
      asm volatile("s_waitcnt vmcnt(0)" ::: "memory");
    }
    __builtin_amdgcn_s_barrier();
    __builtin_amdgcn_sched_barrier(0);
    mfma_step(cb, cb + 8192, wr, wc, lane, acc);
    mfma_step(cb + 4096, cb + 12288, wr, wc, lane, acc);
    __builtin_amdgcn_sched_barrier(0);
    __builtin_amdgcn_s_barrier();
  }
#undef K5_ST
#pragma unroll
  for (int i = 0; i < 4; ++i)
#pragma unroll
    for (int j = 0; j < 4; ++j) {
      const int d = d0 + wc * 64 + j * 16 + col16;
#pragma unroll
      for (int r = 0; r < 4; ++r) {
        const int mm = m0 + wr * 64 + i * 16 + quad * 4 + r;
        ymlp[(size_t)mm * DD + d] = acc[i][j][r];
      }
    }
}

// ---------------------------------------------------------------------------
// K6: y = ln(ymlp)*sqrt(0.1/(ra+1e-6))*scale; out1 = ln(x+y). Block per row.
// ---------------------------------------------------------------------------
__global__ __launch_bounds__(256) void k6_final(
    const float* __restrict__ ymlp, const float* __restrict__ x,
    const float* __restrict__ scale, const float* __restrict__ ra,
    float* __restrict__ out1) {
  const int row = blockIdx.x;
  const int tid = threadIdx.x;
  const int wid = tid >> 6, lane = tid & 63;
  __shared__ float red[8];
  float v[3];
  float sum = 0.f, sq = 0.f;
#pragma unroll
  for (int j = 0; j < 3; ++j) {
    v[j] = ymlp[(size_t)row * DD + tid + j * 256];
    sum += v[j]; sq += v[j] * v[j];
  }
#pragma unroll
  for (int off = 32; off; off >>= 1) { sum += __shfl_xor(sum, off); sq += __shfl_xor(sq, off); }
  if (lane == 0) { red[wid] = sum; red[4 + wid] = sq; }
  __syncthreads();
  sum = red[0] + red[1] + red[2] + red[3];
  sq = red[4] + red[5] + red[6] + red[7];
  const float m1 = sum * (1.f / 768.f);
  const float r1 = rsqrtf(sq * (1.f / 768.f) - m1 * m1 + 1e-5f);
  float z[3];
  float sum2 = 0.f, sq2 = 0.f;
#pragma unroll
  for (int j = 0; j < 3; ++j) {
    const int d = tid + j * 256;
    float y = (v[j] - m1) * r1 * sqrtf(0.1f / (ra[d] + 1e-6f)) * scale[d];
    z[j] = x[(size_t)row * DD + d] + y;
    sum2 += z[j]; sq2 += z[j] * z[j];
  }
  __syncthreads();
#pragma unroll
  for (int off = 32; off; off >>= 1) { sum2 += __shfl_xor(sum2, off); sq2 += __shfl_xor(sq2, off); }
  if (lane == 0) { red[wid] = sum2; red[4 + wid] = sq2; }
  __syncthreads();
  sum2 = red[0] + red[1] + red[2] + red[3];
  sq2 = red[4] + red[5] + red[6] + red[7];
  const float m2 = sum2 * (1.f / 768.f);
  const float r2 = rsqrtf(sq2 * (1.f / 768.f) - m2 * m2 + 1e-5f);
#pragma unroll
  for (int j = 0; j < 3; ++j)
    out1[(size_t)row * DD + tid + j * 256] = (z[j] - m2) * r2;
}

// ---------------------------------------------------------------------------
extern "C" void kernel_launch(void* const* d_in, const int* in_sizes, int n_in,
                              void* d_out, int out_size, void* d_ws, size_t ws_size,
                              hipStream_t stream) {
  const float* x = (const float*)d_in[0];
  const float* enc = (const float*)d_in[1];
  const float* encv = (const float*)d_in[2];
  const float* dec = (const float*)d_in[3];
  const float* scale = (const float*)d_in[4];
  const float* ra = (const float*)d_in[5];
  float* out1 = (float*)d_out;
  float* out2 = out1 + (size_t)BB * TT * DD;
  float* ymlp = out1;                         // k5 scratch, k6 in-place

  const int NS = BB * NHH;  // 24 slices
  unsigned char* p = (unsigned char*)d_ws;
  u16* X16 = (u16*)p;    p += (size_t)BB * TT * DD * 2;
  u16* XT16 = (u16*)p;   p += (size_t)BB * DD * TT * 2;
  u16* ENCT = (u16*)p;   p += (size_t)NHH * NN * DD * 2;
  u16* ENCVT = (u16*)p;  p += (size_t)NHH * NN * DD * 2;
  u16* DECT = (u16*)p;   p += (size_t)DD * NHH * NN * 2;
  u16* QR16 = (u16*)p;   p += (size_t)NS * TT * NN * 2;   // holds QR, then XY
  u16* QRT16 = (u16*)p;  p += (size_t)NS * NN * TT * 2;
  float* COLSUM = (float*)p; p += (size_t)NHH * NN * 4;
  float2* CS = (float2*)p;   p += (size_t)TT * (NN / 2) * sizeof(float2);
  // Per-slice pool: SB + H16 + YKV16 + PART(48B/row)
  const size_t SLICE_B = (size_t)TT * CH * 2 + 3 * (size_t)DD * NN * 2 +
                         (size_t)TT * DD * 2 + (size_t)TT * 48;
  size_t fixed = (size_t)(p - (unsigned char*)d_ws);
  size_t rem = (ws_size > fixed) ? ws_size - fixed : 0;
  int GSmax = (int)(rem / SLICE_B);
  if (GSmax < 1) GSmax = 1;
  if (GSmax > NS) GSmax = NS;
  const int ngrp = (NS + GSmax - 1) / GSmax;
  const int GS = (NS + ngrp - 1) / ngrp;     // balanced groups
  u16* SB = (u16*)p;     p += (size_t)GS * TT * CH * 2;
  u16* H16 = (u16*)p;    p += (size_t)GS * 3 * DD * NN * 2;
  u16* YKV16 = (u16*)p;  p += (size_t)GS * TT * DD * 2;
  float2* PART = (float2*)p; p += (size_t)GS * TT * 6 * sizeof(float2);
  const int gsTT = GS * TT;

  // One-time conversions / transposes / tables: single fused launch,
  // then colsum (reads ENCVT -> separate dispatch).
  k_prep<<<dim3(14080), 256, 0, stream>>>(
      x, X16, XT16, enc, ENCT, encv, ENCVT, dec, DECT, CS);
  k_colsum<<<dim3(NHH * NN / 4), 256, 0, stream>>>(ENCVT, COLSUM);

  k1_encode<<<dim3(BB * TT / 128, NN / 128, NHH), 256, 0, stream>>>(
      X16, ENCT, CS, QR16, QRT16);

  for (int bh0 = 0; bh0 < NS; bh0 += GS) {
    const int gs = imin(GS, NS - bh0);
    kSB<<<dim3(64 * gs), 256, 0, stream>>>(
        QR16, XT16, QRT16, SB, H16, 40 * gs, bh0);
    kA_attn<<<dim3(96 * gs), 256, 0, stream>>>(
        QR16, H16, SB, XT16, YKV16, PART, gsTT, bh0);
    k4_xy<<<dim3(TT / 128, NN / 128, gs), 256, 0, stream>>>(
        YKV16, ENCVT, CS, QR16, PART, COLSUM, out2, gsTT, bh0);
  }

  k5_mlp<<<dim3(192), 256, 0, stream>>>(QR16, DECT, ymlp);
  k6_final<<<dim3(BB * TT), 256, 0, stream>>>(ymlp, x, scale, ra, out1);
}

// Round 9
// 346.463 us; speedup vs baseline: 1.1008x; 1.0189x over previous
//
#include <hip/hip_runtime.h>
#include <math.h>

#define TT 2048
#define DD 768
#define NN 256
#define NHH 12
#define BB 2
#define CH 512           // attention chunk (4 chunks of 4 x 128-tiles)

typedef unsigned short u16;
typedef __attribute__((ext_vector_type(8))) short bf16x8;
typedef __attribute__((ext_vector_type(8))) unsigned short u16x8;
typedef __attribute__((ext_vector_type(4))) float f32x4;

static inline int imin(int a, int b) { return a < b ? a : b; }

__device__ __forceinline__ u16 f2b(float f) {
  union { float f; unsigned u; } a; a.f = f;
  unsigned r = a.u + 0x7FFF + ((a.u >> 16) & 1);
  return (u16)(r >> 16);
}
__device__ __forceinline__ float b2f(u16 h) {
  union { unsigned u; float f; } a; a.u = ((unsigned)h) << 16;
  return a.f;
}

__device__ __forceinline__ void async16(const void* g, void* l) {
  __builtin_amdgcn_global_load_lds(
      (const __attribute__((address_space(1))) unsigned*)g,
      (__attribute__((address_space(3))) unsigned*)l, 16, 0, 0);
}

// K-chunk XOR swizzle: LDS stays linear; the global SOURCE chunk is
// pre-swizzled at stage time and the SAME XOR is applied on every
// fragment read.  chunk' = chunk ^ ((row>>1)&3) gives 2-way bank
// aliasing on ds_read_b128 (free) vs 8-way unswizzled.
#define KSWZ(row) (((row) >> 1) & 3)

// Stage a 128x32 bf16 tile (row-major, ld in elements) into LDS [128][32],
// source-swizzled.
__device__ __forceinline__ void stage128x32(
    const u16* __restrict__ gbase, size_t ld, u16* lds, int tid) {
  const int w = tid >> 6, l = tid & 63;
#pragma unroll
  for (int q = 0; q < 2; ++q) {
    const int row = w * 32 + q * 16 + (l >> 2);
    const int kc = ((l & 3) ^ KSWZ(row)) << 3;
    async16(gbase + (size_t)row * ld + kc, lds + (w * 32 + q * 16) * 32);
  }
}

// Stage a 64x32 bf16 tile into LDS [64][32], source-swizzled.
__device__ __forceinline__ void stage64x32(
    const u16* __restrict__ gbase, size_t ld, u16* lds, int tid) {
  const int w = tid >> 6, l = tid & 63;
  const int row = w * 16 + (l >> 2);
  const int kc = ((l & 3) ^ KSWZ(row)) << 3;
  async16(gbase + (size_t)row * ld + kc, lds + w * 512);
}

// 16 MFMAs of one BK=32 step; wave (wr,wc) computes 64x64 of the 128x128
// tile.  Fragment reads apply the chunk swizzle.
__device__ __forceinline__ void mfma_step(
    const u16* As, const u16* Bs, int wr, int wc, int lane, f32x4 acc[4][4]) {
  const int m16 = lane & 15, quad = lane >> 4;
  bf16x8 a[4], b[4];
#pragma unroll
  for (int i = 0; i < 4; ++i) {
    const int row = wr * 64 + i * 16 + m16;
    a[i] = *(const bf16x8*)&As[row * 32 + ((quad ^ KSWZ(row)) << 3)];
  }
#pragma unroll
  for (int j = 0; j < 4; ++j) {
    const int row = wc * 64 + j * 16 + m16;
    b[j] = *(const bf16x8*)&Bs[row * 32 + ((quad ^ KSWZ(row)) << 3)];
  }
#pragma unroll
  for (int i = 0; i < 4; ++i)
#pragma unroll
    for (int j = 0; j < 4; ++j)
      acc[i][j] = __builtin_amdgcn_mfma_f32_16x16x32_bf16(a[i], b[j], acc[i][j], 0, 0, 0);
}

// copy a full 128x128 u16 tile from LDS (row-major) to global rows of ld.
__device__ __forceinline__ void copy_out128(
    const u16* buf, u16* g, size_t ld, int tid) {
#pragma unroll
  for (int s = 0; s < 8; ++s) {
    const int off = (s * 256 + tid) * 8;
    const int row = off >> 7, col = off & 127;
    *(u16x8*)&g[(size_t)row * ld + col] = *(const u16x8*)&buf[off];
  }
}

#define GEMM_SMEM \
  __shared__ __attribute__((aligned(16))) u16 smem[32768];

#define GEMM_VARS()                                                \
  const int tid = threadIdx.x;                                     \
  const int w = tid >> 6, lane = tid & 63;                         \
  const int wr = w >> 1, wc = w & 1;                               \
  const int col16 = lane & 15, quad = lane >> 4;                   \
  f32x4 acc[4][4];                                                 \
  _Pragma("unroll") for (int i = 0; i < 4; ++i)                    \
  _Pragma("unroll") for (int j = 0; j < 4; ++j)                    \
      acc[i][j] = (f32x4){0.f, 0.f, 0.f, 0.f};

#define GEMM_PROLOGUE() GEMM_SMEM GEMM_VARS()

// Double-buffered, counted-vmcnt pipelined K loop, BK=64:
// 32 MFMA per barrier-pair, 8 async16/thread/phase, vmcnt(8).
#define PIPELINED_K_LOOP64(ABASE, ALD, BBASE, BLD, KTOT)                    \
  {                                                                         \
    stage128x32((ABASE), (ALD), smem, tid);                                 \
    stage128x32((ABASE) + 32, (ALD), smem + 4096, tid);                     \
    stage128x32((BBASE), (BLD), smem + 8192, tid);                          \
    stage128x32((BBASE) + 32, (BLD), smem + 12288, tid);                    \
    const int np_ = (KTOT) / 64;                                            \
    for (int pp_ = 0; pp_ < np_; ++pp_) {                                   \
      u16* cb_ = (pp_ & 1) ? smem + 16384 : smem;                           \
      u16* nb_ = (pp_ & 1) ? smem : smem + 16384;                           \
      if (pp_ + 1 < np_) {                                                  \
        const int kn_ = (pp_ + 1) * 64;                                     \
        stage128x32((ABASE) + kn_, (ALD), nb_, tid);                        \
        stage128x32((ABASE) + kn_ + 32, (ALD), nb_ + 4096, tid);            \
        stage128x32((BBASE) + kn_, (BLD), nb_ + 8192, tid);                 \
        stage128x32((BBASE) + kn_ + 32, (BLD), nb_ + 12288, tid);           \
        asm volatile("s_waitcnt vmcnt(8)" ::: "memory");                    \
      } else {                                                              \
        asm volatile("s_waitcnt vmcnt(0)" ::: "memory");                    \
      }                                                                     \
      __builtin_amdgcn_s_barrier();                                         \
      __builtin_amdgcn_sched_barrier(0);                                    \
      mfma_step(cb_, cb_ + 8192, wr, wc, lane, acc);                        \
      mfma_step(cb_ + 4096, cb_ + 12288, wr, wc, lane, acc);                \
      __builtin_amdgcn_sched_barrier(0);                                    \
      __builtin_amdgcn_s_barrier();                                         \
    }                                                                       \
  }

// ---------------------------------------------------------------------------
// tcvt body: transpose-convert a 32x32 fp32 tile to bf16.
// ---------------------------------------------------------------------------
__device__ __forceinline__ void tcvt_body(
    const float* __restrict__ ip, u16* __restrict__ op, int R, int C,
    int bx, int by, int tid, float (*tile)[33]) {
  const int c0 = bx * 32, r0 = by * 32;
  const int tx = tid & 31, ty = tid >> 5;
#pragma unroll
  for (int p = 0; p < 4; ++p)
    tile[ty + p * 8][tx] = ip[(size_t)(r0 + ty + p * 8) * C + c0 + tx];
  __syncthreads();
#pragma unroll
  for (int p = 0; p < 4; ++p)
    op[(size_t)(c0 + ty + p * 8) * R + r0 + tx] = f2b(tile[tx][ty + p * 8]);
}

// ---------------------------------------------------------------------------
// k_prep: ALL one-time conversions fused into one launch.
// ---------------------------------------------------------------------------
__global__ __launch_bounds__(256) void k_prep(
    const float* __restrict__ x, u16* __restrict__ X16, u16* __restrict__ XT16,
    const float* __restrict__ enc, u16* __restrict__ ENCT,
    const float* __restrict__ encv, u16* __restrict__ ENCVT,
    const float* __restrict__ dec, u16* __restrict__ DECT,
    float2* __restrict__ CS) {
  __shared__ float tile[32][33];
  const int tid = threadIdx.x;
  const int bid = blockIdx.x;
  if (bid < 3072) {
    const size_t i = ((size_t)bid * 256 + tid) * 4;
    float4 v = *(const float4*)&x[i];
    u16 o[4] = {f2b(v.x), f2b(v.y), f2b(v.z), f2b(v.w)};
    *(ushort4*)&X16[i] = *(ushort4*)o;
  } else if (bid < 6144) {
    const int b = bid - 3072;
    const int bz = b / 1536, rb = b % 1536;
    tcvt_body(x + (size_t)bz * TT * DD, XT16 + (size_t)bz * DD * TT,
              TT, DD, rb % 24, rb / 24, tid, tile);
  } else if (bid < 8448) {
    const int b = bid - 6144;
    const int bz = b / 192, rb = b % 192;
    tcvt_body(enc + (size_t)bz * DD * NN, ENCT + (size_t)bz * NN * DD,
              DD, NN, rb % 8, rb / 8, tid, tile);
  } else if (bid < 10752) {
    const int b = bid - 8448;
    const int bz = b / 192, rb = b % 192;
    tcvt_body(encv + (size_t)bz * DD * NN, ENCVT + (size_t)bz * NN * DD,
              DD, NN, rb % 8, rb / 8, tid, tile);
  } else if (bid < 13056) {
    const int b = bid - 10752;
    tcvt_body(dec, DECT, NHH * NN, DD, b % 24, b / 24, tid, tile);
  } else {
    const int idx = (bid - 13056) * 256 + tid;   // t*128 + n2
    const int t = idx >> 7, n2 = idx & 127;
    const float freq = exp2f((float)(2 * n2) * -0.0625f) * 0.15915494309189535f;
    const float phase = (float)t * freq;
    const float ph = (phase - floorf(phase)) * 6.283185307179586f;
    CS[idx] = make_float2(__cosf(ph), __sinf(ph));
  }
}

__global__ __launch_bounds__(256) void k_colsum(
    const u16* __restrict__ encvt, float* __restrict__ colsum) {
  const int row = blockIdx.x * 4 + (threadIdx.x >> 6);
  const int lane = threadIdx.x & 63;
  const u16* pr = encvt + (size_t)row * DD;
  float s = 0.f;
#pragma unroll
  for (int i = 0; i < 3; ++i) {
    ushort4 v = *(const ushort4*)&pr[(lane << 2) + i * 256];
    s += b2f(v.x) + b2f(v.y) + b2f(v.z) + b2f(v.w);
  }
#pragma unroll
  for (int off = 32; off; off >>= 1) s += __shfl_xor(s, off);
  if (lane == 0) colsum[row] = s;
}

// ---------------------------------------------------------------------------
// K1: latent = X16 @ ENCT[h]^T; relu; rope -> QR16 [b][h][t][n] AND
// QRT16 [b][h][n][t].  BK=64 pipeline; XOR-swizzled epilogue tile for the
// QRT column read.
// ---------------------------------------------------------------------------
__device__ __forceinline__ int swz8(int row) { return ((row >> 3) & 7) << 3; }

__global__ __launch_bounds__(256) void k1_encode(
    const u16* __restrict__ x16, const u16* __restrict__ enct,
    const float2* __restrict__ CS,
    u16* __restrict__ qr16, u16* __restrict__ qrt16) {
  const int h = blockIdx.z;
  const int m0 = blockIdx.x * 128, n0 = blockIdx.y * 128;
  GEMM_PROLOGUE();
  PIPELINED_K_LOOP64(x16 + (size_t)m0 * DD, DD,
                     enct + ((size_t)h * NN + n0) * DD, DD, DD);
  __syncthreads();
#pragma unroll
  for (int i = 0; i < 4; ++i)
#pragma unroll
    for (int j = 0; j < 4; ++j) {
      const int n = n0 + wc * 64 + j * 16 + col16;
      float rv[4], pv[4];
#pragma unroll
      for (int r = 0; r < 4; ++r) rv[r] = fmaxf(acc[i][j][r], 0.f);
#pragma unroll
      for (int r = 0; r < 4; ++r) pv[r] = __shfl_xor(rv[r], 1);
#pragma unroll
      for (int r = 0; r < 4; ++r) {
        const int lrow = wr * 64 + i * 16 + quad * 4 + r;
        const int t = (m0 + lrow) & (TT - 1);
        const float2 cs = CS[t * 128 + (n >> 1)];
        const float o = (n & 1) ? (rv[r] * cs.x + pv[r] * cs.y)
                                : (rv[r] * cs.x - pv[r] * cs.y);
        smem[lrow * 128 + ((wc * 64 + j * 16 + col16) ^ swz8(lrow))] = f2b(o);
      }
    }
  __syncthreads();
  const int bq = m0 >> 11, tb = m0 & (TT - 1);
  const size_t sl = (size_t)(bq * NHH + h);
  // row-major copy (swizzle-aware source)
  u16* qg = qr16 + (sl * TT + tb) * NN + n0;
#pragma unroll
  for (int s = 0; s < 8; ++s) {
    const int off = (s * 256 + tid) * 8;
    const int row = off >> 7, col = off & 127;
    *(u16x8*)&qg[(size_t)row * NN + col] =
        *(const u16x8*)&smem[row * 128 + (col ^ swz8(row))];
  }
  // transposed copy: QRT16[sl][n][t] = tile[t][n]
#pragma unroll
  for (int s = 0; s < 8; ++s) {
    const int off = (s * 256 + tid) * 8;
    const int nr = off >> 7, tc = off & 127;
    const int sw = swz8(tc);                 // tc 8-aligned: same for tc..tc+7
    u16 vals[8];
#pragma unroll
    for (int k = 0; k < 8; ++k) vals[k] = smem[(tc + k) * 128 + (nr ^ sw)];
    *(u16x8*)&qrt16[(sl * NN + n0 + nr) * TT + tb + tc] = *(u16x8*)vals;
  }
}

// ---------------------------------------------------------------------------
// kSB: kS (S-band GEMM) and kB (H-state GEMM) FUSED into one launch.
// LPT ordering: kB blocks (K=1536, ~2.3x kS work) launch FIRST so the
// tail is filled by light kS blocks.
// Role split on blockIdx.x (block-uniform): [0,nB) = kB, [nB,..) = kS.
// ---------------------------------------------------------------------------
__global__ __launch_bounds__(256) void kSB(
    const u16* __restrict__ qr16, const u16* __restrict__ xt16,
    const u16* __restrict__ qrt16, u16* __restrict__ sb,
    u16* __restrict__ h16, int nB, int bh0) {
  GEMM_SMEM;
  const int tid = threadIdx.x;
  const int w = tid >> 6, lane = tid & 63;
  const int col16 = lane & 15, quad = lane >> 4;
  if ((int)blockIdx.x >= nB) {
    // ---------------- kS role: S = QR QR^T band tile ----------------
    const int rS = blockIdx.x - nB;
    const int wr = w >> 1, wc = w & 1;
    const int z = rS / 40, sub = rS % 40;
    const int bh = bh0 + z;
    const int cc = sub / 10, rr = sub % 10;
    int i = (int)((sqrtf(8.f * rr + 1.f) - 1.f) * 0.5f);
    while ((i + 1) * (i + 2) / 2 <= rr) ++i;
    while (i * (i + 1) / 2 > rr) --i;
    const int j = rr - i * (i + 1) / 2;
    const int t0 = (cc * 4 + i) * 128;
    const int s0 = cc * CH + j * 128;
    const u16* q = qr16 + (size_t)bh * TT * NN;
    f32x4 acc[4][4];
#pragma unroll
    for (int a = 0; a < 4; ++a)
#pragma unroll
      for (int b = 0; b < 4; ++b) acc[a][b] = (f32x4){0.f, 0.f, 0.f, 0.f};
    PIPELINED_K_LOOP64(q + (size_t)t0 * NN, NN, q + (size_t)s0 * NN, NN, NN);
    const bool diag = (i == j);
    __syncthreads();
#pragma unroll
    for (int ii = 0; ii < 4; ++ii)
#pragma unroll
      for (int jj = 0; jj < 4; ++jj) {
        const int s = s0 + wc * 64 + jj * 16 + col16;
#pragma unroll
        for (int r = 0; r < 4; ++r) {
          const int lrow = wr * 64 + ii * 16 + quad * 4 + r;
          const int t = t0 + lrow;
          float v = acc[ii][jj][r];
          if (diag && s >= t) v = 0.f;
          smem[lrow * 128 + wc * 64 + jj * 16 + col16] = f2b(v);
        }
      }
    __syncthreads();
    copy_out128(smem, sb + ((size_t)z * TT + t0) * CH + j * 128, CH, tid);
  } else {
    // ---------------- kB role: H chunk-prefix GEMM ----------------
    const int r2 = blockIdx.x;
    const int z = r2 / 24, rr2 = r2 % 24;
    const int d0 = (rr2 % 12) * 64, n0 = (rr2 / 12) * 128;
    const int bh = bh0 + z, b = bh / NHH;
    u16* buf0 = smem;          // A0 +0, A1 +2048, B0 +4096, B1 +8192
    u16* buf1 = smem + 12288;
    u16* snap = smem + 24576;  // 64x128 u16
    f32x4 acc[4][2];
#pragma unroll
    for (int i = 0; i < 4; ++i)
#pragma unroll
      for (int j = 0; j < 2; ++j) acc[i][j] = (f32x4){0.f, 0.f, 0.f, 0.f};
    const u16* Ab = xt16 + ((size_t)b * DD + d0) * TT;
    const u16* Bb = qrt16 + ((size_t)bh * NN + n0) * TT;
#define KB_STAGE(buf, k0)                                                   \
  {                                                                         \
    stage64x32(Ab + (k0), TT, (buf), tid);                                  \
    stage64x32(Ab + (k0) + 32, TT, (buf) + 2048, tid);                      \
    stage128x32(Bb + (k0), TT, (buf) + 4096, tid);                          \
    stage128x32(Bb + (k0) + 32, TT, (buf) + 8192, tid);                     \
  }
    for (int c = 0; c < 3; ++c) {
      const int kbase = c * CH;
      KB_STAGE(buf0, kbase);
      for (int s = 0; s < CH / 64; ++s) {
        u16* cb = (s & 1) ? buf1 : buf0;
        u16* nb = (s & 1) ? buf0 : buf1;
        if (s + 1 < CH / 64) {
          KB_STAGE(nb, kbase + (s + 1) * 64);
          asm volatile("s_waitcnt vmcnt(6)" ::: "memory");
        } else {
          asm volatile("s_waitcnt vmcnt(0)" ::: "memory");
        }
        __builtin_amdgcn_s_barrier();
        __builtin_amdgcn_sched_barrier(0);
#pragma unroll
        for (int half = 0; half < 2; ++half) {
          bf16x8 a[4], bb[2];
#pragma unroll
          for (int i = 0; i < 4; ++i) {
            const int row = i * 16 + col16;
            a[i] = *(const bf16x8*)&cb[half * 2048 + row * 32 +
                                       ((quad ^ KSWZ(row)) << 3)];
          }
#pragma unroll
          for (int j = 0; j < 2; ++j) {
            const int row = w * 32 + j * 16 + col16;
            bb[j] = *(const bf16x8*)&cb[4096 + half * 4096 + row * 32 +
                                        ((quad ^ KSWZ(row)) << 3)];
          }
#pragma unroll
          for (int i = 0; i < 4; ++i)
#pragma unroll
            for (int j = 0; j < 2; ++j)
              acc[i][j] = __builtin_amdgcn_mfma_f32_16x16x32_bf16(a[i], bb[j], acc[i][j], 0, 0, 0);
        }
        __builtin_amdgcn_sched_barrier(0);
        __builtin_amdgcn_s_barrier();
      }
      // snapshot H16[z][c]
#pragma unroll
      for (int i = 0; i < 4; ++i)
#pragma unroll
        for (int j = 0; j < 2; ++j)
#pragma unroll
          for (int r = 0; r < 4; ++r)
            snap[(i * 16 + quad * 4 + r) * 128 + w * 32 + j * 16 + col16] =
                f2b(acc[i][j][r]);
      __syncthreads();
      u16* hd = h16 + (size_t)(z * 3 + c) * DD * NN;
#pragma unroll
      for (int s4 = 0; s4 < 4; ++s4) {
        const int off = (s4 * 256 + tid) * 8;
        const int row = off >> 7, col = off & 127;
        *(u16x8*)&hd[(size_t)(d0 + row) * NN + n0 + col] = *(const u16x8*)&snap[off];
      }
      __syncthreads();
    }
#undef KB_STAGE
  }
}

// ---------------------------------------------------------------------------
// kA: 128x128 output, unified panel-pipelined K sequence.
// 1D grid, bijective chunked XCD swizzle (T1) + LPT tt order.
// Fused stats v3: Σ/Σ² ride the copy-out register stream; padded LDS
// scratch; one coalesced dblk-major float2 store per row.
// ---------------------------------------------------------------------------
__device__ static const int TTORD[16] = {15, 11, 7, 14, 10, 6, 13, 9,
                                         5, 3, 12, 8, 4, 2, 1, 0};

__global__ __launch_bounds__(256) void kA_attn(
    const u16* __restrict__ qr16, const u16* __restrict__ h16,
    const u16* __restrict__ sb, const u16* __restrict__ xt16,
    u16* __restrict__ ykv16, float2* __restrict__ PART, int gsTT, int bh0) {
  GEMM_SMEM;
  const int tid = threadIdx.x;
  const int w = tid >> 6, lane = tid & 63;
  const int wr = w >> 1, wc = w & 1;
  const int col16 = lane & 15, quad = lane >> 4;
  const int nwg = gridDim.x;
  const int bid = blockIdx.x;
  const int qn = nwg >> 3, r8 = nwg & 7;
  const int xcd = bid & 7, pos = bid >> 3;
  const int wg = (xcd < r8 ? xcd * (qn + 1) : r8 * (qn + 1) + (xcd - r8) * qn) + pos;
  const int z = wg / 96;
  const int tt = TTORD[(wg / 6) & 15];       // LPT within chunk
  const int dblk = wg % 6;
  const int d0 = dblk * 128;
  const int bh = bh0 + z, b = bh / NHH;
  const int c = tt >> 2, it = tt & 3;
  const int t0 = tt * 128;
  f32x4 acc[4][4];
#pragma unroll
  for (int i = 0; i < 4; ++i)
#pragma unroll
    for (int j = 0; j < 4; ++j) acc[i][j] = (f32x4){0.f, 0.f, 0.f, 0.f};

  const int c4 = (c > 0) ? 4 : 0;
  const int nP = c4 + (it + 1) * 2;          // BK=64 panels total
  const u16* hs = h16 + ((size_t)(z * 3 + (c > 0 ? c - 1 : 0)) * DD + d0) * NN;
  const u16* qb = qr16 + ((size_t)bh * TT + t0) * NN;
  const u16* sbb = sb + ((size_t)z * TT + t0) * CH;
  const u16* xb = xt16 + ((size_t)b * DD + d0) * TT + c * CH;

#define KA_STAGE(buf, p)                                                  \
  {                                                                       \
    const u16 *pa_, *pb_; size_t la_, lb_;                                \
    if ((p) < c4) {                                                       \
      pa_ = qb + (p) * 64; la_ = NN;                                      \
      pb_ = hs + (p) * 64; lb_ = NN;                                      \
    } else {                                                              \
      const int q_ = (p) - c4;                                            \
      const int j_ = q_ >> 1, kk_ = (q_ & 1) << 6;                        \
      pa_ = sbb + j_ * 128 + kk_; la_ = CH;                               \
      pb_ = xb + j_ * 128 + kk_; lb_ = TT;                                \
    }                                                                     \
    stage128x32(pa_, la_, (buf), tid);                                    \
    stage128x32(pa_ + 32, la_, (buf) + 4096, tid);                        \
    stage128x32(pb_, lb_, (buf) + 8192, tid);                             \
    stage128x32(pb_ + 32, lb_, (buf) + 12288, tid);                       \
  }

  u16* bufA = smem;
  u16* bufB = smem + 16384;
  KA_STAGE(bufA, 0);
  for (int p = 0; p < nP; ++p) {
    u16* cb = (p & 1) ? bufB : bufA;
    u16* nb = (p & 1) ? bufA : bufB;
    if (p + 1 < nP) {
      KA_STAGE(nb, p + 1);
      asm volatile("s_waitcnt vmcnt(8)" ::: "memory");
    } else {
      asm volatile("s_waitcnt vmcnt(0)" ::: "memory");
    }
    __builtin_amdgcn_s_barrier();            // publish panel p across waves
    __builtin_amdgcn_sched_barrier(0);
    mfma_step(cb, cb + 8192, wr, wc, lane, acc);
    mfma_step(cb + 4096, cb + 12288, wr, wc, lane, acc);
    __builtin_amdgcn_sched_barrier(0);
    __builtin_amdgcn_s_barrier();            // reads of cb done before overwrite
  }
#undef KA_STAGE

  __syncthreads();
#pragma unroll
  for (int i = 0; i < 4; ++i)
#pragma unroll
    for (int j = 0; j < 4; ++j)
#pragma unroll
      for (int r = 0; r < 4; ++r) {
        const int lrow = wr * 64 + i * 16 + quad * 4 + r;
        smem[lrow * 128 + wc * 64 + j * 16 + col16] = f2b(acc[i][j][r]);
      }
  __syncthreads();
  // copy-out + per-chunk stats.
  float2* scratch = (float2*)&smem[16384];   // [128][17] padded
  u16* yg = ykv16 + ((size_t)z * TT + t0) * DD + d0;
#pragma unroll
  for (int s = 0; s < 8; ++s) {
    const int off = (s * 256 + tid) * 8;
    const int row = off >> 7, col = off & 127;
    const u16x8 v = *(const u16x8*)&smem[off];
    *(u16x8*)&yg[(size_t)row * DD + col] = v;
    float ps = 0.f, pq = 0.f;
#pragma unroll
    for (int k = 0; k < 8; ++k) {
      const float f = b2f(v[k]);
      ps += f;
      pq += f * f;
    }
    scratch[row * 17 + (tid & 15)] = make_float2(ps, pq);
  }
  __syncthreads();
  if (tid < 128) {
    const float2* pr = &scratch[tid * 17];
    float s = 0.f, q2 = 0.f;
#pragma unroll
    for (int k = 0; k < 16; ++k) { s += pr[k].x; q2 += pr[k].y; }
    PART[(size_t)dblk * gsTT + z * TT + t0 + tid] = make_float2(s, q2);
  }
}

// ---------------------------------------------------------------------------
// K4: raw GEMM ykv16 @ ENCVT[h]^T with LN as epilogue affine; row stats
// folded INLINE from PART; xs via inverse rope of QR16 (CS table).
// QR tile prefetch OVERLAPPED with the final K-phase: np=12 is even so
// the final phase consumes bufB -> issue QR asyncs into the free bufA
// and wait only vmcnt(8) (panel loads) before the final MFMA cluster.
// Epilogue: QR read from bufA, val tile built in bufB, copied out.
// ---------------------------------------------------------------------------
__global__ __launch_bounds__(256) void k4_xy(
    const u16* __restrict__ ykv16, const u16* __restrict__ encvt,
    const float2* __restrict__ CS,
    u16* __restrict__ qrxy, const float2* __restrict__ PART,
    const float* __restrict__ colsum,
    float* __restrict__ out2, int gsTT, int bh0) {
  const int z = blockIdx.z;
  const int bh = bh0 + z, h = bh % NHH;
  const int t0 = blockIdx.x * 128, n0 = blockIdx.y * 128;
  GEMM_PROLOGUE();
  const u16* Ab = ykv16 + ((size_t)z * TT + t0) * DD;
  const u16* Bb = encvt + ((size_t)h * NN + n0) * DD;
  const u16* qg = qrxy + ((size_t)bh * TT + t0) * NN + n0;
  stage128x32(Ab, DD, smem, tid);
  stage128x32(Ab + 32, DD, smem + 4096, tid);
  stage128x32(Bb, DD, smem + 8192, tid);
  stage128x32(Bb + 32, DD, smem + 12288, tid);
  const int np = DD / 64;                    // 12 (even)
  for (int pp = 0; pp < np; ++pp) {
    u16* cb = (pp & 1) ? smem + 16384 : smem;
    u16* nb = (pp & 1) ? smem : smem + 16384;
    if (pp + 1 < np) {
      const int kn = (pp + 1) * 64;
      stage128x32(Ab + kn, DD, nb, tid);
      stage128x32(Ab + kn + 32, DD, nb + 4096, tid);
      stage128x32(Bb + kn, DD, nb + 8192, tid);
      stage128x32(Bb + kn + 32, DD, nb + 12288, tid);
      asm volatile("s_waitcnt vmcnt(8)" ::: "memory");
    } else {
      // final phase: prefetch QR tile into the free buffer (bufA).
#pragma unroll
      for (int s = 0; s < 8; ++s) {
        const int row = s * 16 + w * 4 + (lane >> 4);
        const int col = (lane & 15) * 8;
        async16(qg + (size_t)row * NN + col, smem + (s * 256 + w * 64) * 8);
      }
      asm volatile("s_waitcnt vmcnt(8)" ::: "memory");
    }
    __builtin_amdgcn_s_barrier();
    __builtin_amdgcn_sched_barrier(0);
    mfma_step(cb, cb + 8192, wr, wc, lane, acc);
    mfma_step(cb + 4096, cb + 12288, wr, wc, lane, acc);
    __builtin_amdgcn_sched_barrier(0);
    __builtin_amdgcn_s_barrier();
  }
  asm volatile("s_waitcnt vmcnt(0)" ::: "memory");   // QR landed
  __syncthreads();
#pragma unroll
  for (int i = 0; i < 4; ++i) {
    float muv[4], rsv[4];
#pragma unroll
    for (int r = 0; r < 4; ++r) {
      const int grow = z * TT + t0 + wr * 64 + i * 16 + quad * 4 + r;
      float s_ = 0.f, q_ = 0.f;
#pragma unroll
      for (int d = 0; d < 6; ++d) {
        const float2 p2 = PART[(size_t)d * gsTT + grow];
        s_ += p2.x;
        q_ += p2.y;
      }
      const float m_ = s_ * (1.f / 768.f);
      muv[r] = m_;
      rsv[r] = rsqrtf(q_ * (1.f / 768.f) - m_ * m_ + 1e-5f);
    }
#pragma unroll
    for (int j = 0; j < 4; ++j) {
      const int lcol = wc * 64 + j * 16 + col16;
      const int n = n0 + lcol;
      const float csum = colsum[h * NN + n];
#pragma unroll
      for (int r = 0; r < 4; ++r) {
        const int lrow = wr * 64 + i * 16 + quad * 4 + r;
        const int t = t0 + lrow;
        const float ys = fmaxf(rsv[r] * acc[i][j][r] - rsv[r] * muv[r] * csum, 0.f);
        const unsigned pq =
            *(const unsigned*)&smem[lrow * 128 + (lcol & ~1)];
        const float lo = b2f((u16)pq), hi = b2f((u16)(pq >> 16));
        const float2 cs = CS[t * 128 + (n >> 1)];
        const float xs = (n & 1) ? (hi * cs.x - lo * cs.y)
                                 : (lo * cs.x + hi * cs.y);
        const float val = ys * xs;
        out2[((size_t)bh * TT + t) * NN + n] = val;
        smem[16384 + lrow * 128 + lcol] = f2b(val);
      }
    }
  }
  __syncthreads();
  copy_out128(smem + 16384, qrxy + ((size_t)bh * TT + t0) * NN + n0, NN, tid);
}

// ---------------------------------------------------------------------------
// K5: ymlp = flat(XY) @ DECT^T.  M=4096, N=768, K=3072.  128x128 tiles,
// BK=64 dbuf + vmcnt(8), SPLIT-K=2: each output tile computed by two
// blocks (K halves 0..1535 / 1536..3071) writing fp32 partials to
// ymp0/ymp1; k6 sums them.  Grid 384 = 1.5 blocks/CU restores the
// inter-block overlap that hides the 2-phase stalls (192 was 0.75/CU).
// ---------------------------------------------------------------------------
__global__ __launch_bounds__(256) void k5_mlp(
    const u16* __restrict__ xyq, const u16* __restrict__ dect,
    float* __restrict__ ymp0, float* __restrict__ ymp1) {
  GEMM_PROLOGUE();
  const int bid = blockIdx.x;                // 384 = 8 XCD x 48
  const int wg = (bid & 7) * 48 + (bid >> 3);
  const int kh = wg / 192;                   // K half
  const int r = wg % 192;
  const int m0 = (r / 6) * 128, d0 = (r % 6) * 128;
  const int b = m0 >> 11, t0 = m0 & (TT - 1);
  const int kbase = kh * 1536;
#define K5_ST(buf, p)                                                       \
  {                                                                         \
    const int k0_ = kbase + (p) * 64, hh_ = k0_ >> 8, kk_ = k0_ & 255;      \
    const u16* pa_ = xyq + ((size_t)(b * NHH + hh_) * TT + t0) * NN + kk_;  \
    const u16* pb_ = dect + (size_t)d0 * (NHH * NN) + k0_;                  \
    stage128x32(pa_, NN, (buf), tid);                                       \
    stage128x32(pa_ + 32, NN, (buf) + 4096, tid);                           \
    stage128x32(pb_, NHH * NN, (buf) + 8192, tid);                          \
    stage128x32(pb_ + 32, NHH * NN, (buf) + 12288, tid);                    \
  }
  const int NP = 1536 / 64;                  // 24 panels per half
  u16* bufA = smem;
  u16* bufB = smem + 16384;
  K5_ST(bufA, 0);
  for (int p = 0; p < NP; ++p) {
    u16* cb = (p & 1) ? bufB : bufA;
    u16* nb = (p & 1) ? bufA : bufB;
    if (p + 1 < NP) {
      K5_ST(nb, p + 1);
      asm volatile("s_waitcnt vmcnt(8)" ::: "memory");
    } else {
      asm volatile("s_waitcnt vmcnt(0)" ::: "memory");
    }
    __builtin_amdgcn_s_barrier();
    __builtin_amdgcn_sched_barrier(0);
    mfma_step(cb, cb + 8192, wr, wc, lane, acc);
    mfma_step(cb + 4096, cb + 12288, wr, wc, lane, acc);
    __builtin_amdgcn_sched_barrier(0);
    __builtin_amdgcn_s_barrier();
  }
#undef K5_ST
  float* ymlp = kh ? ymp1 : ymp0;
#pragma unroll
  for (int i = 0; i < 4; ++i)
#pragma unroll
    for (int j = 0; j < 4; ++j) {
      const int d = d0 + wc * 64 + j * 16 + col16;
#pragma unroll
      for (int r4 = 0; r4 < 4; ++r4) {
        const int mm = m0 + wr * 64 + i * 16 + quad * 4 + r4;
        ymlp[(size_t)mm * DD + d] = acc[i][j][r4];
      }
    }
}

// ---------------------------------------------------------------------------
// K6: v = ym0+ym1 (split-K partials); y = ln(v)*sqrt(0.1/(ra+1e-6))*scale;
// out1 = ln(x+y).  Block per row; ym0 aliases out1 (in-place per row).
// ---------------------------------------------------------------------------
__global__ __launch_bounds__(256) void k6_final(
    const float* __restrict__ ym0, const float* __restrict__ ym1,
    const float* __restrict__ x,
    const float* __restrict__ scale, const float* __restrict__ ra,
    float* __restrict__ out1) {
  const int row = blockIdx.x;
  const int tid = threadIdx.x;
  const int wid = tid >> 6, lane = tid & 63;
  __shared__ float red[8];
  float v[3];
  float sum = 0.f, sq = 0.f;
#pragma unroll
  for (int j = 0; j < 3; ++j) {
    const size_t idx = (size_t)row * DD + tid + j * 256;
    v[j] = ym0[idx] + ym1[idx];
    sum += v[j]; sq += v[j] * v[j];
  }
#pragma unroll
  for (int off = 32; off; off >>= 1) { sum += __shfl_xor(sum, off); sq += __shfl_xor(sq, off); }
  if (lane == 0) { red[wid] = sum; red[4 + wid] = sq; }
  __syncthreads();
  sum = red[0] + red[1] + red[2] + red[3];
  sq = red[4] + red[5] + red[6] + red[7];
  const float m1 = sum * (1.f / 768.f);
  const float r1 = rsqrtf(sq * (1.f / 768.f) - m1 * m1 + 1e-5f);
  float z[3];
  float sum2 = 0.f, sq2 = 0.f;
#pragma unroll
  for (int j = 0; j < 3; ++j) {
    const int d = tid + j * 256;
    float y = (v[j] - m1) * r1 * sqrtf(0.1f / (ra[d] + 1e-6f)) * scale[d];
    z[j] = x[(size_t)row * DD + d] + y;
    sum2 += z[j]; sq2 += z[j] * z[j];
  }
  __syncthreads();
#pragma unroll
  for (int off = 32; off; off >>= 1) { sum2 += __shfl_xor(sum2, off); sq2 += __shfl_xor(sq2, off); }
  if (lane == 0) { red[wid] = sum2; red[4 + wid] = sq2; }
  __syncthreads();
  sum2 = red[0] + red[1] + red[2] + red[3];
  sq2 = red[4] + red[5] + red[6] + red[7];
  const float m2 = sum2 * (1.f / 768.f);
  const float r2 = rsqrtf(sq2 * (1.f / 768.f) - m2 * m2 + 1e-5f);
#pragma unroll
  for (int j = 0; j < 3; ++j)
    out1[(size_t)row * DD + tid + j * 256] = (z[j] - m2) * r2;
}

// ---------------------------------------------------------------------------
extern "C" void kernel_launch(void* const* d_in, const int* in_sizes, int n_in,
                              void* d_out, int out_size, void* d_ws, size_t ws_size,
                              hipStream_t stream) {
  const float* x = (const float*)d_in[0];
  const float* enc = (const float*)d_in[1];
  const float* encv = (const float*)d_in[2];
  const float* dec = (const float*)d_in[3];
  const float* scale = (const float*)d_in[4];
  const float* ra = (const float*)d_in[5];
  float* out1 = (float*)d_out;
  float* out2 = out1 + (size_t)BB * TT * DD;
  float* ym0 = out1;                          // k5 half-0 partial, k6 in-place

  const int NS = BB * NHH;  // 24 slices
  unsigned char* p = (unsigned char*)d_ws;
  u16* X16 = (u16*)p;    p += (size_t)BB * TT * DD * 2;
  u16* XT16 = (u16*)p;   p += (size_t)BB * DD * TT * 2;
  u16* ENCT = (u16*)p;   p += (size_t)NHH * NN * DD * 2;
  u16* ENCVT = (u16*)p;  p += (size_t)NHH * NN * DD * 2;
  u16* DECT = (u16*)p;   p += (size_t)DD * NHH * NN * 2;
  u16* QR16 = (u16*)p;   p += (size_t)NS * TT * NN * 2;   // holds QR, then XY
  u16* QRT16 = (u16*)p;  p += (size_t)NS * NN * TT * 2;
  float* COLSUM = (float*)p; p += (size_t)NHH * NN * 4;
  float2* CS = (float2*)p;   p += (size_t)TT * (NN / 2) * sizeof(float2);
  float* YM1 = (float*)p;    p += (size_t)BB * TT * DD * 4;  // k5 half-1 partial
  // Per-slice pool: SB + H16 + YKV16 + PART(48B/row)
  const size_t SLICE_B = (size_t)TT * CH * 2 + 3 * (size_t)DD * NN * 2 +
                         (size_t)TT * DD * 2 + (size_t)TT * 48;
  size_t fixed = (size_t)(p - (unsigned char*)d_ws);
  size_t rem = (ws_size > fixed) ? ws_size - fixed : 0;
  int GSmax = (int)(rem / SLICE_B);
  if (GSmax < 1) GSmax = 1;
  if (GSmax > NS) GSmax = NS;
  const int ngrp = (NS + GSmax - 1) / GSmax;
  const int GS = (NS + ngrp - 1) / ngrp;     // balanced groups
  u16* SB = (u16*)p;     p += (size_t)GS * TT * CH * 2;
  u16* H16 = (u16*)p;    p += (size_t)GS * 3 * DD * NN * 2;
  u16* YKV16 = (u16*)p;  p += (size_t)GS * TT * DD * 2;
  float2* PART = (float2*)p; p += (size_t)GS * TT * 6 * sizeof(float2);
  const int gsTT = GS * TT;

  // One-time conversions / transposes / tables: single fused launch,
  // then colsum (reads ENCVT -> separate dispatch).
  k_prep<<<dim3(14080), 256, 0, stream>>>(
      x, X16, XT16, enc, ENCT, encv, ENCVT, dec, DECT, CS);
  k_colsum<<<dim3(NHH * NN / 4), 256, 0, stream>>>(ENCVT, COLSUM);

  k1_encode<<<dim3(BB * TT / 128, NN / 128, NHH), 256, 0, stream>>>(
      X16, ENCT, CS, QR16, QRT16);

  for (int bh0 = 0; bh0 < NS; bh0 += GS) {
    const int gs = imin(GS, NS - bh0);
    kSB<<<dim3(64 * gs), 256, 0, stream>>>(
        QR16, XT16, QRT16, SB, H16, 24 * gs, bh0);
    kA_attn<<<dim3(96 * gs), 256, 0, stream>>>(
        QR16, H16, SB, XT16, YKV16, PART, gsTT, bh0);
    k4_xy<<<dim3(TT / 128, NN / 128, gs), 256, 0, stream>>>(
        YKV16, ENCVT, CS, QR16, PART, COLSUM, out2, gsTT, bh0);
  }

  k5_mlp<<<dim3(384), 256, 0, stream>>>(QR16, DECT, ym0, YM1);
  k6_final<<<dim3(BB * TT), 256, 0, stream>>>(ym0, YM1, x, scale, ra, out1);
}

// Round 10
// 332.411 us; speedup vs baseline: 1.1473x; 1.0423x over previous
//
#include <hip/hip_runtime.h>
#include <math.h>

#define TT 2048
#define DD 768
#define NN 256
#define NHH 12
#define BB 2
#define CH 512           // attention chunk (4 chunks of 4 x 128-tiles)

typedef unsigned short u16;
typedef __attribute__((ext_vector_type(8))) short bf16x8;
typedef __attribute__((ext_vector_type(8))) unsigned short u16x8;
typedef __attribute__((ext_vector_type(4))) float f32x4;

static inline int imin(int a, int b) { return a < b ? a : b; }

__device__ __forceinline__ u16 f2b(float f) {
  union { float f; unsigned u; } a; a.f = f;
  unsigned r = a.u + 0x7FFF + ((a.u >> 16) & 1);
  return (u16)(r >> 16);
}
__device__ __forceinline__ float b2f(u16 h) {
  union { unsigned u; float f; } a; a.u = ((unsigned)h) << 16;
  return a.f;
}

__device__ __forceinline__ void async16(const void* g, void* l) {
  __builtin_amdgcn_global_load_lds(
      (const __attribute__((address_space(1))) unsigned*)g,
      (__attribute__((address_space(3))) unsigned*)l, 16, 0, 0);
}

// K-chunk XOR swizzle: LDS stays linear; the global SOURCE chunk is
// pre-swizzled at stage time and the SAME XOR is applied on every
// fragment read.  chunk' = chunk ^ ((row>>1)&3) gives 2-way bank
// aliasing on ds_read_b128 (free) vs 8-way unswizzled.
#define KSWZ(row) (((row) >> 1) & 3)

// Stage a 128x32 bf16 tile (row-major, ld in elements) into LDS [128][32],
// source-swizzled.
__device__ __forceinline__ void stage128x32(
    const u16* __restrict__ gbase, size_t ld, u16* lds, int tid) {
  const int w = tid >> 6, l = tid & 63;
#pragma unroll
  for (int q = 0; q < 2; ++q) {
    const int row = w * 32 + q * 16 + (l >> 2);
    const int kc = ((l & 3) ^ KSWZ(row)) << 3;
    async16(gbase + (size_t)row * ld + kc, lds + (w * 32 + q * 16) * 32);
  }
}

// 16 MFMAs of one BK=32 step; wave (wr,wc) computes 64x64 of the 128x128
// tile.  Fragment reads apply the chunk swizzle.
__device__ __forceinline__ void mfma_step(
    const u16* As, const u16* Bs, int wr, int wc, int lane, f32x4 acc[4][4]) {
  const int m16 = lane & 15, quad = lane >> 4;
  bf16x8 a[4], b[4];
#pragma unroll
  for (int i = 0; i < 4; ++i) {
    const int row = wr * 64 + i * 16 + m16;
    a[i] = *(const bf16x8*)&As[row * 32 + ((quad ^ KSWZ(row)) << 3)];
  }
#pragma unroll
  for (int j = 0; j < 4; ++j) {
    const int row = wc * 64 + j * 16 + m16;
    b[j] = *(const bf16x8*)&Bs[row * 32 + ((quad ^ KSWZ(row)) << 3)];
  }
#pragma unroll
  for (int i = 0; i < 4; ++i)
#pragma unroll
    for (int j = 0; j < 4; ++j)
      acc[i][j] = __builtin_amdgcn_mfma_f32_16x16x32_bf16(a[i], b[j], acc[i][j], 0, 0, 0);
}

// copy a full 128x128 u16 tile from LDS (row-major) to global rows of ld.
__device__ __forceinline__ void copy_out128(
    const u16* buf, u16* g, size_t ld, int tid) {
#pragma unroll
  for (int s = 0; s < 8; ++s) {
    const int off = (s * 256 + tid) * 8;
    const int row = off >> 7, col = off & 127;
    *(u16x8*)&g[(size_t)row * ld + col] = *(const u16x8*)&buf[off];
  }
}

#define GEMM_SMEM \
  __shared__ __attribute__((aligned(16))) u16 smem[32768];

#define GEMM_VARS()                                                \
  const int tid = threadIdx.x;                                     \
  const int w = tid >> 6, lane = tid & 63;                         \
  const int wr = w >> 1, wc = w & 1;                               \
  const int col16 = lane & 15, quad = lane >> 4;                   \
  f32x4 acc[4][4];                                                 \
  _Pragma("unroll") for (int i = 0; i < 4; ++i)                    \
  _Pragma("unroll") for (int j = 0; j < 4; ++j)                    \
      acc[i][j] = (f32x4){0.f, 0.f, 0.f, 0.f};

#define GEMM_PROLOGUE() GEMM_SMEM GEMM_VARS()

// Double-buffered, counted-vmcnt pipelined K loop, BK=64:
// 32 MFMA per barrier-pair, 8 async16/thread/phase, vmcnt(8).
#define PIPELINED_K_LOOP64(ABASE, ALD, BBASE, BLD, KTOT)                    \
  {                                                                         \
    stage128x32((ABASE), (ALD), smem, tid);                                 \
    stage128x32((ABASE) + 32, (ALD), smem + 4096, tid);                     \
    stage128x32((BBASE), (BLD), smem + 8192, tid);                          \
    stage128x32((BBASE) + 32, (BLD), smem + 12288, tid);                    \
    const int np_ = (KTOT) / 64;                                            \
    for (int pp_ = 0; pp_ < np_; ++pp_) {                                   \
      u16* cb_ = (pp_ & 1) ? smem + 16384 : smem;                           \
      u16* nb_ = (pp_ & 1) ? smem : smem + 16384;                           \
      if (pp_ + 1 < np_) {                                                  \
        const int kn_ = (pp_ + 1) * 64;                                     \
        stage128x32((ABASE) + kn_, (ALD), nb_, tid);                        \
        stage128x32((ABASE) + kn_ + 32, (ALD), nb_ + 4096, tid);            \
        stage128x32((BBASE) + kn_, (BLD), nb_ + 8192, tid);                 \
        stage128x32((BBASE) + kn_ + 32, (BLD), nb_ + 12288, tid);           \
        asm volatile("s_waitcnt vmcnt(8)" ::: "memory");                    \
      } else {                                                              \
        asm volatile("s_waitcnt vmcnt(0)" ::: "memory");                    \
      }                                                                     \
      __builtin_amdgcn_s_barrier();                                         \
      __builtin_amdgcn_sched_barrier(0);                                    \
      mfma_step(cb_, cb_ + 8192, wr, wc, lane, acc);                        \
      mfma_step(cb_ + 4096, cb_ + 12288, wr, wc, lane, acc);                \
      __builtin_amdgcn_sched_barrier(0);                                    \
      __builtin_amdgcn_s_barrier();                                         \
    }                                                                       \
  }

// ---------------------------------------------------------------------------
// tcvt body: transpose-convert a 32x32 fp32 tile to bf16.
// ---------------------------------------------------------------------------
__device__ __forceinline__ void tcvt_body(
    const float* __restrict__ ip, u16* __restrict__ op, int R, int C,
    int bx, int by, int tid, float (*tile)[33]) {
  const int c0 = bx * 32, r0 = by * 32;
  const int tx = tid & 31, ty = tid >> 5;
#pragma unroll
  for (int p = 0; p < 4; ++p)
    tile[ty + p * 8][tx] = ip[(size_t)(r0 + ty + p * 8) * C + c0 + tx];
  __syncthreads();
#pragma unroll
  for (int p = 0; p < 4; ++p)
    op[(size_t)(c0 + ty + p * 8) * R + r0 + tx] = f2b(tile[tx][ty + p * 8]);
}

// ---------------------------------------------------------------------------
// k_prep: ALL one-time conversions fused into one launch.  The encv role
// additionally folds COLSUM (column sums of bf16-rounded ENCVT) via
// per-tile partials + atomicAdd (COLSUM pre-zeroed by memset) — kills the
// separate k_colsum dispatch.
// ---------------------------------------------------------------------------
__global__ __launch_bounds__(256) void k_prep(
    const float* __restrict__ x, u16* __restrict__ X16, u16* __restrict__ XT16,
    const float* __restrict__ enc, u16* __restrict__ ENCT,
    const float* __restrict__ encv, u16* __restrict__ ENCVT,
    const float* __restrict__ dec, u16* __restrict__ DECT,
    float2* __restrict__ CS, float* __restrict__ colsum) {
  __shared__ float tile[32][33];
  const int tid = threadIdx.x;
  const int bid = blockIdx.x;
  if (bid < 3072) {
    const size_t i = ((size_t)bid * 256 + tid) * 4;
    float4 v = *(const float4*)&x[i];
    u16 o[4] = {f2b(v.x), f2b(v.y), f2b(v.z), f2b(v.w)};
    *(ushort4*)&X16[i] = *(ushort4*)o;
  } else if (bid < 6144) {
    const int b = bid - 3072;
    const int bz = b / 1536, rb = b % 1536;
    tcvt_body(x + (size_t)bz * TT * DD, XT16 + (size_t)bz * DD * TT,
              TT, DD, rb % 24, rb / 24, tid, tile);
  } else if (bid < 8448) {
    const int b = bid - 6144;
    const int bz = b / 192, rb = b % 192;
    tcvt_body(enc + (size_t)bz * DD * NN, ENCT + (size_t)bz * NN * DD,
              DD, NN, rb % 8, rb / 8, tid, tile);
  } else if (bid < 10752) {
    const int b = bid - 8448;
    const int bz = b / 192, rb = b % 192;
    tcvt_body(encv + (size_t)bz * DD * NN, ENCVT + (size_t)bz * NN * DD,
              DD, NN, rb % 8, rb / 8, tid, tile);
    // colsum partial: tile[d_local][n_local] holds encv fp32; sum the
    // bf16-rounded values over this tile's 32 d-rows for each n.
    if (tid < 32) {
      float s = 0.f;
#pragma unroll
      for (int d = 0; d < 32; ++d) s += b2f(f2b(tile[d][tid]));
      atomicAdd(&colsum[bz * NN + (rb % 8) * 32 + tid], s);
    }
  } else if (bid < 13056) {
    const int b = bid - 10752;
    tcvt_body(dec, DECT, NHH * NN, DD, b % 24, b / 24, tid, tile);
  } else {
    const int idx = (bid - 13056) * 256 + tid;   // t*128 + n2
    const int t = idx >> 7, n2 = idx & 127;
    const float freq = exp2f((float)(2 * n2) * -0.0625f) * 0.15915494309189535f;
    const float phase = (float)t * freq;
    const float ph = (phase - floorf(phase)) * 6.283185307179586f;
    CS[idx] = make_float2(__cosf(ph), __sinf(ph));
  }
}

// ---------------------------------------------------------------------------
// K1: latent = X16 @ ENCT[h]^T; relu; rope -> QR16 [b][h][t][n] AND
// QRT16 [b][h][n][t].  BK=64 pipeline; XOR-swizzled epilogue tile for the
// QRT column read.
// ---------------------------------------------------------------------------
__device__ __forceinline__ int swz8(int row) { return ((row >> 3) & 7) << 3; }

__global__ __launch_bounds__(256) void k1_encode(
    const u16* __restrict__ x16, const u16* __restrict__ enct,
    const float2* __restrict__ CS,
    u16* __restrict__ qr16, u16* __restrict__ qrt16) {
  const int h = blockIdx.z;
  const int m0 = blockIdx.x * 128, n0 = blockIdx.y * 128;
  GEMM_PROLOGUE();
  PIPELINED_K_LOOP64(x16 + (size_t)m0 * DD, DD,
                     enct + ((size_t)h * NN + n0) * DD, DD, DD);
  __syncthreads();
#pragma unroll
  for (int i = 0; i < 4; ++i)
#pragma unroll
    for (int j = 0; j < 4; ++j) {
      const int n = n0 + wc * 64 + j * 16 + col16;
      float rv[4], pv[4];
#pragma unroll
      for (int r = 0; r < 4; ++r) rv[r] = fmaxf(acc[i][j][r], 0.f);
#pragma unroll
      for (int r = 0; r < 4; ++r) pv[r] = __shfl_xor(rv[r], 1);
#pragma unroll
      for (int r = 0; r < 4; ++r) {
        const int lrow = wr * 64 + i * 16 + quad * 4 + r;
        const int t = (m0 + lrow) & (TT - 1);
        const float2 cs = CS[t * 128 + (n >> 1)];
        const float o = (n & 1) ? (rv[r] * cs.x + pv[r] * cs.y)
                                : (rv[r] * cs.x - pv[r] * cs.y);
        smem[lrow * 128 + ((wc * 64 + j * 16 + col16) ^ swz8(lrow))] = f2b(o);
      }
    }
  __syncthreads();
  const int bq = m0 >> 11, tb = m0 & (TT - 1);
  const size_t sl = (size_t)(bq * NHH + h);
  // row-major copy (swizzle-aware source)
  u16* qg = qr16 + (sl * TT + tb) * NN + n0;
#pragma unroll
  for (int s = 0; s < 8; ++s) {
    const int off = (s * 256 + tid) * 8;
    const int row = off >> 7, col = off & 127;
    *(u16x8*)&qg[(size_t)row * NN + col] =
        *(const u16x8*)&smem[row * 128 + (col ^ swz8(row))];
  }
  // transposed copy: QRT16[sl][n][t] = tile[t][n]
#pragma unroll
  for (int s = 0; s < 8; ++s) {
    const int off = (s * 256 + tid) * 8;
    const int nr = off >> 7, tc = off & 127;
    const int sw = swz8(tc);                 // tc 8-aligned: same for tc..tc+7
    u16 vals[8];
#pragma unroll
    for (int k = 0; k < 8; ++k) vals[k] = smem[(tc + k) * 128 + (nr ^ sw)];
    *(u16x8*)&qrt16[(sl * NN + n0 + nr) * TT + tb + tc] = *(u16x8*)vals;
  }
}

// ---------------------------------------------------------------------------
// kSB: kS (S-band GEMM) and kB (H-state GEMM) FUSED into one launch.
// LPT ordering: kB blocks (K=1536, ~6x kS per-block work) launch FIRST.
// kB role now uses 128x128 tiles (32 MFMA/phase, half the barrier pairs of
// the old 64x128): the snapshot reuses the K-loop buffers BETWEEN chunks
// (both buffers are dead at chunk boundaries), so 64KB LDS still fits.
// Role split on blockIdx.x (block-uniform): [0,nB) = kB, [nB,..) = kS.
// ---------------------------------------------------------------------------
__global__ __launch_bounds__(256) void kSB(
    const u16* __restrict__ qr16, const u16* __restrict__ xt16,
    const u16* __restrict__ qrt16, u16* __restrict__ sb,
    u16* __restrict__ h16, int nB, int bh0) {
  GEMM_SMEM;
  const int tid = threadIdx.x;
  const int w = tid >> 6, lane = tid & 63;
  const int wr = w >> 1, wc = w & 1;
  const int col16 = lane & 15, quad = lane >> 4;
  if ((int)blockIdx.x >= nB) {
    // ---------------- kS role: S = QR QR^T band tile ----------------
    const int rS = blockIdx.x - nB;
    const int z = rS / 40, sub = rS % 40;
    const int bh = bh0 + z;
    const int cc = sub / 10, rr = sub % 10;
    int i = (int)((sqrtf(8.f * rr + 1.f) - 1.f) * 0.5f);
    while ((i + 1) * (i + 2) / 2 <= rr) ++i;
    while (i * (i + 1) / 2 > rr) --i;
    const int j = rr - i * (i + 1) / 2;
    const int t0 = (cc * 4 + i) * 128;
    const int s0 = cc * CH + j * 128;
    const u16* q = qr16 + (size_t)bh * TT * NN;
    f32x4 acc[4][4];
#pragma unroll
    for (int a = 0; a < 4; ++a)
#pragma unroll
      for (int b = 0; b < 4; ++b) acc[a][b] = (f32x4){0.f, 0.f, 0.f, 0.f};
    PIPELINED_K_LOOP64(q + (size_t)t0 * NN, NN, q + (size_t)s0 * NN, NN, NN);
    const bool diag = (i == j);
    __syncthreads();
#pragma unroll
    for (int ii = 0; ii < 4; ++ii)
#pragma unroll
      for (int jj = 0; jj < 4; ++jj) {
        const int s = s0 + wc * 64 + jj * 16 + col16;
#pragma unroll
        for (int r = 0; r < 4; ++r) {
          const int lrow = wr * 64 + ii * 16 + quad * 4 + r;
          const int t = t0 + lrow;
          float v = acc[ii][jj][r];
          if (diag && s >= t) v = 0.f;
          smem[lrow * 128 + wc * 64 + jj * 16 + col16] = f2b(v);
        }
      }
    __syncthreads();
    copy_out128(smem, sb + ((size_t)z * TT + t0) * CH + j * 128, CH, tid);
  } else {
    // ---------------- kB role: H chunk-prefix GEMM (128x128) ----------------
    const int r2 = blockIdx.x;
    const int z = r2 / 12, rr2 = r2 % 12;
    const int d0 = (rr2 % 6) * 128, n0 = (rr2 / 6) * 128;
    const int bh = bh0 + z, b = bh / NHH;
    f32x4 acc[4][4];
#pragma unroll
    for (int a = 0; a < 4; ++a)
#pragma unroll
      for (int b2 = 0; b2 < 4; ++b2) acc[a][b2] = (f32x4){0.f, 0.f, 0.f, 0.f};
    const u16* Ab = xt16 + ((size_t)b * DD + d0) * TT;
    const u16* Bb = qrt16 + ((size_t)bh * NN + n0) * TT;
    for (int c = 0; c < 3; ++c) {
      const int kbase = c * CH;
      stage128x32(Ab + kbase, TT, smem, tid);
      stage128x32(Ab + kbase + 32, TT, smem + 4096, tid);
      stage128x32(Bb + kbase, TT, smem + 8192, tid);
      stage128x32(Bb + kbase + 32, TT, smem + 12288, tid);
      for (int s = 0; s < CH / 64; ++s) {
        u16* cb = (s & 1) ? smem + 16384 : smem;
        u16* nb = (s & 1) ? smem : smem + 16384;
        if (s + 1 < CH / 64) {
          const int kn = kbase + (s + 1) * 64;
          stage128x32(Ab + kn, TT, nb, tid);
          stage128x32(Ab + kn + 32, TT, nb + 4096, tid);
          stage128x32(Bb + kn, TT, nb + 8192, tid);
          stage128x32(Bb + kn + 32, TT, nb + 12288, tid);
          asm volatile("s_waitcnt vmcnt(8)" ::: "memory");
        } else {
          asm volatile("s_waitcnt vmcnt(0)" ::: "memory");
        }
        __builtin_amdgcn_s_barrier();
        __builtin_amdgcn_sched_barrier(0);
        mfma_step(cb, cb + 8192, wr, wc, lane, acc);
        mfma_step(cb + 4096, cb + 12288, wr, wc, lane, acc);
        __builtin_amdgcn_sched_barrier(0);
        __builtin_amdgcn_s_barrier();
      }
      // snapshot H16[z][c]: both LDS buffers are dead here — reuse them.
      __syncthreads();
#pragma unroll
      for (int i = 0; i < 4; ++i)
#pragma unroll
        for (int j = 0; j < 4; ++j)
#pragma unroll
          for (int r = 0; r < 4; ++r) {
            const int lrow = wr * 64 + i * 16 + quad * 4 + r;
            smem[lrow * 128 + wc * 64 + j * 16 + col16] = f2b(acc[i][j][r]);
          }
      __syncthreads();
      copy_out128(smem, h16 + ((size_t)(z * 3 + c) * DD + d0) * NN + n0, NN, tid);
      __syncthreads();   // copy reads done before next chunk's stage
    }
  }
}

// ---------------------------------------------------------------------------
// kA: 128x128 output, unified panel-pipelined K sequence.
// 1D grid, bijective chunked XCD swizzle (T1) + LPT tt order.
// Fused stats v3: Σ/Σ² ride the copy-out register stream; padded LDS
// scratch; one coalesced dblk-major float2 store per row.
// ---------------------------------------------------------------------------
__device__ static const int TTORD[16] = {15, 11, 7, 14, 10, 6, 13, 9,
                                         5, 3, 12, 8, 4, 2, 1, 0};

__global__ __launch_bounds__(256) void kA_attn(
    const u16* __restrict__ qr16, const u16* __restrict__ h16,
    const u16* __restrict__ sb, const u16* __restrict__ xt16,
    u16* __restrict__ ykv16, float2* __restrict__ PART, int gsTT, int bh0) {
  GEMM_SMEM;
  const int tid = threadIdx.x;
  const int w = tid >> 6, lane = tid & 63;
  const int wr = w >> 1, wc = w & 1;
  const int col16 = lane & 15, quad = lane >> 4;
  const int nwg = gridDim.x;
  const int bid = blockIdx.x;
  const int qn = nwg >> 3, r8 = nwg & 7;
  const int xcd = bid & 7, pos = bid >> 3;
  const int wg = (xcd < r8 ? xcd * (qn + 1) : r8 * (qn + 1) + (xcd - r8) * qn) + pos;
  const int z = wg / 96;
  const int tt = TTORD[(wg / 6) & 15];       // LPT within chunk
  const int dblk = wg % 6;
  const int d0 = dblk * 128;
  const int bh = bh0 + z, b = bh / NHH;
  const int c = tt >> 2, it = tt & 3;
  const int t0 = tt * 128;
  f32x4 acc[4][4];
#pragma unroll
  for (int i = 0; i < 4; ++i)
#pragma unroll
    for (int j = 0; j < 4; ++j) acc[i][j] = (f32x4){0.f, 0.f, 0.f, 0.f};

  const int c4 = (c > 0) ? 4 : 0;
  const int nP = c4 + (it + 1) * 2;          // BK=64 panels total
  const u16* hs = h16 + ((size_t)(z * 3 + (c > 0 ? c - 1 : 0)) * DD + d0) * NN;
  const u16* qb = qr16 + ((size_t)bh * TT + t0) * NN;
  const u16* sbb = sb + ((size_t)z * TT + t0) * CH;
  const u16* xb = xt16 + ((size_t)b * DD + d0) * TT + c * CH;

#define KA_STAGE(buf, p)                                                  \
  {                                                                       \
    const u16 *pa_, *pb_; size_t la_, lb_;                                \
    if ((p) < c4) {                                                       \
      pa_ = qb + (p) * 64; la_ = NN;                                      \
      pb_ = hs + (p) * 64; lb_ = NN;                                      \
    } else {                                                              \
      const int q_ = (p) - c4;                                            \
      const int j_ = q_ >> 1, kk_ = (q_ & 1) << 6;                        \
      pa_ = sbb + j_ * 128 + kk_; la_ = CH;                               \
      pb_ = xb + j_ * 128 + kk_; lb_ = TT;                                \
    }                                                                     \
    stage128x32(pa_, la_, (buf), tid);                                    \
    stage128x32(pa_ + 32, la_, (buf) + 4096, tid);                        \
    stage128x32(pb_, lb_, (buf) + 8192, tid);                             \
    stage128x32(pb_ + 32, lb_, (buf) + 12288, tid);                       \
  }

  u16* bufA = smem;
  u16* bufB = smem + 16384;
  KA_STAGE(bufA, 0);
  for (int p = 0; p < nP; ++p) {
    u16* cb = (p & 1) ? bufB : bufA;
    u16* nb = (p & 1) ? bufA : bufB;
    if (p + 1 < nP) {
      KA_STAGE(nb, p + 1);
      asm volatile("s_waitcnt vmcnt(8)" ::: "memory");
    } else {
      asm volatile("s_waitcnt vmcnt(0)" ::: "memory");
    }
    __builtin_amdgcn_s_barrier();            // publish panel p across waves
    __builtin_amdgcn_sched_barrier(0);
    mfma_step(cb, cb + 8192, wr, wc, lane, acc);
    mfma_step(cb + 4096, cb + 12288, wr, wc, lane, acc);
    __builtin_amdgcn_sched_barrier(0);
    __builtin_amdgcn_s_barrier();            // reads of cb done before overwrite
  }
#undef KA_STAGE

  __syncthreads();
#pragma unroll
  for (int i = 0; i < 4; ++i)
#pragma unroll
    for (int j = 0; j < 4; ++j)
#pragma unroll
      for (int r = 0; r < 4; ++r) {
        const int lrow = wr * 64 + i * 16 + quad * 4 + r;
        smem[lrow * 128 + wc * 64 + j * 16 + col16] = f2b(acc[i][j][r]);
      }
  __syncthreads();
  // copy-out + per-chunk stats.
  float2* scratch = (float2*)&smem[16384];   // [128][17] padded
  u16* yg = ykv16 + ((size_t)z * TT + t0) * DD + d0;
#pragma unroll
  for (int s = 0; s < 8; ++s) {
    const int off = (s * 256 + tid) * 8;
    const int row = off >> 7, col = off & 127;
    const u16x8 v = *(const u16x8*)&smem[off];
    *(u16x8*)&yg[(size_t)row * DD + col] = v;
    float ps = 0.f, pq = 0.f;
#pragma unroll
    for (int k = 0; k < 8; ++k) {
      const float f = b2f(v[k]);
      ps += f;
      pq += f * f;
    }
    scratch[row * 17 + (tid & 15)] = make_float2(ps, pq);
  }
  __syncthreads();
  if (tid < 128) {
    const float2* pr = &scratch[tid * 17];
    float s = 0.f, q2 = 0.f;
#pragma unroll
    for (int k = 0; k < 16; ++k) { s += pr[k].x; q2 += pr[k].y; }
    PART[(size_t)dblk * gsTT + z * TT + t0 + tid] = make_float2(s, q2);
  }
}

// ---------------------------------------------------------------------------
// K4: raw GEMM ykv16 @ ENCVT[h]^T with LN as epilogue affine; row stats
// folded INLINE from PART; xs via inverse rope of QR16 (CS table).
// QR tile prefetch OVERLAPPED with the final K-phase (np=12 even, final
// phase consumes bufB -> QR asyncs go to the free bufA, vmcnt(8)).
// ---------------------------------------------------------------------------
__global__ __launch_bounds__(256) void k4_xy(
    const u16* __restrict__ ykv16, const u16* __restrict__ encvt,
    const float2* __restrict__ CS,
    u16* __restrict__ qrxy, const float2* __restrict__ PART,
    const float* __restrict__ colsum,
    float* __restrict__ out2, int gsTT, int bh0) {
  const int z = blockIdx.z;
  const int bh = bh0 + z, h = bh % NHH;
  const int t0 = blockIdx.x * 128, n0 = blockIdx.y * 128;
  GEMM_PROLOGUE();
  const u16* Ab = ykv16 + ((size_t)z * TT + t0) * DD;
  const u16* Bb = encvt + ((size_t)h * NN + n0) * DD;
  const u16* qg = qrxy + ((size_t)bh * TT + t0) * NN + n0;
  stage128x32(Ab, DD, smem, tid);
  stage128x32(Ab + 32, DD, smem + 4096, tid);
  stage128x32(Bb, DD, smem + 8192, tid);
  stage128x32(Bb + 32, DD, smem + 12288, tid);
  const int np = DD / 64;                    // 12 (even)
  for (int pp = 0; pp < np; ++pp) {
    u16* cb = (pp & 1) ? smem + 16384 : smem;
    u16* nb = (pp & 1) ? smem : smem + 16384;
    if (pp + 1 < np) {
      const int kn = (pp + 1) * 64;
      stage128x32(Ab + kn, DD, nb, tid);
      stage128x32(Ab + kn + 32, DD, nb + 4096, tid);
      stage128x32(Bb + kn, DD, nb + 8192, tid);
      stage128x32(Bb + kn + 32, DD, nb + 12288, tid);
      asm volatile("s_waitcnt vmcnt(8)" ::: "memory");
    } else {
      // final phase: prefetch QR tile into the free buffer (bufA).
#pragma unroll
      for (int s = 0; s < 8; ++s) {
        const int row = s * 16 + w * 4 + (lane >> 4);
        const int col = (lane & 15) * 8;
        async16(qg + (size_t)row * NN + col, smem + (s * 256 + w * 64) * 8);
      }
      asm volatile("s_waitcnt vmcnt(8)" ::: "memory");
    }
    __builtin_amdgcn_s_barrier();
    __builtin_amdgcn_sched_barrier(0);
    mfma_step(cb, cb + 8192, wr, wc, lane, acc);
    mfma_step(cb + 4096, cb + 12288, wr, wc, lane, acc);
    __builtin_amdgcn_sched_barrier(0);
    __builtin_amdgcn_s_barrier();
  }
  asm volatile("s_waitcnt vmcnt(0)" ::: "memory");   // QR landed
  __syncthreads();
#pragma unroll
  for (int i = 0; i < 4; ++i) {
    float muv[4], rsv[4];
#pragma unroll
    for (int r = 0; r < 4; ++r) {
      const int grow = z * TT + t0 + wr * 64 + i * 16 + quad * 4 + r;
      float s_ = 0.f, q_ = 0.f;
#pragma unroll
      for (int d = 0; d < 6; ++d) {
        const float2 p2 = PART[(size_t)d * gsTT + grow];
        s_ += p2.x;
        q_ += p2.y;
      }
      const float m_ = s_ * (1.f / 768.f);
      muv[r] = m_;
      rsv[r] = rsqrtf(q_ * (1.f / 768.f) - m_ * m_ + 1e-5f);
    }
#pragma unroll
    for (int j = 0; j < 4; ++j) {
      const int lcol = wc * 64 + j * 16 + col16;
      const int n = n0 + lcol;
      const float csum = colsum[h * NN + n];
#pragma unroll
      for (int r = 0; r < 4; ++r) {
        const int lrow = wr * 64 + i * 16 + quad * 4 + r;
        const int t = t0 + lrow;
        const float ys = fmaxf(rsv[r] * acc[i][j][r] - rsv[r] * muv[r] * csum, 0.f);
        const unsigned pq =
            *(const unsigned*)&smem[lrow * 128 + (lcol & ~1)];
        const float lo = b2f((u16)pq), hi = b2f((u16)(pq >> 16));
        const float2 cs = CS[t * 128 + (n >> 1)];
        const float xs = (n & 1) ? (hi * cs.x - lo * cs.y)
                                 : (lo * cs.x + hi * cs.y);
        const float val = ys * xs;
        out2[((size_t)bh * TT + t) * NN + n] = val;
        smem[16384 + lrow * 128 + lcol] = f2b(val);
      }
    }
  }
  __syncthreads();
  copy_out128(smem + 16384, qrxy + ((size_t)bh * TT + t0) * NN + n0, NN, tid);
}

// ---------------------------------------------------------------------------
// K5: ymlp = flat(XY) @ DECT^T.  M=4096, N=768, K=3072.  128x128 tiles,
// BK=64 dbuf + vmcnt(8), SPLIT-K=2 (fp32 partials to ymp0/ymp1; k6 sums).
// Grid 384 = 1.5 blocks/CU keeps inter-block overlap.
// ---------------------------------------------------------------------------
__global__ __launch_bounds__(256) void k5_mlp(
    const u16* __restrict__ xyq, const u16* __restrict__ dect,
    float* __restrict__ ymp0, float* __restrict__ ymp1) {
  GEMM_PROLOGUE();
  const int bid = blockIdx.x;                // 384 = 8 XCD x 48
  const int wg = (bid & 7) * 48 + (bid >> 3);
  const int kh = wg / 192;                   // K half
  const int r = wg % 192;
  const int m0 = (r / 6) * 128, d0 = (r % 6) * 128;
  const int b = m0 >> 11, t0 = m0 & (TT - 1);
  const int kbase = kh * 1536;
#define K5_ST(buf, p)                                                       \
  {                                                                         \
    const int k0_ = kbase + (p) * 64, hh_ = k0_ >> 8, kk_ = k0_ & 255;      \
    const u16* pa_ = xyq + ((size_t)(b * NHH + hh_) * TT + t0) * NN + kk_;  \
    const u16* pb_ = dect + (size_t)d0 * (NHH * NN) + k0_;                  \
    stage128x32(pa_, NN, (buf), tid);                                       \
    stage128x32(pa_ + 32, NN, (buf) + 4096, tid);                           \
    stage128x32(pb_, NHH * NN, (buf) + 8192, tid);                          \
    stage128x32(pb_ + 32, NHH * NN, (buf) + 12288, tid);                    \
  }
  const int NP = 1536 / 64;                  // 24 panels per half
  u16* bufA = smem;
  u16* bufB = smem + 16384;
  K5_ST(bufA, 0);
  for (int p = 0; p < NP; ++p) {
    u16* cb = (p & 1) ? bufB : bufA;
    u16* nb = (p & 1) ? bufA : bufB;
    if (p + 1 < NP) {
      K5_ST(nb, p + 1);
      asm volatile("s_waitcnt vmcnt(8)" ::: "memory");
    } else {
      asm volatile("s_waitcnt vmcnt(0)" ::: "memory");
    }
    __builtin_amdgcn_s_barrier();
    __builtin_amdgcn_sched_barrier(0);
    mfma_step(cb, cb + 8192, wr, wc, lane, acc);
    mfma_step(cb + 4096, cb + 12288, wr, wc, lane, acc);
    __builtin_amdgcn_sched_barrier(0);
    __builtin_amdgcn_s_barrier();
  }
#undef K5_ST
  float* ymlp = kh ? ymp1 : ymp0;
#pragma unroll
  for (int i = 0; i < 4; ++i)
#pragma unroll
    for (int j = 0; j < 4; ++j) {
      const int d = d0 + wc * 64 + j * 16 + col16;
#pragma unroll
      for (int r4 = 0; r4 < 4; ++r4) {
        const int mm = m0 + wr * 64 + i * 16 + quad * 4 + r4;
        ymlp[(size_t)mm * DD + d] = acc[i][j][r4];
      }
    }
}

// ---------------------------------------------------------------------------
// K6: v = ym0+ym1 (split-K partials); y = ln(v)*sqrt(0.1/(ra+1e-6))*scale;
// out1 = ln(x+y).  Wave per row (float4 x3 per lane), 4 rows/block,
// pure-wave shuffle reductions — no LDS, no barriers.
// ---------------------------------------------------------------------------
__global__ __launch_bounds__(256) void k6_final(
    const float* __restrict__ ym0, const float* __restrict__ ym1,
    const float* __restrict__ x,
    const float* __restrict__ scale, const float* __restrict__ ra,
    float* __restrict__ out1) {
  const int row = blockIdx.x * 4 + (threadIdx.x >> 6);
  const int lane = threadIdx.x & 63;
  const size_t base = (size_t)row * DD;
  float4 v[3];
  float sum = 0.f, sq = 0.f;
#pragma unroll
  for (int k = 0; k < 3; ++k) {
    const size_t idx = base + k * 256 + lane * 4;
    const float4 a = *(const float4*)&ym0[idx];
    const float4 b = *(const float4*)&ym1[idx];
    v[k] = make_float4(a.x + b.x, a.y + b.y, a.z + b.z, a.w + b.w);
    sum += v[k].x + v[k].y + v[k].z + v[k].w;
    sq += v[k].x * v[k].x + v[k].y * v[k].y + v[k].z * v[k].z + v[k].w * v[k].w;
  }
#pragma unroll
  for (int off = 32; off; off >>= 1) { sum += __shfl_xor(sum, off); sq += __shfl_xor(sq, off); }
  const float m1 = sum * (1.f / 768.f);
  const float r1 = rsqrtf(sq * (1.f / 768.f) - m1 * m1 + 1e-5f);
  float4 z[3];
  float sum2 = 0.f, sq2 = 0.f;
#pragma unroll
  for (int k = 0; k < 3; ++k) {
    const int d = k * 256 + lane * 4;
    const float4 sc = *(const float4*)&scale[d];
    const float4 rv = *(const float4*)&ra[d];
    const float4 xv = *(const float4*)&x[base + d];
    float4 zz;
    zz.x = xv.x + (v[k].x - m1) * r1 * sqrtf(0.1f / (rv.x + 1e-6f)) * sc.x;
    zz.y = xv.y + (v[k].y - m1) * r1 * sqrtf(0.1f / (rv.y + 1e-6f)) * sc.y;
    zz.z = xv.z + (v[k].z - m1) * r1 * sqrtf(0.1f / (rv.z + 1e-6f)) * sc.z;
    zz.w = xv.w + (v[k].w - m1) * r1 * sqrtf(0.1f / (rv.w + 1e-6f)) * sc.w;
    z[k] = zz;
    sum2 += zz.x + zz.y + zz.z + zz.w;
    sq2 += zz.x * zz.x + zz.y * zz.y + zz.z * zz.z + zz.w * zz.w;
  }
#pragma unroll
  for (int off = 32; off; off >>= 1) { sum2 += __shfl_xor(sum2, off); sq2 += __shfl_xor(sq2, off); }
  const float m2 = sum2 * (1.f / 768.f);
  const float r2 = rsqrtf(sq2 * (1.f / 768.f) - m2 * m2 + 1e-5f);
#pragma unroll
  for (int k = 0; k < 3; ++k) {
    const int d = k * 256 + lane * 4;
    float4 o;
    o.x = (z[k].x - m2) * r2;
    o.y = (z[k].y - m2) * r2;
    o.z = (z[k].z - m2) * r2;
    o.w = (z[k].w - m2) * r2;
    *(float4*)&out1[base + d] = o;
  }
}

// ---------------------------------------------------------------------------
extern "C" void kernel_launch(void* const* d_in, const int* in_sizes, int n_in,
                              void* d_out, int out_size, void* d_ws, size_t ws_size,
                              hipStream_t stream) {
  const float* x = (const float*)d_in[0];
  const float* enc = (const float*)d_in[1];
  const float* encv = (const float*)d_in[2];
  const float* dec = (const float*)d_in[3];
  const float* scale = (const float*)d_in[4];
  const float* ra = (const float*)d_in[5];
  float* out1 = (float*)d_out;
  float* out2 = out1 + (size_t)BB * TT * DD;
  float* ym0 = out1;                          // k5 half-0 partial, k6 in-place

  const int NS = BB * NHH;  // 24 slices
  unsigned char* p = (unsigned char*)d_ws;
  u16* X16 = (u16*)p;    p += (size_t)BB * TT * DD * 2;
  u16* XT16 = (u16*)p;   p += (size_t)BB * DD * TT * 2;
  u16* ENCT = (u16*)p;   p += (size_t)NHH * NN * DD * 2;
  u16* ENCVT = (u16*)p;  p += (size_t)NHH * NN * DD * 2;
  u16* DECT = (u16*)p;   p += (size_t)DD * NHH * NN * 2;
  u16* QR16 = (u16*)p;   p += (size_t)NS * TT * NN * 2;   // holds QR, then XY
  u16* QRT16 = (u16*)p;  p += (size_t)NS * NN * TT * 2;
  float* COLSUM = (float*)p; p += (size_t)NHH * NN * 4;
  float2* CS = (float2*)p;   p += (size_t)TT * (NN / 2) * sizeof(float2);
  float* YM1 = (float*)p;    p += (size_t)BB * TT * DD * 4;  // k5 half-1 partial
  // Per-slice pool: SB + H16 + YKV16 + PART(48B/row)
  const size_t SLICE_B = (size_t)TT * CH * 2 + 3 * (size_t)DD * NN * 2 +
                         (size_t)TT * DD * 2 + (size_t)TT * 48;
  size_t fixed = (size_t)(p - (unsigned char*)d_ws);
  size_t rem = (ws_size > fixed) ? ws_size - fixed : 0;
  int GSmax = (int)(rem / SLICE_B);
  if (GSmax < 1) GSmax = 1;
  if (GSmax > NS) GSmax = NS;
  const int ngrp = (NS + GSmax - 1) / GSmax;
  const int GS = (NS + ngrp - 1) / ngrp;     // balanced groups
  u16* SB = (u16*)p;     p += (size_t)GS * TT * CH * 2;
  u16* H16 = (u16*)p;    p += (size_t)GS * 3 * DD * NN * 2;
  u16* YKV16 = (u16*)p;  p += (size_t)GS * TT * DD * 2;
  float2* PART = (float2*)p; p += (size_t)GS * TT * 6 * sizeof(float2);
  const int gsTT = GS * TT;

  // One-time conversions / transposes / tables / colsum: one fused launch.
  hipMemsetAsync(COLSUM, 0, (size_t)NHH * NN * 4, stream);
  k_prep<<<dim3(14080), 256, 0, stream>>>(
      x, X16, XT16, enc, ENCT, encv, ENCVT, dec, DECT, CS, COLSUM);

  k1_encode<<<dim3(BB * TT / 128, NN / 128, NHH), 256, 0, stream>>>(
      X16, ENCT, CS, QR16, QRT16);

  for (int bh0 = 0; bh0 < NS; bh0 += GS) {
    const int gs = imin(GS, NS - bh0);
    kSB<<<dim3(52 * gs), 256, 0, stream>>>(
        QR16, XT16, QRT16, SB, H16, 12 * gs, bh0);
    kA_attn<<<dim3(96 * gs), 256, 0, stream>>>(
        QR16, H16, SB, XT16, YKV16, PART, gsTT, bh0);
    k4_xy<<<dim3(TT / 128, NN / 128, gs), 256, 0, stream>>>(
        YKV16, ENCVT, CS, QR16, PART, COLSUM, out2, gsTT, bh0);
  }

  k5_mlp<<<dim3(384), 256, 0, stream>>>(QR16, DECT, ym0, YM1);
  k6_final<<<dim3(BB * TT / 4), 256, 0, stream>>>(ym0, YM1, x, scale, ra, out1);
}